// Round 1
// baseline (1198.293 us; speedup 1.0000x reference)
//
#include <hip/hip_runtime.h>
#include <stdint.h>

#define NN 65536
#define EE 524288
#define BB 512

// ===================== graph prep =====================
__global__ void k_hist(const int* __restrict__ src, const int* __restrict__ dst,
                       float* __restrict__ degf, int* __restrict__ counts) {
  int e = blockIdx.x * 256 + threadIdx.x;
  if (e >= EE) return;
  atomicAdd(&degf[dst[e]], 1.0f);
  atomicAdd(&counts[src[e] >> 7], 1);
}

__global__ void k_scan(const int* __restrict__ counts, int* __restrict__ offs,
                       int* __restrict__ cursor) {
  __shared__ int s[512];
  int t = threadIdx.x;
  s[t] = counts[t];
  __syncthreads();
  for (int d = 1; d < 512; d <<= 1) {
    int v = (t >= d) ? s[t - d] : 0;
    __syncthreads();
    s[t] += v;
    __syncthreads();
  }
  int excl = (t == 0) ? 0 : s[t - 1];
  offs[t] = excl;
  cursor[t] = excl;
  if (t == 511) offs[512] = s[511];
}

__global__ void k_scatter(const int* __restrict__ src, const int* __restrict__ dst,
                          int* __restrict__ cursor, uint32_t* __restrict__ pk) {
  int e = blockIdx.x * 256 + threadIdx.x;
  if (e >= EE) return;
  int s = src[e], d = dst[e];
  int slot = atomicAdd(&cursor[s >> 7], 1);
  pk[slot] = (uint32_t)(s & 127) | ((uint32_t)(d & 127) << 8);
}

__global__ void k_norm(const float* __restrict__ degf, float* __restrict__ nrm) {
  int i = blockIdx.x * 256 + threadIdx.x;
  nrm[i] = rsqrtf(degf[i] + 1.0f);
}

// ===================== weight prep (GAT folding) =====================
// u_h = Wg_in_h @ al_h ; wv_h = Wg_in_h @ ar_h ; q_h = Wpp @ u_h ; ch_h = bpp . u_h
// G = mean_h Wg_w_h ; g0w = mean_h bg_w_h ; g0in = mean_h bg_in_h
__global__ void k_prep(const float* __restrict__ Wg_in, const float* __restrict__ al_in,
                       const float* __restrict__ ar_in, const float* __restrict__ bg_in,
                       const float* __restrict__ Wpp, const float* __restrict__ bpp,
                       const float* __restrict__ Wg_w, const float* __restrict__ bg_w,
                       float* __restrict__ u, float* __restrict__ wv, float* __restrict__ q,
                       float* __restrict__ ch, float* __restrict__ G,
                       float* __restrict__ g0w, float* __restrict__ g0in) {
  int t = threadIdx.x;
  for (int i = t; i < 384; i += 256) {
    int h = i >> 7, k = i & 127;
    float su = 0.f, sw = 0.f;
    for (int c = 0; c < 128; ++c) {
      float g = Wg_in[k * 384 + h * 128 + c];
      su += g * al_in[h * 128 + c];
      sw += g * ar_in[h * 128 + c];
    }
    u[i] = su;
    wv[i] = sw;
  }
  __syncthreads();
  for (int i = t; i < 384; i += 256) {
    int h = i >> 7, j = i & 127;
    float s = 0.f;
    for (int k = 0; k < 128; ++k) s += Wpp[j * 128 + k] * u[h * 128 + k];
    q[i] = s;
  }
  if (t < 3) {
    float s = 0.f;
    for (int k = 0; k < 128; ++k) s += bpp[k] * u[t * 128 + k];
    ch[t] = s;
  }
  for (int i = t; i < 16384; i += 256) {
    int k = i >> 7, c = i & 127;
    G[i] = (Wg_w[k * 384 + c] + Wg_w[k * 384 + 128 + c] + Wg_w[k * 384 + 256 + c]) * (1.0f / 3.0f);
  }
  if (t < 128) {
    g0w[t] = (bg_w[t] + bg_w[128 + t] + bg_w[256 + t]) * (1.0f / 3.0f);
    g0in[t] = (bg_in[t] + bg_in[128 + t] + bg_in[256 + t]) * (1.0f / 3.0f);
  }
}

// ===================== hrs encoder: [512,2048]@[2048,128] (K split in 2) =====================
__global__ void k_hrs(const float* __restrict__ img, const float* __restrict__ Whrs,
                      const float* __restrict__ bhrs, float* __restrict__ hrs) {
  __shared__ float sI[8 * 1024];
  int bb = blockIdx.x >> 1, kh = blockIdx.x & 1;
  int t = threadIdx.x;
  int r0 = bb * 8;
  for (int i = t; i < 8192; i += 256) {
    int r = i >> 10, k = i & 1023;
    sI[i] = img[(size_t)(r0 + r) * 2048 + kh * 1024 + k];
  }
  __syncthreads();
  int c = t & 127, rh = t >> 7;
  float a0 = 0.f, a1 = 0.f, a2 = 0.f, a3 = 0.f;
  const float* W = Whrs + (size_t)kh * 1024 * 128 + c;
  const float* s0 = sI + (rh * 4 + 0) * 1024;
  const float* s1 = sI + (rh * 4 + 1) * 1024;
  const float* s2 = sI + (rh * 4 + 2) * 1024;
  const float* s3 = sI + (rh * 4 + 3) * 1024;
  for (int k = 0; k < 1024; ++k) {
    float w = W[(size_t)k * 128];
    a0 += s0[k] * w;
    a1 += s1[k] * w;
    a2 += s2[k] * w;
    a3 += s3[k] * w;
  }
  float bias = (kh == 0) ? bhrs[c] : 0.f;
  int rb = r0 + rh * 4;
  atomicAdd(&hrs[(rb + 0) * 128 + c], a0 + bias);
  atomicAdd(&hrs[(rb + 1) * 128 + c], a1 + bias);
  atomicAdd(&hrs[(rb + 2) * 128 + c], a2 + bias);
  atomicAdd(&hrs[(rb + 3) * 128 + c], a3 + bias);
}

// ===================== generic C[M,128] = X[M,128] @ W[128,128] + bias =====================
__global__ void k_gemm128(const float* __restrict__ X, const float* __restrict__ W,
                          const float* __restrict__ bias, float* __restrict__ C) {
  __shared__ float sX[8 * 128];
  int r0 = blockIdx.x * 8;
  int t = threadIdx.x;
  for (int i = t; i < 1024; i += 256) sX[i] = X[(size_t)r0 * 128 + i];
  __syncthreads();
  int c = t & 127, rh = t >> 7;
  float b = bias[c];
  float a0 = b, a1 = b, a2 = b, a3 = b;
  const float* s = sX + (rh * 4) * 128;
  for (int k = 0; k < 128; ++k) {
    float w = W[k * 128 + c];
    a0 += s[k] * w;
    a1 += s[128 + k] * w;
    a2 += s[256 + k] * w;
    a3 += s[384 + k] * w;
  }
  int rb = r0 + rh * 4;
  C[(size_t)(rb + 0) * 128 + c] = a0;
  C[(size_t)(rb + 1) * 128 + c] = a1;
  C[(size_t)(rb + 2) * 128 + c] = a2;
  C[(size_t)(rb + 3) * 128 + c] = a3;
}

// ===================== er[b,h] = ph[b] . wv_h =====================
__global__ void k_er(const float* __restrict__ ph, const float* __restrict__ wv,
                     float* __restrict__ er) {
  int i = blockIdx.x * 256 + threadIdx.x;
  if (i >= BB * 3) return;
  int b = i / 3, h = i % 3;
  float s = 0.f;
  for (int k = 0; k < 128; ++k) s += ph[b * 128 + k] * wv[h * 128 + k];
  er[i] = s;
}

// ===================== GCN layer 1 (per parcel, fused agg + matmul + relu) =====================
__global__ void __launch_bounds__(256) k_gcn1(const float* __restrict__ x,
                                              const float* __restrict__ W1,
                                              const float* __restrict__ b1,
                                              const float* __restrict__ nrm,
                                              const uint32_t* __restrict__ pk,
                                              const int* __restrict__ offs,
                                              float* __restrict__ h1) {
  extern __shared__ float sm[];
  float* sA = sm;          // [128][64] swizzled: h = x*norm
  float* sB = sm + 8192;   // [128][64] swizzled: agg accumulator
  int b = blockIdx.x, t = threadIdx.x;
  int base = b << 7;
  for (int i = t; i < 8192; i += 256) {
    int r = i >> 6, k = i & 63;
    float v = x[(size_t)(base + r) * 64 + k] * nrm[base + r];
    int idx = (r << 6) | (k ^ (r & 31));
    sA[idx] = v;
    sB[idx] = v;  // self loop
  }
  __syncthreads();
  int e0 = offs[b], e1 = offs[b + 1];
  int wave = t >> 6, lane = t & 63;
  for (int e = e0 + wave; e < e1; e += 4) {
    uint32_t p = pk[e];
    int ls = p & 127, ld = (p >> 8) & 127;
    float v = sA[(ls << 6) | (lane ^ (ls & 31))];
    atomicAdd(&sB[(ld << 6) | (lane ^ (ld & 31))], v);
  }
  __syncthreads();
  for (int i = t; i < 8192; i += 256) sB[i] *= nrm[base + (i >> 6)];
  __syncthreads();
  // out[128,128] = sB[128,64] @ W1[64,128] + b1, relu -> h1
  int rg = t >> 4, cg = t & 15;
  int r0 = rg * 8, c0 = cg * 8;
  float acc[8][8];
#pragma unroll
  for (int j = 0; j < 8; ++j) {
    float bv = b1[c0 + j];
#pragma unroll
    for (int i = 0; i < 8; ++i) acc[i][j] = bv;
  }
  for (int k = 0; k < 64; ++k) {
    float a[8];
#pragma unroll
    for (int i = 0; i < 8; ++i) a[i] = sB[((r0 + i) << 6) | (k ^ ((r0 + i) & 31))];
    float4 w0 = *(const float4*)(&W1[k * 128 + c0]);
    float4 w1 = *(const float4*)(&W1[k * 128 + c0 + 4]);
    float w[8] = {w0.x, w0.y, w0.z, w0.w, w1.x, w1.y, w1.z, w1.w};
#pragma unroll
    for (int i = 0; i < 8; ++i)
#pragma unroll
      for (int j = 0; j < 8; ++j) acc[i][j] += a[i] * w[j];
  }
#pragma unroll
  for (int i = 0; i < 8; ++i) {
    float4 o0, o1;
    o0.x = fmaxf(acc[i][0], 0.f); o0.y = fmaxf(acc[i][1], 0.f);
    o0.z = fmaxf(acc[i][2], 0.f); o0.w = fmaxf(acc[i][3], 0.f);
    o1.x = fmaxf(acc[i][4], 0.f); o1.y = fmaxf(acc[i][5], 0.f);
    o1.z = fmaxf(acc[i][6], 0.f); o1.w = fmaxf(acc[i][7], 0.f);
    float4* dp = (float4*)&h1[(size_t)(base + r0 + i) * 128 + c0];
    dp[0] = o0;
    dp[1] = o1;
  }
}

// ===================== GCN layer 2 + poi_pool + GAT-in softmax/pool (per parcel) =====================
__global__ void __launch_bounds__(256) k_gcn2(const float* __restrict__ h1,
                                              const float* __restrict__ W2,
                                              const float* __restrict__ b2,
                                              const float* __restrict__ nrm,
                                              const uint32_t* __restrict__ pk,
                                              const int* __restrict__ offs,
                                              const float* __restrict__ q,
                                              const float* __restrict__ ch,
                                              const float* __restrict__ er,
                                              float* __restrict__ poi_pool,
                                              float* __restrict__ pooled) {
  extern __shared__ float sm[];
  float* sB = sm;                  // [128][128] swizzled
  float* sNorm = sm + 16384;       // [128]
  float* sQ = sNorm + 128;         // [3][128]
  float* sAl = sQ + 384;           // [3][128] e -> alpha
  float* sEr = sAl + 384;          // [3]
  float* sCh = sEr + 4;            // [3]
  int b = blockIdx.x, t = threadIdx.x;
  int base = b << 7;
  if (t < 128) sNorm[t] = nrm[base + t];
  for (int i = t; i < 384; i += 256) sQ[i] = q[i];
  if (t < 3) {
    sEr[t] = er[b * 3 + t];
    sCh[t] = ch[t];
  }
  __syncthreads();
  for (int i = t; i < 16384; i += 256) {
    int r = i >> 7, k = i & 127;
    float v = h1[(size_t)(base + r) * 128 + k] * sNorm[r];
    sB[(r << 7) | (k ^ (r & 31))] = v;  // self loop init
  }
  __syncthreads();
  int e0 = offs[b], e1 = offs[b + 1];
  int wave = t >> 6, lane = t & 63;
  for (int e = e0 + wave; e < e1; e += 4) {
    uint32_t p = pk[e];
    int ls = p & 127, ld = (p >> 8) & 127;
    float ns = sNorm[ls];
    const float* hrow = &h1[(size_t)(base + ls) * 128];
    float v0 = hrow[lane] * ns;
    float v1 = hrow[lane + 64] * ns;
    atomicAdd(&sB[(ld << 7) | (lane ^ (ld & 31))], v0);
    atomicAdd(&sB[(ld << 7) | ((lane + 64) ^ (ld & 31))], v1);
  }
  __syncthreads();
  for (int i = t; i < 16384; i += 256) sB[i] *= sNorm[i >> 7];
  __syncthreads();
  // poi_node = sB @ W2 + b2 (kept in LDS only)
  int rg = t >> 4, cg = t & 15;
  int r0 = rg * 8, c0 = cg * 8;
  float acc[8][8];
#pragma unroll
  for (int j = 0; j < 8; ++j) {
    float bv = b2[c0 + j];
#pragma unroll
    for (int i = 0; i < 8; ++i) acc[i][j] = bv;
  }
  for (int k = 0; k < 128; ++k) {
    float a[8];
#pragma unroll
    for (int i = 0; i < 8; ++i) a[i] = sB[((r0 + i) << 7) | (k ^ ((r0 + i) & 31))];
    float4 w0 = *(const float4*)(&W2[k * 128 + c0]);
    float4 w1 = *(const float4*)(&W2[k * 128 + c0 + 4]);
    float w[8] = {w0.x, w0.y, w0.z, w0.w, w1.x, w1.y, w1.z, w1.w};
#pragma unroll
    for (int i = 0; i < 8; ++i)
#pragma unroll
      for (int j = 0; j < 8; ++j) acc[i][j] += a[i] * w[j];
  }
  __syncthreads();  // all sB reads done before overwrite
#pragma unroll
  for (int i = 0; i < 8; ++i)
#pragma unroll
    for (int j = 0; j < 8; ++j)
      sB[((r0 + i) << 7) | ((c0 + j) ^ ((r0 + i) & 31))] = acc[i][j];
  __syncthreads();
  // tail: poi_pool (waves 0,1) + el/e per row (waves 2,3)
  if (t < 128) {
    int c = t;
    float s = 0.f;
    for (int r = 0; r < 128; ++r) s += sB[(r << 7) | (c ^ (r & 31))];
    poi_pool[b * 128 + c] = s * (1.0f / 128.0f);
  } else {
    int r = t - 128;
    float d0 = 0.f, d1 = 0.f, d2 = 0.f;
    for (int c = 0; c < 128; ++c) {
      float v = sB[(r << 7) | (c ^ (r & 31))];
      d0 += v * sQ[c];
      d1 += v * sQ[128 + c];
      d2 += v * sQ[256 + c];
    }
    float e0v = d0 + sCh[0] + sEr[0];
    float e1v = d1 + sCh[1] + sEr[1];
    float e2v = d2 + sCh[2] + sEr[2];
    sAl[r] = (e0v > 0.f) ? e0v : 0.2f * e0v;
    sAl[128 + r] = (e1v > 0.f) ? e1v : 0.2f * e1v;
    sAl[256 + r] = (e2v > 0.f) ? e2v : 0.2f * e2v;
  }
  __syncthreads();
  // per-head softmax over the 128 pois (one wave per head)
  int h = t >> 6;
  if (h < 3) {
    int l = t & 63;
    float v0 = sAl[h * 128 + l], v1 = sAl[h * 128 + 64 + l];
    float m = fmaxf(v0, v1);
    for (int off = 32; off > 0; off >>= 1) m = fmaxf(m, __shfl_xor(m, off));
    float x0 = __expf(v0 - m), x1 = __expf(v1 - m);
    float s = x0 + x1;
    for (int off = 32; off > 0; off >>= 1) s += __shfl_xor(s, off);
    float inv = 1.0f / s;
    sAl[h * 128 + l] = x0 * inv;
    sAl[h * 128 + 64 + l] = x1 * inv;
  }
  __syncthreads();
  // pooled[b,h,:] = sum_r alpha[r,h] * poi_node[r,:]
  for (int task = t; task < 384; task += 256) {
    int hh = task >> 7, c = task & 127;
    float s = 0.f;
    for (int r = 0; r < 128; ++r) s += sAl[hh * 128 + r] * sB[(r << 7) | (c ^ (r & 31))];
    pooled[((size_t)b * 3 + hh) * 128 + c] = s;
  }
}

// ===================== med pipeline =====================
__global__ void k_mfn(const float* __restrict__ hrs, const float* __restrict__ pool,
                      float* __restrict__ mfn) {
  int r = blockIdx.x, l = threadIdx.x;  // 64 threads
  float v0 = hrs[r * 128 + l], v1 = hrs[r * 128 + 64 + l];
  float v2 = pool[r * 128 + l], v3 = pool[r * 128 + 64 + l];
  float ss = v0 * v0 + v1 * v1 + v2 * v2 + v3 * v3;
  for (int off = 32; off > 0; off >>= 1) ss += __shfl_xor(ss, off);
  float rn = rsqrtf(ss);
  mfn[r * 256 + l] = v0 * rn;
  mfn[r * 256 + 64 + l] = v1 * rn;
  mfn[r * 256 + 128 + l] = v2 * rn;
  mfn[r * 256 + 192 + l] = v3 * rn;
}

__global__ void k_med(const float* __restrict__ mfn, float* __restrict__ med) {
  __shared__ float sI[64 * 64];
  __shared__ float sJ[64 * 64];
  int bi = blockIdx.x >> 3, bj = blockIdx.x & 7;
  int t = threadIdx.x;
  int ti = t >> 4, tj = t & 15;
  float acc[4][4] = {};
  for (int k0 = 0; k0 < 256; k0 += 64) {
    __syncthreads();
    for (int i = t; i < 4096; i += 256) {
      int r = i >> 6, k = i & 63;
      int idx = (r << 6) | (k ^ (r & 31));
      sI[idx] = mfn[(bi * 64 + r) * 256 + k0 + k];
      sJ[idx] = mfn[(bj * 64 + r) * 256 + k0 + k];
    }
    __syncthreads();
    for (int k = 0; k < 64; ++k) {
      float a[4], c4[4];
#pragma unroll
      for (int ii = 0; ii < 4; ++ii) a[ii] = sI[((ti * 4 + ii) << 6) | (k ^ ((ti * 4 + ii) & 31))];
#pragma unroll
      for (int jj = 0; jj < 4; ++jj) c4[jj] = sJ[((tj * 4 + jj) << 6) | (k ^ ((tj * 4 + jj) & 31))];
#pragma unroll
      for (int ii = 0; ii < 4; ++ii)
#pragma unroll
        for (int jj = 0; jj < 4; ++jj) acc[ii][jj] += a[ii] * c4[jj];
    }
  }
#pragma unroll
  for (int ii = 0; ii < 4; ++ii)
#pragma unroll
    for (int jj = 0; jj < 4; ++jj)
      med[(size_t)(bi * 64 + ti * 4 + ii) * 512 + bj * 64 + tj * 4 + jj] =
          (acc[ii][jj] + 1.0f) * 0.5f;
}

__global__ void k_rowsum(const float* __restrict__ med, const float* __restrict__ T0p,
                         float* __restrict__ dinv) {
  int r = blockIdx.x, l = threadIdx.x;  // 64 threads
  float T0 = *T0p;
  float cnt = 0.f;
  for (int j = l; j < 512; j += 64) cnt += ((med[(size_t)r * 512 + j] >= T0) || (j == r)) ? 1.0f : 0.0f;
  for (int off = 32; off > 0; off >>= 1) cnt += __shfl_xor(cnt, off);
  if (l == 0) dinv[r] = rsqrtf(cnt);
}

__global__ void k_Aagg(const float* __restrict__ med, const float* __restrict__ T0p,
                       const float* __restrict__ dinv, const float* __restrict__ hrs,
                       const float* __restrict__ pool, float* __restrict__ t1,
                       float* __restrict__ t2) {
  int i = blockIdx.x, t = threadIdx.x;
  int c = t & 127, half = t >> 7;
  float T0 = *T0p;
  const float* srcm = half ? pool : hrs;
  float acc = 0.f;
  for (int j = 0; j < 512; ++j) {
    float m = med[(size_t)i * 512 + j];
    if (m >= T0 || j == i) acc += dinv[j] * srcm[j * 128 + c];
  }
  float v = acc * dinv[i];
  if (half)
    t2[i * 128 + c] = v;
  else
    t1[i * 128 + c] = v;
}

// ===================== poi2img finish =====================
__global__ void k_poi2img(const float* __restrict__ Y, const float* __restrict__ Wg_in,
                          const float* __restrict__ g0in, float* __restrict__ poi2img) {
  int b = blockIdx.x, c = threadIdx.x;  // 128 threads
  float acc = 0.f;
  for (int h = 0; h < 3; ++h) {
    const float* y = &Y[((size_t)b * 3 + h) * 128];
    for (int k = 0; k < 128; ++k) acc += y[k] * Wg_in[k * 384 + h * 128 + c];
  }
  poi2img[b * 128 + c] = acc * (1.0f / 3.0f) + g0in[c];
}

// ===================== final fc =====================
__global__ void k_final(const float* __restrict__ img2poi, const float* __restrict__ poi_agg,
                        const float* __restrict__ poi2img, const float* __restrict__ hrs_agg,
                        const float* __restrict__ Wfc, const float* __restrict__ bfc,
                        float* __restrict__ out) {
  int i = blockIdx.x * 256 + threadIdx.x;  // 8192
  int b = i >> 4, o = i & 15;
  float acc = bfc[o];
  const float* srcs[4] = {img2poi, poi_agg, poi2img, hrs_agg};
#pragma unroll
  for (int s = 0; s < 4; ++s) {
    const float* X = srcs[s] + (size_t)b * 128;
    const float* W = Wfc + (size_t)(s * 128) * 16 + o;
    for (int k = 0; k < 128; ++k) acc += X[k] * W[k * 16];
  }
  out[i] = acc;
}

// ===================== host =====================
extern "C" void kernel_launch(void* const* d_in, const int* in_sizes, int n_in,
                              void* d_out, int out_size, void* d_ws, size_t ws_size,
                              hipStream_t stream) {
  const float* poi_x = (const float*)d_in[0];
  const float* img = (const float*)d_in[1];
  const int* edges = (const int*)d_in[2];
  const float* T0p = (const float*)d_in[4];
  const float* W1 = (const float*)d_in[5];
  const float* b1 = (const float*)d_in[6];
  const float* W2 = (const float*)d_in[7];
  const float* b2 = (const float*)d_in[8];
  const float* Whrs = (const float*)d_in[9];
  const float* bhrs = (const float*)d_in[10];
  const float* Wph = (const float*)d_in[11];
  const float* bph = (const float*)d_in[12];
  const float* Wpp = (const float*)d_in[13];
  const float* bpp = (const float*)d_in[14];
  const float* Wg_in = (const float*)d_in[15];
  const float* al_in = (const float*)d_in[16];
  const float* ar_in = (const float*)d_in[17];
  const float* bg_in = (const float*)d_in[18];
  const float* Wg_w = (const float*)d_in[19];
  const float* bg_w = (const float*)d_in[22];
  const float* Wh1 = (const float*)d_in[23];
  const float* bh1 = (const float*)d_in[24];
  const float* Wp1 = (const float*)d_in[25];
  const float* bp1 = (const float*)d_in[26];
  const float* Wfc = (const float*)d_in[27];
  const float* bfc = (const float*)d_in[28];

  const int* esrc = edges;
  const int* edst = edges + EE;

  char* ws = (char*)d_ws;
  size_t off = 0;
  auto alloc = [&](size_t nbytes) -> char* {
    char* p = ws + off;
    off += (nbytes + 255) & ~(size_t)255;
    return p;
  };
  float* degf = (float*)alloc((size_t)NN * 4);
  float* nrm = (float*)alloc((size_t)NN * 4);
  int* counts = (int*)alloc(512 * 4);
  int* offs = (int*)alloc(513 * 4);
  int* cursor = (int*)alloc(512 * 4);
  uint32_t* pkd = (uint32_t*)alloc((size_t)EE * 4);
  float* h1 = (float*)alloc((size_t)NN * 128 * 4);
  float* hrs = (float*)alloc(512 * 128 * 4);
  float* ph = (float*)alloc(512 * 128 * 4);
  float* er = (float*)alloc(512 * 3 * 4);
  float* u = (float*)alloc(384 * 4);
  float* wv = (float*)alloc(384 * 4);
  float* q = (float*)alloc(384 * 4);
  float* chv = (float*)alloc(16);
  float* G = (float*)alloc(16384 * 4);
  float* g0w = (float*)alloc(128 * 4);
  float* g0in = (float*)alloc(128 * 4);
  float* pool = (float*)alloc(512 * 128 * 4);
  float* pooled = (float*)alloc((size_t)1536 * 128 * 4);
  float* Y = (float*)alloc((size_t)1536 * 128 * 4);
  float* mfn = (float*)alloc(512 * 256 * 4);
  float* dinv = (float*)alloc(512 * 4);
  float* t1b = (float*)alloc(512 * 128 * 4);
  float* t2b = (float*)alloc(512 * 128 * 4);
  float* hrs_agg = (float*)alloc(512 * 128 * 4);
  float* poi_agg = (float*)alloc(512 * 128 * 4);
  float* v_poi2img = (float*)alloc(512 * 128 * 4);
  float* v_img2poi = (float*)alloc(512 * 128 * 4);

  float* out = (float*)d_out;
  float* med = out + 512 * 16;

  hipMemsetAsync(degf, 0, (size_t)NN * 4, stream);
  hipMemsetAsync(counts, 0, 512 * 4, stream);
  hipMemsetAsync(hrs, 0, 512 * 128 * 4, stream);

  hipFuncSetAttribute((const void*)k_gcn1, hipFuncAttributeMaxDynamicSharedMemorySize, 65536);
  hipFuncSetAttribute((const void*)k_gcn2, hipFuncAttributeMaxDynamicSharedMemorySize, 70912);

  k_prep<<<1, 256, 0, stream>>>(Wg_in, al_in, ar_in, bg_in, Wpp, bpp, Wg_w, bg_w, u, wv, q, chv,
                                G, g0w, g0in);
  k_hist<<<EE / 256, 256, 0, stream>>>(esrc, edst, degf, counts);
  k_scan<<<1, 512, 0, stream>>>(counts, offs, cursor);
  k_scatter<<<EE / 256, 256, 0, stream>>>(esrc, edst, cursor, pkd);
  k_norm<<<NN / 256, 256, 0, stream>>>(degf, nrm);
  k_hrs<<<128, 256, 0, stream>>>(img, Whrs, bhrs, hrs);
  k_gcn1<<<512, 256, 65536, stream>>>(poi_x, W1, b1, nrm, pkd, offs, h1);
  k_gemm128<<<64, 256, 0, stream>>>(hrs, Wph, bph, ph);
  k_er<<<6, 256, 0, stream>>>(ph, wv, er);
  {
    // dyn LDS for gcn2: 16384 + 128 + 384 + 384 + 4 + 4 floats
    size_t dyn2 = (16384 + 128 + 384 + 384 + 4 + 4) * sizeof(float);
    k_gcn2<<<512, 256, dyn2, stream>>>(h1, W2, b2, nrm, pkd, offs, q, chv, er, pool, pooled);
  }
  k_mfn<<<512, 64, 0, stream>>>(hrs, pool, mfn);
  k_med<<<64, 256, 0, stream>>>(mfn, med);
  k_rowsum<<<512, 64, 0, stream>>>(med, T0p, dinv);
  k_Aagg<<<512, 256, 0, stream>>>(med, T0p, dinv, hrs, pool, t1b, t2b);
  k_gemm128<<<64, 256, 0, stream>>>(t1b, Wh1, bh1, hrs_agg);
  k_gemm128<<<64, 256, 0, stream>>>(t2b, Wp1, bp1, poi_agg);
  k_gemm128<<<192, 256, 0, stream>>>(pooled, Wpp, bpp, Y);
  k_poi2img<<<512, 128, 0, stream>>>(Y, Wg_in, g0in, v_poi2img);
  k_gemm128<<<64, 256, 0, stream>>>(ph, G, g0w, v_img2poi);
  k_final<<<32, 256, 0, stream>>>(v_img2poi, poi_agg, v_poi2img, hrs_agg, Wfc, bfc, out);

  (void)in_sizes; (void)n_in; (void)out_size; (void)ws_size;
}

// Round 2
// 1196.188 us; speedup vs baseline: 1.0018x; 1.0018x over previous
//
#include <hip/hip_runtime.h>
#include <stdint.h>

#define NN 65536
#define EE 524288
#define BB 512

// ===================== graph prep =====================
__global__ void k_hist(const int* __restrict__ src, const int* __restrict__ dst,
                       float* __restrict__ degf, int* __restrict__ counts) {
  int e = blockIdx.x * 256 + threadIdx.x;
  if (e >= EE) return;
  atomicAdd(&degf[dst[e]], 1.0f);
  atomicAdd(&counts[src[e] >> 7], 1);
}

__global__ void k_scan(const int* __restrict__ counts, int* __restrict__ offs,
                       int* __restrict__ cursor) {
  __shared__ int s[512];
  int t = threadIdx.x;
  s[t] = counts[t];
  __syncthreads();
  for (int d = 1; d < 512; d <<= 1) {
    int v = (t >= d) ? s[t - d] : 0;
    __syncthreads();
    s[t] += v;
    __syncthreads();
  }
  int excl = (t == 0) ? 0 : s[t - 1];
  offs[t] = excl;
  cursor[t] = excl;
  if (t == 511) offs[512] = s[511];
}

__global__ void k_scatter(const int* __restrict__ src, const int* __restrict__ dst,
                          int* __restrict__ cursor, uint32_t* __restrict__ pk) {
  int e = blockIdx.x * 256 + threadIdx.x;
  if (e >= EE) return;
  int s = src[e], d = dst[e];
  int slot = atomicAdd(&cursor[s >> 7], 1);
  pk[slot] = (uint32_t)(s & 127) | ((uint32_t)(d & 127) << 8);
}

__global__ void k_norm(const float* __restrict__ degf, float* __restrict__ nrm) {
  int i = blockIdx.x * 256 + threadIdx.x;
  nrm[i] = rsqrtf(degf[i] + 1.0f);
}

// ===================== weight prep (GAT folding) =====================
__global__ void k_prep(const float* __restrict__ Wg_in, const float* __restrict__ al_in,
                       const float* __restrict__ ar_in, const float* __restrict__ bg_in,
                       const float* __restrict__ Wpp, const float* __restrict__ bpp,
                       const float* __restrict__ Wg_w, const float* __restrict__ bg_w,
                       float* __restrict__ u, float* __restrict__ wv, float* __restrict__ q,
                       float* __restrict__ ch, float* __restrict__ G,
                       float* __restrict__ g0w, float* __restrict__ g0in) {
  int t = threadIdx.x;
  for (int i = t; i < 384; i += 256) {
    int h = i >> 7, k = i & 127;
    float su = 0.f, sw = 0.f;
    for (int c = 0; c < 128; ++c) {
      float g = Wg_in[k * 384 + h * 128 + c];
      su += g * al_in[h * 128 + c];
      sw += g * ar_in[h * 128 + c];
    }
    u[i] = su;
    wv[i] = sw;
  }
  __syncthreads();
  for (int i = t; i < 384; i += 256) {
    int h = i >> 7, j = i & 127;
    float s = 0.f;
    for (int k = 0; k < 128; ++k) s += Wpp[j * 128 + k] * u[h * 128 + k];
    q[i] = s;
  }
  if (t < 3) {
    float s = 0.f;
    for (int k = 0; k < 128; ++k) s += bpp[k] * u[t * 128 + k];
    ch[t] = s;
  }
  for (int i = t; i < 16384; i += 256) {
    int k = i >> 7, c = i & 127;
    G[i] = (Wg_w[k * 384 + c] + Wg_w[k * 384 + 128 + c] + Wg_w[k * 384 + 256 + c]) * (1.0f / 3.0f);
  }
  if (t < 128) {
    g0w[t] = (bg_w[t] + bg_w[128 + t] + bg_w[256 + t]) * (1.0f / 3.0f);
    g0in[t] = (bg_in[t] + bg_in[128 + t] + bg_in[256 + t]) * (1.0f / 3.0f);
  }
}

// ===================== hrs encoder =====================
__global__ void k_hrs(const float* __restrict__ img, const float* __restrict__ Whrs,
                      const float* __restrict__ bhrs, float* __restrict__ hrs) {
  __shared__ float sI[8 * 1024];
  int bb = blockIdx.x >> 1, kh = blockIdx.x & 1;
  int t = threadIdx.x;
  int r0 = bb * 8;
  for (int i = t; i < 8192; i += 256) {
    int r = i >> 10, k = i & 1023;
    sI[i] = img[(size_t)(r0 + r) * 2048 + kh * 1024 + k];
  }
  __syncthreads();
  int c = t & 127, rh = t >> 7;
  float a0 = 0.f, a1 = 0.f, a2 = 0.f, a3 = 0.f;
  const float* W = Whrs + (size_t)kh * 1024 * 128 + c;
  const float* s0 = sI + (rh * 4 + 0) * 1024;
  const float* s1 = sI + (rh * 4 + 1) * 1024;
  const float* s2 = sI + (rh * 4 + 2) * 1024;
  const float* s3 = sI + (rh * 4 + 3) * 1024;
  for (int k = 0; k < 1024; ++k) {
    float w = W[(size_t)k * 128];
    a0 += s0[k] * w;
    a1 += s1[k] * w;
    a2 += s2[k] * w;
    a3 += s3[k] * w;
  }
  float bias = (kh == 0) ? bhrs[c] : 0.f;
  int rb = r0 + rh * 4;
  atomicAdd(&hrs[(rb + 0) * 128 + c], a0 + bias);
  atomicAdd(&hrs[(rb + 1) * 128 + c], a1 + bias);
  atomicAdd(&hrs[(rb + 2) * 128 + c], a2 + bias);
  atomicAdd(&hrs[(rb + 3) * 128 + c], a3 + bias);
}

// ===================== generic C[M,128] = X[M,128] @ W[128,128] + bias =====================
__global__ void k_gemm128(const float* __restrict__ X, const float* __restrict__ W,
                          const float* __restrict__ bias, float* __restrict__ C) {
  __shared__ float sX[8 * 128];
  int r0 = blockIdx.x * 8;
  int t = threadIdx.x;
  for (int i = t; i < 1024; i += 256) sX[i] = X[(size_t)r0 * 128 + i];
  __syncthreads();
  int c = t & 127, rh = t >> 7;
  float b = bias[c];
  float a0 = b, a1 = b, a2 = b, a3 = b;
  const float* s = sX + (rh * 4) * 128;
  for (int k = 0; k < 128; ++k) {
    float w = W[k * 128 + c];
    a0 += s[k] * w;
    a1 += s[128 + k] * w;
    a2 += s[256 + k] * w;
    a3 += s[384 + k] * w;
  }
  int rb = r0 + rh * 4;
  C[(size_t)(rb + 0) * 128 + c] = a0;
  C[(size_t)(rb + 1) * 128 + c] = a1;
  C[(size_t)(rb + 2) * 128 + c] = a2;
  C[(size_t)(rb + 3) * 128 + c] = a3;
}

// ===================== er[b,h] = ph[b] . wv_h =====================
__global__ void k_er(const float* __restrict__ ph, const float* __restrict__ wv,
                     float* __restrict__ er) {
  int i = blockIdx.x * 256 + threadIdx.x;
  if (i >= BB * 3) return;
  int b = i / 3, h = i % 3;
  float s = 0.f;
  for (int k = 0; k < 128; ++k) s += ph[b * 128 + k] * wv[h * 128 + k];
  er[i] = s;
}

// ===================== FUSED 2-layer GCN + pool + GAT-in softmax (one block per parcel) ======
// LDS plan (floats):
//   sH   [16384]  : layer-1 output h1*norm (swizzled [128][128]), later poi_node
//   sAgg [16384]  : phase 1: sX [128][64] + sAcc [128][64]; phase 2: agg accumulator [128][128]
//   sNorm[128], sQ[384], sAl[384], sEr[4], sCh[4], sPool[128]
__global__ void __launch_bounds__(512) k_gcn_fused(
    const float* __restrict__ x, const float* __restrict__ W1, const float* __restrict__ b1,
    const float* __restrict__ W2, const float* __restrict__ b2,
    const float* __restrict__ nrm, const uint32_t* __restrict__ pk,
    const int* __restrict__ offs, const float* __restrict__ q, const float* __restrict__ ch,
    const float* __restrict__ er, float* __restrict__ poi_pool, float* __restrict__ pooled) {
  extern __shared__ float sm[];
  float* sH = sm;               // 16384
  float* sAgg = sm + 16384;     // 16384
  float* sNorm = sm + 32768;    // 128
  float* sQ = sNorm + 128;      // 384
  float* sAl = sQ + 384;        // 384
  float* sEr = sAl + 384;       // 4
  float* sCh = sEr + 4;         // 4
  float* sPool = sCh + 4;       // 128
  float* sX = sAgg;             // [128][64] swizzled
  float* sAcc = sAgg + 8192;    // [128][64] swizzled

  int b = blockIdx.x, t = threadIdx.x;
  int base = b << 7;
  if (t < 128) {
    sNorm[t] = nrm[base + t];
    sPool[t] = 0.f;
  }
  for (int i = t; i < 384; i += 512) sQ[i] = q[i];
  if (t < 3) {
    sEr[t] = er[b * 3 + t];
    sCh[t] = ch[t];
  }
  __syncthreads();

  // ---- load x * norm into sX and sAcc (self loop) ----
  for (int i = t; i < 8192; i += 512) {
    int r = i >> 6, k = i & 63;
    float v = x[(size_t)(base + r) * 64 + k] * sNorm[r];
    int idx = (r << 6) | (k ^ (r & 31));
    sX[idx] = v;
    sAcc[idx] = v;
  }
  __syncthreads();

  int e0 = offs[b], e1 = offs[b + 1];
  int wave = t >> 6, lane = t & 63;

  // ---- edge pass 1 (64-wide features) ----
  for (int e = e0 + wave; e < e1; e += 8) {
    uint32_t p = pk[e];
    int ls = p & 127, ld = (p >> 8) & 127;
    float v = sX[(ls << 6) | (lane ^ (ls & 31))];
    atomicAdd(&sAcc[(ld << 6) | (lane ^ (ld & 31))], v);
  }
  __syncthreads();
  for (int i = t; i < 8192; i += 512) sAcc[i] *= sNorm[i >> 6];
  __syncthreads();

  // ---- matmul 1: h1 = relu(sAcc[128,64] @ W1[64,128] + b1); store h1*norm into sH ----
  int rg = t >> 4, cg = t & 15;
  int r0 = rg * 4, c0 = cg * 8;
  {
    float acc[4][8];
#pragma unroll
    for (int j = 0; j < 8; ++j) {
      float bv = b1[c0 + j];
#pragma unroll
      for (int i = 0; i < 4; ++i) acc[i][j] = bv;
    }
    for (int k = 0; k < 64; ++k) {
      float a[4];
#pragma unroll
      for (int i = 0; i < 4; ++i) a[i] = sAcc[((r0 + i) << 6) | (k ^ ((r0 + i) & 31))];
      float4 w0 = *(const float4*)(&W1[k * 128 + c0]);
      float4 w1 = *(const float4*)(&W1[k * 128 + c0 + 4]);
      float w[8] = {w0.x, w0.y, w0.z, w0.w, w1.x, w1.y, w1.z, w1.w};
#pragma unroll
      for (int i = 0; i < 4; ++i)
#pragma unroll
        for (int j = 0; j < 8; ++j) acc[i][j] += a[i] * w[j];
    }
#pragma unroll
    for (int i = 0; i < 4; ++i) {
      int r = r0 + i;
      float ns = sNorm[r];
#pragma unroll
      for (int j = 0; j < 8; ++j)
        sH[(r << 7) | ((c0 + j) ^ (r & 31))] = fmaxf(acc[i][j], 0.f) * ns;
    }
  }
  __syncthreads();  // sAcc reads done; sH complete

  // ---- init agg = sH (self loop), overwriting sX/sAcc region ----
  for (int i = t; i < 16384; i += 512) sAgg[i] = sH[i];
  __syncthreads();

  // ---- edge pass 2 (128-wide features, all LDS) ----
  for (int e = e0 + wave; e < e1; e += 8) {
    uint32_t p = pk[e];
    int ls = p & 127, ld = (p >> 8) & 127;
    float v0 = sH[(ls << 7) | (lane ^ (ls & 31))];
    float v1 = sH[(ls << 7) | ((lane + 64) ^ (ls & 31))];
    atomicAdd(&sAgg[(ld << 7) | (lane ^ (ld & 31))], v0);
    atomicAdd(&sAgg[(ld << 7) | ((lane + 64) ^ (ld & 31))], v1);
  }
  __syncthreads();
  for (int i = t; i < 16384; i += 512) sAgg[i] *= sNorm[i >> 7];
  __syncthreads();

  // ---- matmul 2: poi_node = sAgg[128,128] @ W2[128,128] + b2 -> overwrite sH ----
  {
    float acc[4][8];
#pragma unroll
    for (int j = 0; j < 8; ++j) {
      float bv = b2[c0 + j];
#pragma unroll
      for (int i = 0; i < 4; ++i) acc[i][j] = bv;
    }
    for (int k = 0; k < 128; ++k) {
      float a[4];
#pragma unroll
      for (int i = 0; i < 4; ++i) a[i] = sAgg[((r0 + i) << 7) | (k ^ ((r0 + i) & 31))];
      float4 w0 = *(const float4*)(&W2[k * 128 + c0]);
      float4 w1 = *(const float4*)(&W2[k * 128 + c0 + 4]);
      float w[8] = {w0.x, w0.y, w0.z, w0.w, w1.x, w1.y, w1.z, w1.w};
#pragma unroll
      for (int i = 0; i < 4; ++i)
#pragma unroll
        for (int j = 0; j < 8; ++j) acc[i][j] += a[i] * w[j];
    }
    __syncthreads();  // all sH (edge pass) reads complete before overwrite
#pragma unroll
    for (int i = 0; i < 4; ++i) {
      int r = r0 + i;
#pragma unroll
      for (int j = 0; j < 8; ++j) sH[(r << 7) | ((c0 + j) ^ (r & 31))] = acc[i][j];
    }
  }
  __syncthreads();

  // ---- poi_pool partial col sums (all 512 threads) ----
  {
    int c = t & 127, qd = t >> 7;
    float s = 0.f;
    for (int rr = 0; rr < 32; ++rr) {
      int r = qd * 32 + rr;
      s += sH[(r << 7) | (c ^ (r & 31))];
    }
    atomicAdd(&sPool[c], s);
  }
  __syncthreads();
  if (t < 128) poi_pool[b * 128 + t] = sPool[t] * (1.0f / 128.0f);

  // ---- el per (row, head) ----
  if (t < 384) {
    int r = t & 127, h = t >> 7;
    float d = 0.f;
    const float* qh = &sQ[h * 128];
    for (int c = 0; c < 128; ++c) d += sH[(r << 7) | (c ^ (r & 31))] * qh[c];
    float e = d + sCh[h] + sEr[h];
    sAl[h * 128 + r] = (e > 0.f) ? e : 0.2f * e;
  }
  __syncthreads();

  // ---- per-head softmax over 128 pois (one wave per head) ----
  if (t < 192) {
    int h = t >> 6, l = t & 63;
    float v0 = sAl[h * 128 + l], v1 = sAl[h * 128 + 64 + l];
    float m = fmaxf(v0, v1);
    for (int off = 32; off > 0; off >>= 1) m = fmaxf(m, __shfl_xor(m, off));
    float x0 = __expf(v0 - m), x1 = __expf(v1 - m);
    float s = x0 + x1;
    for (int off = 32; off > 0; off >>= 1) s += __shfl_xor(s, off);
    float inv = 1.0f / s;
    sAl[h * 128 + l] = x0 * inv;
    sAl[h * 128 + 64 + l] = x1 * inv;
  }
  __syncthreads();

  // ---- pooled[b,h,:] = sum_r alpha[r,h] * poi_node[r,:] ----
  if (t < 384) {
    int hh = t >> 7, c = t & 127;
    float s = 0.f;
    const float* al = &sAl[hh * 128];
    for (int r = 0; r < 128; ++r) s += al[r] * sH[(r << 7) | (c ^ (r & 31))];
    pooled[((size_t)b * 3 + hh) * 128 + c] = s;
  }
}

// ===================== med pipeline =====================
__global__ void k_mfn(const float* __restrict__ hrs, const float* __restrict__ pool,
                      float* __restrict__ mfn) {
  int r = blockIdx.x, l = threadIdx.x;  // 64 threads
  float v0 = hrs[r * 128 + l], v1 = hrs[r * 128 + 64 + l];
  float v2 = pool[r * 128 + l], v3 = pool[r * 128 + 64 + l];
  float ss = v0 * v0 + v1 * v1 + v2 * v2 + v3 * v3;
  for (int off = 32; off > 0; off >>= 1) ss += __shfl_xor(ss, off);
  float rn = rsqrtf(ss);
  mfn[r * 256 + l] = v0 * rn;
  mfn[r * 256 + 64 + l] = v1 * rn;
  mfn[r * 256 + 128 + l] = v2 * rn;
  mfn[r * 256 + 192 + l] = v3 * rn;
}

__global__ void k_med(const float* __restrict__ mfn, float* __restrict__ med) {
  __shared__ float sI[64 * 64];
  __shared__ float sJ[64 * 64];
  int bi = blockIdx.x >> 3, bj = blockIdx.x & 7;
  int t = threadIdx.x;
  int ti = t >> 4, tj = t & 15;
  float acc[4][4] = {};
  for (int k0 = 0; k0 < 256; k0 += 64) {
    __syncthreads();
    for (int i = t; i < 4096; i += 256) {
      int r = i >> 6, k = i & 63;
      int idx = (r << 6) | (k ^ (r & 31));
      sI[idx] = mfn[(bi * 64 + r) * 256 + k0 + k];
      sJ[idx] = mfn[(bj * 64 + r) * 256 + k0 + k];
    }
    __syncthreads();
    for (int k = 0; k < 64; ++k) {
      float a[4], c4[4];
#pragma unroll
      for (int ii = 0; ii < 4; ++ii) a[ii] = sI[((ti * 4 + ii) << 6) | (k ^ ((ti * 4 + ii) & 31))];
#pragma unroll
      for (int jj = 0; jj < 4; ++jj) c4[jj] = sJ[((tj * 4 + jj) << 6) | (k ^ ((tj * 4 + jj) & 31))];
#pragma unroll
      for (int ii = 0; ii < 4; ++ii)
#pragma unroll
        for (int jj = 0; jj < 4; ++jj) acc[ii][jj] += a[ii] * c4[jj];
    }
  }
#pragma unroll
  for (int ii = 0; ii < 4; ++ii)
#pragma unroll
    for (int jj = 0; jj < 4; ++jj)
      med[(size_t)(bi * 64 + ti * 4 + ii) * 512 + bj * 64 + tj * 4 + jj] =
          (acc[ii][jj] + 1.0f) * 0.5f;
}

__global__ void k_rowsum(const float* __restrict__ med, const float* __restrict__ T0p,
                         float* __restrict__ dinv) {
  int r = blockIdx.x, l = threadIdx.x;  // 64 threads
  float T0 = *T0p;
  float cnt = 0.f;
  for (int j = l; j < 512; j += 64) cnt += ((med[(size_t)r * 512 + j] >= T0) || (j == r)) ? 1.0f : 0.0f;
  for (int off = 32; off > 0; off >>= 1) cnt += __shfl_xor(cnt, off);
  if (l == 0) dinv[r] = rsqrtf(cnt);
}

__global__ void k_Aagg(const float* __restrict__ med, const float* __restrict__ T0p,
                       const float* __restrict__ dinv, const float* __restrict__ hrs,
                       const float* __restrict__ pool, float* __restrict__ t1,
                       float* __restrict__ t2) {
  int i = blockIdx.x, t = threadIdx.x;
  int c = t & 127, half = t >> 7;
  float T0 = *T0p;
  const float* srcm = half ? pool : hrs;
  float acc = 0.f;
  for (int j = 0; j < 512; ++j) {
    float m = med[(size_t)i * 512 + j];
    if (m >= T0 || j == i) acc += dinv[j] * srcm[j * 128 + c];
  }
  float v = acc * dinv[i];
  if (half)
    t2[i * 128 + c] = v;
  else
    t1[i * 128 + c] = v;
}

// ===================== poi2img finish =====================
__global__ void k_poi2img(const float* __restrict__ Y, const float* __restrict__ Wg_in,
                          const float* __restrict__ g0in, float* __restrict__ poi2img) {
  int b = blockIdx.x, c = threadIdx.x;  // 128 threads
  float acc = 0.f;
  for (int h = 0; h < 3; ++h) {
    const float* y = &Y[((size_t)b * 3 + h) * 128];
    for (int k = 0; k < 128; ++k) acc += y[k] * Wg_in[k * 384 + h * 128 + c];
  }
  poi2img[b * 128 + c] = acc * (1.0f / 3.0f) + g0in[c];
}

// ===================== final fc =====================
__global__ void k_final(const float* __restrict__ img2poi, const float* __restrict__ poi_agg,
                        const float* __restrict__ poi2img, const float* __restrict__ hrs_agg,
                        const float* __restrict__ Wfc, const float* __restrict__ bfc,
                        float* __restrict__ out) {
  int i = blockIdx.x * 256 + threadIdx.x;  // 8192
  int b = i >> 4, o = i & 15;
  float acc = bfc[o];
  const float* srcs[4] = {img2poi, poi_agg, poi2img, hrs_agg};
#pragma unroll
  for (int s = 0; s < 4; ++s) {
    const float* X = srcs[s] + (size_t)b * 128;
    const float* W = Wfc + (size_t)(s * 128) * 16 + o;
    for (int k = 0; k < 128; ++k) acc += X[k] * W[k * 16];
  }
  out[i] = acc;
}

// ===================== host =====================
extern "C" void kernel_launch(void* const* d_in, const int* in_sizes, int n_in,
                              void* d_out, int out_size, void* d_ws, size_t ws_size,
                              hipStream_t stream) {
  const float* poi_x = (const float*)d_in[0];
  const float* img = (const float*)d_in[1];
  const int* edges = (const int*)d_in[2];
  const float* T0p = (const float*)d_in[4];
  const float* W1 = (const float*)d_in[5];
  const float* b1 = (const float*)d_in[6];
  const float* W2 = (const float*)d_in[7];
  const float* b2 = (const float*)d_in[8];
  const float* Whrs = (const float*)d_in[9];
  const float* bhrs = (const float*)d_in[10];
  const float* Wph = (const float*)d_in[11];
  const float* bph = (const float*)d_in[12];
  const float* Wpp = (const float*)d_in[13];
  const float* bpp = (const float*)d_in[14];
  const float* Wg_in = (const float*)d_in[15];
  const float* al_in = (const float*)d_in[16];
  const float* ar_in = (const float*)d_in[17];
  const float* bg_in = (const float*)d_in[18];
  const float* Wg_w = (const float*)d_in[19];
  const float* bg_w = (const float*)d_in[22];
  const float* Wh1 = (const float*)d_in[23];
  const float* bh1 = (const float*)d_in[24];
  const float* Wp1 = (const float*)d_in[25];
  const float* bp1 = (const float*)d_in[26];
  const float* Wfc = (const float*)d_in[27];
  const float* bfc = (const float*)d_in[28];

  const int* esrc = edges;
  const int* edst = edges + EE;

  char* ws = (char*)d_ws;
  size_t off = 0;
  auto alloc = [&](size_t nbytes) -> char* {
    char* p = ws + off;
    off += (nbytes + 255) & ~(size_t)255;
    return p;
  };
  float* degf = (float*)alloc((size_t)NN * 4);
  float* nrm = (float*)alloc((size_t)NN * 4);
  int* counts = (int*)alloc(512 * 4);
  int* offs = (int*)alloc(513 * 4);
  int* cursor = (int*)alloc(512 * 4);
  uint32_t* pkd = (uint32_t*)alloc((size_t)EE * 4);
  float* hrs = (float*)alloc(512 * 128 * 4);
  float* ph = (float*)alloc(512 * 128 * 4);
  float* er = (float*)alloc(512 * 3 * 4);
  float* u = (float*)alloc(384 * 4);
  float* wv = (float*)alloc(384 * 4);
  float* q = (float*)alloc(384 * 4);
  float* chv = (float*)alloc(16);
  float* G = (float*)alloc(16384 * 4);
  float* g0w = (float*)alloc(128 * 4);
  float* g0in = (float*)alloc(128 * 4);
  float* pool = (float*)alloc(512 * 128 * 4);
  float* pooled = (float*)alloc((size_t)1536 * 128 * 4);
  float* Y = (float*)alloc((size_t)1536 * 128 * 4);
  float* mfn = (float*)alloc(512 * 256 * 4);
  float* dinv = (float*)alloc(512 * 4);
  float* t1b = (float*)alloc(512 * 128 * 4);
  float* t2b = (float*)alloc(512 * 128 * 4);
  float* hrs_agg = (float*)alloc(512 * 128 * 4);
  float* poi_agg = (float*)alloc(512 * 128 * 4);
  float* v_poi2img = (float*)alloc(512 * 128 * 4);
  float* v_img2poi = (float*)alloc(512 * 128 * 4);

  float* out = (float*)d_out;
  float* med = out + 512 * 16;

  hipMemsetAsync(degf, 0, (size_t)NN * 4, stream);
  hipMemsetAsync(counts, 0, 512 * 4, stream);
  hipMemsetAsync(hrs, 0, 512 * 128 * 4, stream);

  // fused gcn dyn LDS: 16384+16384+128+384+384+4+4+128 floats = 135200 B
  size_t dynf = (16384 + 16384 + 128 + 384 + 384 + 4 + 4 + 128) * sizeof(float);
  hipFuncSetAttribute((const void*)k_gcn_fused, hipFuncAttributeMaxDynamicSharedMemorySize,
                      (int)dynf);

  k_prep<<<1, 256, 0, stream>>>(Wg_in, al_in, ar_in, bg_in, Wpp, bpp, Wg_w, bg_w, u, wv, q, chv,
                                G, g0w, g0in);
  k_hist<<<EE / 256, 256, 0, stream>>>(esrc, edst, degf, counts);
  k_scan<<<1, 512, 0, stream>>>(counts, offs, cursor);
  k_scatter<<<EE / 256, 256, 0, stream>>>(esrc, edst, cursor, pkd);
  k_norm<<<NN / 256, 256, 0, stream>>>(degf, nrm);
  k_hrs<<<128, 256, 0, stream>>>(img, Whrs, bhrs, hrs);
  k_gemm128<<<64, 256, 0, stream>>>(hrs, Wph, bph, ph);
  k_er<<<6, 256, 0, stream>>>(ph, wv, er);
  k_gcn_fused<<<512, 512, dynf, stream>>>(poi_x, W1, b1, W2, b2, nrm, pkd, offs, q, chv, er,
                                          pool, pooled);
  k_mfn<<<512, 64, 0, stream>>>(hrs, pool, mfn);
  k_med<<<64, 256, 0, stream>>>(mfn, med);
  k_rowsum<<<512, 64, 0, stream>>>(med, T0p, dinv);
  k_Aagg<<<512, 256, 0, stream>>>(med, T0p, dinv, hrs, pool, t1b, t2b);
  k_gemm128<<<64, 256, 0, stream>>>(t1b, Wh1, bh1, hrs_agg);
  k_gemm128<<<64, 256, 0, stream>>>(t2b, Wp1, bp1, poi_agg);
  k_gemm128<<<192, 256, 0, stream>>>(pooled, Wpp, bpp, Y);
  k_poi2img<<<512, 128, 0, stream>>>(Y, Wg_in, g0in, v_poi2img);
  k_gemm128<<<64, 256, 0, stream>>>(ph, G, g0w, v_img2poi);
  k_final<<<32, 256, 0, stream>>>(v_img2poi, poi_agg, v_poi2img, hrs_agg, Wfc, bfc, out);

  (void)in_sizes; (void)n_in; (void)out_size; (void)ws_size;
}

// Round 3
// 620.715 us; speedup vs baseline: 1.9305x; 1.9271x over previous
//
#include <hip/hip_runtime.h>
#include <stdint.h>

#define NN 65536
#define EE 524288
#define BB 512
#define LIST_CAP 2048

// ===================== graph prep =====================
__global__ void k_hist(const int* __restrict__ src, const int* __restrict__ dst,
                       float* __restrict__ degf, int* __restrict__ counts) {
  int e = blockIdx.x * 256 + threadIdx.x;
  if (e >= EE) return;
  atomicAdd(&degf[dst[e]], 1.0f);
  atomicAdd(&counts[src[e] >> 7], 1);
}

__global__ void k_scan(const int* __restrict__ counts, int* __restrict__ offs) {
  __shared__ int s[512];
  int t = threadIdx.x;
  s[t] = counts[t];
  __syncthreads();
  for (int d = 1; d < 512; d <<= 1) {
    int v = (t >= d) ? s[t - d] : 0;
    __syncthreads();
    s[t] += v;
    __syncthreads();
  }
  offs[t] = (t == 0) ? 0 : s[t - 1];
  if (t == 511) offs[512] = s[511];
}

// per-node CSR offsets within each parcel + cursors
__global__ void k_nodeoff(const float* __restrict__ degf, const int* __restrict__ offs,
                          int* __restrict__ nodeoff, int* __restrict__ cursor) {
  __shared__ int s[128];
  int b = blockIdx.x, t = threadIdx.x;
  int base = b << 7;
  int d = (int)degf[base + t];
  s[t] = d;
  __syncthreads();
  for (int dd = 1; dd < 128; dd <<= 1) {
    int v = (t >= dd) ? s[t - dd] : 0;
    __syncthreads();
    s[t] += v;
    __syncthreads();
  }
  int excl = s[t] - d + offs[b];
  nodeoff[base + t] = excl;
  cursor[base + t] = excl;
}

__global__ void k_scatter(const int* __restrict__ src, const int* __restrict__ dst,
                          int* __restrict__ cursor, uint8_t* __restrict__ list8) {
  int e = blockIdx.x * 256 + threadIdx.x;
  if (e >= EE) return;
  int s = src[e], d = dst[e];
  int slot = atomicAdd(&cursor[d], 1);
  list8[slot] = (uint8_t)(s & 127);
}

// ===================== weight prep (GAT folding) =====================
__global__ void k_prep(const float* __restrict__ Wg_in, const float* __restrict__ al_in,
                       const float* __restrict__ ar_in, const float* __restrict__ bg_in,
                       const float* __restrict__ Wpp, const float* __restrict__ bpp,
                       const float* __restrict__ Wg_w, const float* __restrict__ bg_w,
                       float* __restrict__ u, float* __restrict__ wv, float* __restrict__ q,
                       float* __restrict__ ch, float* __restrict__ G,
                       float* __restrict__ g0w, float* __restrict__ g0in) {
  int t = threadIdx.x;
  for (int i = t; i < 384; i += 256) {
    int h = i >> 7, k = i & 127;
    float su = 0.f, sw = 0.f;
#pragma unroll 4
    for (int c = 0; c < 128; ++c) {
      float g = Wg_in[k * 384 + h * 128 + c];
      su += g * al_in[h * 128 + c];
      sw += g * ar_in[h * 128 + c];
    }
    u[i] = su;
    wv[i] = sw;
  }
  __syncthreads();
  for (int i = t; i < 384; i += 256) {
    int h = i >> 7, j = i & 127;
    float s = 0.f;
#pragma unroll 4
    for (int k = 0; k < 128; ++k) s += Wpp[j * 128 + k] * u[h * 128 + k];
    q[i] = s;
  }
  if (t < 3) {
    float s = 0.f;
#pragma unroll 4
    for (int k = 0; k < 128; ++k) s += bpp[k] * u[t * 128 + k];
    ch[t] = s;
  }
  for (int i = t; i < 16384; i += 256) {
    int k = i >> 7, c = i & 127;
    G[i] = (Wg_w[k * 384 + c] + Wg_w[k * 384 + 128 + c] + Wg_w[k * 384 + 256 + c]) * (1.0f / 3.0f);
  }
  if (t < 128) {
    g0w[t] = (bg_w[t] + bg_w[128 + t] + bg_w[256 + t]) * (1.0f / 3.0f);
    g0in[t] = (bg_in[t] + bg_in[128 + t] + bg_in[256 + t]) * (1.0f / 3.0f);
  }
}

// ===================== hrs encoder =====================
__global__ void k_hrs(const float* __restrict__ img, const float* __restrict__ Whrs,
                      const float* __restrict__ bhrs, float* __restrict__ hrs) {
  __shared__ float sI[8 * 1024];
  int bb = blockIdx.x >> 1, kh = blockIdx.x & 1;
  int t = threadIdx.x;
  int r0 = bb * 8;
  for (int i = t; i < 8192; i += 256) {
    int r = i >> 10, k = i & 1023;
    sI[i] = img[(size_t)(r0 + r) * 2048 + kh * 1024 + k];
  }
  __syncthreads();
  int c = t & 127, rh = t >> 7;
  float a0 = 0.f, a1 = 0.f, a2 = 0.f, a3 = 0.f;
  const float* W = Whrs + (size_t)kh * 1024 * 128 + c;
  const float* s0 = sI + (rh * 4 + 0) * 1024;
  const float* s1 = sI + (rh * 4 + 1) * 1024;
  const float* s2 = sI + (rh * 4 + 2) * 1024;
  const float* s3 = sI + (rh * 4 + 3) * 1024;
  for (int k = 0; k < 1024; ++k) {
    float w = W[(size_t)k * 128];
    a0 += s0[k] * w;
    a1 += s1[k] * w;
    a2 += s2[k] * w;
    a3 += s3[k] * w;
  }
  float bias = (kh == 0) ? bhrs[c] : 0.f;
  int rb = r0 + rh * 4;
  atomicAdd(&hrs[(rb + 0) * 128 + c], a0 + bias);
  atomicAdd(&hrs[(rb + 1) * 128 + c], a1 + bias);
  atomicAdd(&hrs[(rb + 2) * 128 + c], a2 + bias);
  atomicAdd(&hrs[(rb + 3) * 128 + c], a3 + bias);
}

// ===================== generic C[M,128] = X[M,128] @ W[128,128] + bias =====================
__global__ void k_gemm128(const float* __restrict__ X, const float* __restrict__ W,
                          const float* __restrict__ bias, float* __restrict__ C) {
  __shared__ float sX[8 * 128];
  int r0 = blockIdx.x * 8;
  int t = threadIdx.x;
  for (int i = t; i < 1024; i += 256) sX[i] = X[(size_t)r0 * 128 + i];
  __syncthreads();
  int c = t & 127, rh = t >> 7;
  float b = bias[c];
  float a0 = b, a1 = b, a2 = b, a3 = b;
  const float* s = sX + (rh * 4) * 128;
  for (int k = 0; k < 128; ++k) {
    float w = W[k * 128 + c];
    a0 += s[k] * w;
    a1 += s[128 + k] * w;
    a2 += s[256 + k] * w;
    a3 += s[384 + k] * w;
  }
  int rb = r0 + rh * 4;
  C[(size_t)(rb + 0) * 128 + c] = a0;
  C[(size_t)(rb + 1) * 128 + c] = a1;
  C[(size_t)(rb + 2) * 128 + c] = a2;
  C[(size_t)(rb + 3) * 128 + c] = a3;
}

// ===================== er[b,h] = ph[b] . wv_h =====================
__global__ void k_er(const float* __restrict__ ph, const float* __restrict__ wv,
                     float* __restrict__ er) {
  int i = blockIdx.x * 256 + threadIdx.x;
  if (i >= BB * 3) return;
  int b = i / 3, h = i % 3;
  float s = 0.f;
#pragma unroll 4
  for (int k = 0; k < 128; ++k) s += ph[b * 128 + k] * wv[h * 128 + k];
  er[i] = s;
}

// ===================== gather edge passes (no atomics) =====================
template <bool STG>
__device__ __forceinline__ void pass64(const float* sX, float* sAcc, const float* sNorm,
                                       const int* sRow, const uint8_t* sList,
                                       const uint8_t* glist, int wave, int lane) {
  for (int r = wave; r < 128; r += 8) {
    int beg = sRow[r], end = sRow[r + 1];
    float a0 = sX[(r << 6) | (lane ^ (r & 31))];
    int e = beg;
    for (; e + 1 < end; e += 2) {
      int l0 = STG ? (int)sList[e] : (int)glist[e];
      int l1 = STG ? (int)sList[e + 1] : (int)glist[e + 1];
      a0 += sX[(l0 << 6) | (lane ^ (l0 & 31))];
      a0 += sX[(l1 << 6) | (lane ^ (l1 & 31))];
    }
    if (e < end) {
      int l0 = STG ? (int)sList[e] : (int)glist[e];
      a0 += sX[(l0 << 6) | (lane ^ (l0 & 31))];
    }
    sAcc[(r << 6) | (lane ^ (r & 31))] = a0 * sNorm[r];
  }
}

template <bool STG>
__device__ __forceinline__ void pass128(const float* sH, float* sAgg, const float* sNorm,
                                        const int* sRow, const uint8_t* sList,
                                        const uint8_t* glist, int wave, int lane) {
  for (int r = wave; r < 128; r += 8) {
    int beg = sRow[r], end = sRow[r + 1];
    float a0 = sH[(r << 7) | (lane ^ (r & 31))];
    float a1 = sH[(r << 7) | ((lane + 64) ^ (r & 31))];
    int e = beg;
    for (; e + 1 < end; e += 2) {
      int l0 = STG ? (int)sList[e] : (int)glist[e];
      int l1 = STG ? (int)sList[e + 1] : (int)glist[e + 1];
      a0 += sH[(l0 << 7) | (lane ^ (l0 & 31))];
      a1 += sH[(l0 << 7) | ((lane + 64) ^ (l0 & 31))];
      a0 += sH[(l1 << 7) | (lane ^ (l1 & 31))];
      a1 += sH[(l1 << 7) | ((lane + 64) ^ (l1 & 31))];
    }
    if (e < end) {
      int l0 = STG ? (int)sList[e] : (int)glist[e];
      a0 += sH[(l0 << 7) | (lane ^ (l0 & 31))];
      a1 += sH[(l0 << 7) | ((lane + 64) ^ (l0 & 31))];
    }
    float ns = sNorm[r];
    sAgg[(r << 7) | (lane ^ (r & 31))] = a0 * ns;
    sAgg[(r << 7) | ((lane + 64) ^ (r & 31))] = a1 * ns;
  }
}

// ===================== FUSED 2-layer GCN + pool + GAT-in softmax (one block per parcel) ======
__global__ void __launch_bounds__(512) k_gcn_fused(
    const float* __restrict__ x, const float* __restrict__ W1, const float* __restrict__ b1,
    const float* __restrict__ W2, const float* __restrict__ b2,
    const float* __restrict__ degf, const uint8_t* __restrict__ g_list,
    const int* __restrict__ nodeoff, const int* __restrict__ offs,
    const float* __restrict__ q, const float* __restrict__ ch, const float* __restrict__ er,
    float* __restrict__ poi_pool, float* __restrict__ pooled) {
  extern __shared__ float sm[];
  float* sH = sm;                // 16384
  float* sAgg = sm + 16384;      // 16384
  float* sNorm = sm + 32768;     // 128
  float* sQ = sNorm + 128;       // 384
  float* sAl = sQ + 384;         // 384
  float* sEr = sAl + 384;        // 4
  float* sCh = sEr + 4;          // 4
  float* sPool = sCh + 4;        // 128
  int* sRow = (int*)(sPool + 128);            // 132
  uint8_t* sList = (uint8_t*)(sRow + 132);    // 2048 B
  float* sX = sAgg;              // [128][64] swizzled
  float* sAcc = sAgg + 8192;     // [128][64] swizzled

  int b = blockIdx.x, t = threadIdx.x;
  int base = b << 7;
  int e0 = offs[b], e1 = offs[b + 1];
  int cnt = e1 - e0;
  if (t < 128) {
    sNorm[t] = rsqrtf(degf[base + t] + 1.0f);
    sPool[t] = 0.f;
    sRow[t] = nodeoff[base + t] - e0;
  }
  if (t == 128) sRow[128] = cnt;
  for (int i = t; i < 384; i += 512) sQ[i] = q[i];
  if (t < 3) {
    sEr[t] = er[b * 3 + t];
    sCh[t] = ch[t];
  }
  int scnt = cnt < LIST_CAP ? cnt : LIST_CAP;
  for (int i = t; i < scnt; i += 512) sList[i] = g_list[e0 + i];
  __syncthreads();

  // ---- load x * norm into sX (self values) ----
  for (int i = t; i < 8192; i += 512) {
    int r = i >> 6, k = i & 63;
    float v = x[(size_t)(base + r) * 64 + k] * sNorm[r];
    sX[(r << 6) | (k ^ (r & 31))] = v;
  }
  __syncthreads();

  int wave = t >> 6, lane = t & 63;

  // ---- edge pass 1 (gather, 64-wide) ----
  if (cnt <= LIST_CAP)
    pass64<true>(sX, sAcc, sNorm, sRow, sList, g_list + e0, wave, lane);
  else
    pass64<false>(sX, sAcc, sNorm, sRow, sList, g_list + e0, wave, lane);
  __syncthreads();

  // ---- matmul 1: h1 = relu(sAcc[128,64] @ W1[64,128] + b1); store h1*norm into sH ----
  int rg = t >> 4, cg = t & 15;
  int r0 = rg * 4, c0 = cg * 8;
  {
    float acc[4][8];
#pragma unroll
    for (int j = 0; j < 8; ++j) {
      float bv = b1[c0 + j];
#pragma unroll
      for (int i = 0; i < 4; ++i) acc[i][j] = bv;
    }
    for (int k = 0; k < 64; ++k) {
      float a[4];
#pragma unroll
      for (int i = 0; i < 4; ++i) a[i] = sAcc[((r0 + i) << 6) | (k ^ ((r0 + i) & 31))];
      float4 w0 = *(const float4*)(&W1[k * 128 + c0]);
      float4 w1 = *(const float4*)(&W1[k * 128 + c0 + 4]);
      float w[8] = {w0.x, w0.y, w0.z, w0.w, w1.x, w1.y, w1.z, w1.w};
#pragma unroll
      for (int i = 0; i < 4; ++i)
#pragma unroll
        for (int j = 0; j < 8; ++j) acc[i][j] += a[i] * w[j];
    }
#pragma unroll
    for (int i = 0; i < 4; ++i) {
      int r = r0 + i;
      float ns = sNorm[r];
#pragma unroll
      for (int j = 0; j < 8; ++j)
        sH[(r << 7) | ((c0 + j) ^ (r & 31))] = fmaxf(acc[i][j], 0.f) * ns;
    }
  }
  __syncthreads();

  // ---- edge pass 2 (gather, 128-wide) ----
  if (cnt <= LIST_CAP)
    pass128<true>(sH, sAgg, sNorm, sRow, sList, g_list + e0, wave, lane);
  else
    pass128<false>(sH, sAgg, sNorm, sRow, sList, g_list + e0, wave, lane);
  __syncthreads();

  // ---- matmul 2: poi_node = sAgg[128,128] @ W2[128,128] + b2 -> overwrite sH ----
  {
    float acc[4][8];
#pragma unroll
    for (int j = 0; j < 8; ++j) {
      float bv = b2[c0 + j];
#pragma unroll
      for (int i = 0; i < 4; ++i) acc[i][j] = bv;
    }
    for (int k = 0; k < 128; ++k) {
      float a[4];
#pragma unroll
      for (int i = 0; i < 4; ++i) a[i] = sAgg[((r0 + i) << 7) | (k ^ ((r0 + i) & 31))];
      float4 w0 = *(const float4*)(&W2[k * 128 + c0]);
      float4 w1 = *(const float4*)(&W2[k * 128 + c0 + 4]);
      float w[8] = {w0.x, w0.y, w0.z, w0.w, w1.x, w1.y, w1.z, w1.w};
#pragma unroll
      for (int i = 0; i < 4; ++i)
#pragma unroll
        for (int j = 0; j < 8; ++j) acc[i][j] += a[i] * w[j];
    }
    __syncthreads();
#pragma unroll
    for (int i = 0; i < 4; ++i) {
      int r = r0 + i;
#pragma unroll
      for (int j = 0; j < 8; ++j) sH[(r << 7) | ((c0 + j) ^ (r & 31))] = acc[i][j];
    }
  }
  __syncthreads();

  // ---- poi_pool partial col sums ----
  {
    int c = t & 127, qd = t >> 7;
    float s = 0.f;
    for (int rr = 0; rr < 32; ++rr) {
      int r = qd * 32 + rr;
      s += sH[(r << 7) | (c ^ (r & 31))];
    }
    atomicAdd(&sPool[c], s);
  }
  __syncthreads();
  if (t < 128) poi_pool[b * 128 + t] = sPool[t] * (1.0f / 128.0f);

  // ---- el per (row, head) ----
  if (t < 384) {
    int r = t & 127, h = t >> 7;
    float d = 0.f;
    const float* qh = &sQ[h * 128];
    for (int c = 0; c < 128; ++c) d += sH[(r << 7) | (c ^ (r & 31))] * qh[c];
    float e = d + sCh[h] + sEr[h];
    sAl[h * 128 + r] = (e > 0.f) ? e : 0.2f * e;
  }
  __syncthreads();

  // ---- per-head softmax over 128 pois ----
  if (t < 192) {
    int h = t >> 6, l = t & 63;
    float v0 = sAl[h * 128 + l], v1 = sAl[h * 128 + 64 + l];
    float m = fmaxf(v0, v1);
    for (int off = 32; off > 0; off >>= 1) m = fmaxf(m, __shfl_xor(m, off));
    float x0 = __expf(v0 - m), x1 = __expf(v1 - m);
    float s = x0 + x1;
    for (int off = 32; off > 0; off >>= 1) s += __shfl_xor(s, off);
    float inv = 1.0f / s;
    sAl[h * 128 + l] = x0 * inv;
    sAl[h * 128 + 64 + l] = x1 * inv;
  }
  __syncthreads();

  // ---- pooled[b,h,:] = sum_r alpha[r,h] * poi_node[r,:] ----
  if (t < 384) {
    int hh = t >> 7, c = t & 127;
    float s = 0.f;
    const float* al = &sAl[hh * 128];
    for (int r = 0; r < 128; ++r) s += al[r] * sH[(r << 7) | (c ^ (r & 31))];
    pooled[((size_t)b * 3 + hh) * 128 + c] = s;
  }
}

// ===================== med pipeline =====================
__global__ void k_mfn(const float* __restrict__ hrs, const float* __restrict__ pool,
                      float* __restrict__ mfn) {
  int r = blockIdx.x, l = threadIdx.x;  // 64 threads
  float v0 = hrs[r * 128 + l], v1 = hrs[r * 128 + 64 + l];
  float v2 = pool[r * 128 + l], v3 = pool[r * 128 + 64 + l];
  float ss = v0 * v0 + v1 * v1 + v2 * v2 + v3 * v3;
  for (int off = 32; off > 0; off >>= 1) ss += __shfl_xor(ss, off);
  float rn = rsqrtf(ss);
  mfn[r * 256 + l] = v0 * rn;
  mfn[r * 256 + 64 + l] = v1 * rn;
  mfn[r * 256 + 128 + l] = v2 * rn;
  mfn[r * 256 + 192 + l] = v3 * rn;
}

__global__ void k_med(const float* __restrict__ mfn, float* __restrict__ med) {
  __shared__ float sI[64 * 64];
  __shared__ float sJ[64 * 64];
  int bi = blockIdx.x >> 3, bj = blockIdx.x & 7;
  int t = threadIdx.x;
  int ti = t >> 4, tj = t & 15;
  float acc[4][4] = {};
  for (int k0 = 0; k0 < 256; k0 += 64) {
    __syncthreads();
    for (int i = t; i < 4096; i += 256) {
      int r = i >> 6, k = i & 63;
      int idx = (r << 6) | (k ^ (r & 31));
      sI[idx] = mfn[(bi * 64 + r) * 256 + k0 + k];
      sJ[idx] = mfn[(bj * 64 + r) * 256 + k0 + k];
    }
    __syncthreads();
    for (int k = 0; k < 64; ++k) {
      float a[4], c4[4];
#pragma unroll
      for (int ii = 0; ii < 4; ++ii) a[ii] = sI[((ti * 4 + ii) << 6) | (k ^ ((ti * 4 + ii) & 31))];
#pragma unroll
      for (int jj = 0; jj < 4; ++jj) c4[jj] = sJ[((tj * 4 + jj) << 6) | (k ^ ((tj * 4 + jj) & 31))];
#pragma unroll
      for (int ii = 0; ii < 4; ++ii)
#pragma unroll
        for (int jj = 0; jj < 4; ++jj) acc[ii][jj] += a[ii] * c4[jj];
    }
  }
#pragma unroll
  for (int ii = 0; ii < 4; ++ii)
#pragma unroll
    for (int jj = 0; jj < 4; ++jj)
      med[(size_t)(bi * 64 + ti * 4 + ii) * 512 + bj * 64 + tj * 4 + jj] =
          (acc[ii][jj] + 1.0f) * 0.5f;
}

__global__ void k_rowsum(const float* __restrict__ med, const float* __restrict__ T0p,
                         float* __restrict__ dinv) {
  int r = blockIdx.x, l = threadIdx.x;  // 64 threads
  float T0 = *T0p;
  float cnt = 0.f;
  for (int j = l; j < 512; j += 64) cnt += ((med[(size_t)r * 512 + j] >= T0) || (j == r)) ? 1.0f : 0.0f;
  for (int off = 32; off > 0; off >>= 1) cnt += __shfl_xor(cnt, off);
  if (l == 0) dinv[r] = rsqrtf(cnt);
}

__global__ void k_Aagg(const float* __restrict__ med, const float* __restrict__ T0p,
                       const float* __restrict__ dinv, const float* __restrict__ hrs,
                       const float* __restrict__ pool, float* __restrict__ t1,
                       float* __restrict__ t2) {
  int i = blockIdx.x, t = threadIdx.x;
  int c = t & 127, half = t >> 7;
  float T0 = *T0p;
  const float* srcm = half ? pool : hrs;
  float acc = 0.f;
  for (int j = 0; j < 512; ++j) {
    float m = med[(size_t)i * 512 + j];
    if (m >= T0 || j == i) acc += dinv[j] * srcm[j * 128 + c];
  }
  float v = acc * dinv[i];
  if (half)
    t2[i * 128 + c] = v;
  else
    t1[i * 128 + c] = v;
}

// ===================== poi2img finish =====================
__global__ void k_poi2img(const float* __restrict__ Y, const float* __restrict__ Wg_in,
                          const float* __restrict__ g0in, float* __restrict__ poi2img) {
  int b = blockIdx.x, c = threadIdx.x;  // 128 threads
  float acc = 0.f;
  for (int h = 0; h < 3; ++h) {
    const float* y = &Y[((size_t)b * 3 + h) * 128];
#pragma unroll 4
    for (int k = 0; k < 128; ++k) acc += y[k] * Wg_in[k * 384 + h * 128 + c];
  }
  poi2img[b * 128 + c] = acc * (1.0f / 3.0f) + g0in[c];
}

// ===================== final fc =====================
__global__ void k_final(const float* __restrict__ img2poi, const float* __restrict__ poi_agg,
                        const float* __restrict__ poi2img, const float* __restrict__ hrs_agg,
                        const float* __restrict__ Wfc, const float* __restrict__ bfc,
                        float* __restrict__ out) {
  int i = blockIdx.x * 256 + threadIdx.x;  // 8192
  int b = i >> 4, o = i & 15;
  float acc = bfc[o];
  const float* srcs[4] = {img2poi, poi_agg, poi2img, hrs_agg};
#pragma unroll
  for (int s = 0; s < 4; ++s) {
    const float* X = srcs[s] + (size_t)b * 128;
    const float* W = Wfc + (size_t)(s * 128) * 16 + o;
#pragma unroll 4
    for (int k = 0; k < 128; ++k) acc += X[k] * W[k * 16];
  }
  out[i] = acc;
}

// ===================== host =====================
extern "C" void kernel_launch(void* const* d_in, const int* in_sizes, int n_in,
                              void* d_out, int out_size, void* d_ws, size_t ws_size,
                              hipStream_t stream) {
  const float* poi_x = (const float*)d_in[0];
  const float* img = (const float*)d_in[1];
  const int* edges = (const int*)d_in[2];
  const float* T0p = (const float*)d_in[4];
  const float* W1 = (const float*)d_in[5];
  const float* b1 = (const float*)d_in[6];
  const float* W2 = (const float*)d_in[7];
  const float* b2 = (const float*)d_in[8];
  const float* Whrs = (const float*)d_in[9];
  const float* bhrs = (const float*)d_in[10];
  const float* Wph = (const float*)d_in[11];
  const float* bph = (const float*)d_in[12];
  const float* Wpp = (const float*)d_in[13];
  const float* bpp = (const float*)d_in[14];
  const float* Wg_in = (const float*)d_in[15];
  const float* al_in = (const float*)d_in[16];
  const float* ar_in = (const float*)d_in[17];
  const float* bg_in = (const float*)d_in[18];
  const float* Wg_w = (const float*)d_in[19];
  const float* bg_w = (const float*)d_in[22];
  const float* Wh1 = (const float*)d_in[23];
  const float* bh1 = (const float*)d_in[24];
  const float* Wp1 = (const float*)d_in[25];
  const float* bp1 = (const float*)d_in[26];
  const float* Wfc = (const float*)d_in[27];
  const float* bfc = (const float*)d_in[28];

  const int* esrc = edges;
  const int* edst = edges + EE;

  char* ws = (char*)d_ws;
  size_t off = 0;
  auto alloc = [&](size_t nbytes) -> char* {
    char* p = ws + off;
    off += (nbytes + 255) & ~(size_t)255;
    return p;
  };
  float* degf = (float*)alloc((size_t)NN * 4);
  int* counts = (int*)alloc(512 * 4);
  int* offs = (int*)alloc(513 * 4);
  int* nodeoff = (int*)alloc((size_t)NN * 4);
  int* cursor = (int*)alloc((size_t)NN * 4);
  uint8_t* list8 = (uint8_t*)alloc((size_t)EE);
  float* hrs = (float*)alloc(512 * 128 * 4);
  float* ph = (float*)alloc(512 * 128 * 4);
  float* er = (float*)alloc(512 * 3 * 4);
  float* u = (float*)alloc(384 * 4);
  float* wv = (float*)alloc(384 * 4);
  float* q = (float*)alloc(384 * 4);
  float* chv = (float*)alloc(16);
  float* G = (float*)alloc(16384 * 4);
  float* g0w = (float*)alloc(128 * 4);
  float* g0in = (float*)alloc(128 * 4);
  float* pool = (float*)alloc(512 * 128 * 4);
  float* pooled = (float*)alloc((size_t)1536 * 128 * 4);
  float* Y = (float*)alloc((size_t)1536 * 128 * 4);
  float* mfn = (float*)alloc(512 * 256 * 4);
  float* dinv = (float*)alloc(512 * 4);
  float* t1b = (float*)alloc(512 * 128 * 4);
  float* t2b = (float*)alloc(512 * 128 * 4);
  float* hrs_agg = (float*)alloc(512 * 128 * 4);
  float* poi_agg = (float*)alloc(512 * 128 * 4);
  float* v_poi2img = (float*)alloc(512 * 128 * 4);
  float* v_img2poi = (float*)alloc(512 * 128 * 4);

  float* out = (float*)d_out;
  float* med = out + 512 * 16;

  hipMemsetAsync(degf, 0, (size_t)NN * 4, stream);
  hipMemsetAsync(counts, 0, 512 * 4, stream);
  hipMemsetAsync(hrs, 0, 512 * 128 * 4, stream);

  // fused gcn dyn LDS: 32768 floats + extras + rows + list
  size_t dynf = (16384 + 16384 + 128 + 384 + 384 + 4 + 4 + 128) * sizeof(float) + 132 * 4 + 2048;
  hipFuncSetAttribute((const void*)k_gcn_fused, hipFuncAttributeMaxDynamicSharedMemorySize,
                      (int)dynf);

  k_prep<<<1, 256, 0, stream>>>(Wg_in, al_in, ar_in, bg_in, Wpp, bpp, Wg_w, bg_w, u, wv, q, chv,
                                G, g0w, g0in);
  k_hist<<<EE / 256, 256, 0, stream>>>(esrc, edst, degf, counts);
  k_scan<<<1, 512, 0, stream>>>(counts, offs);
  k_nodeoff<<<512, 128, 0, stream>>>(degf, offs, nodeoff, cursor);
  k_scatter<<<EE / 256, 256, 0, stream>>>(esrc, edst, cursor, list8);
  k_hrs<<<128, 256, 0, stream>>>(img, Whrs, bhrs, hrs);
  k_gemm128<<<64, 256, 0, stream>>>(hrs, Wph, bph, ph);
  k_er<<<6, 256, 0, stream>>>(ph, wv, er);
  k_gcn_fused<<<512, 512, dynf, stream>>>(poi_x, W1, b1, W2, b2, degf, list8, nodeoff, offs, q,
                                          chv, er, pool, pooled);
  k_mfn<<<512, 64, 0, stream>>>(hrs, pool, mfn);
  k_med<<<64, 256, 0, stream>>>(mfn, med);
  k_rowsum<<<512, 64, 0, stream>>>(med, T0p, dinv);
  k_Aagg<<<512, 256, 0, stream>>>(med, T0p, dinv, hrs, pool, t1b, t2b);
  k_gemm128<<<64, 256, 0, stream>>>(t1b, Wh1, bh1, hrs_agg);
  k_gemm128<<<64, 256, 0, stream>>>(t2b, Wp1, bp1, poi_agg);
  k_gemm128<<<192, 256, 0, stream>>>(pooled, Wpp, bpp, Y);
  k_poi2img<<<512, 128, 0, stream>>>(Y, Wg_in, g0in, v_poi2img);
  k_gemm128<<<64, 256, 0, stream>>>(ph, G, g0w, v_img2poi);
  k_final<<<32, 256, 0, stream>>>(v_img2poi, poi_agg, v_poi2img, hrs_agg, Wfc, bfc, out);

  (void)in_sizes; (void)n_in; (void)out_size; (void)ws_size;
}

// Round 4
// 494.887 us; speedup vs baseline: 2.4213x; 1.2543x over previous
//
#include <hip/hip_runtime.h>
#include <stdint.h>

#define NN 65536
#define EE 524288
#define BB 512
#define LIST_CAP 2048

// ===================== graph prep =====================
__global__ void k_hist(const int* __restrict__ dst, int* __restrict__ deg) {
  int e = blockIdx.x * 256 + threadIdx.x;
  if (e >= EE) return;
  atomicAdd(&deg[dst[e]], 1);  // native int atomic, ~8 updates/address
}

// per-parcel edge counts from per-node degrees (no atomics)
__global__ void k_parcsum(const int* __restrict__ deg, int* __restrict__ counts) {
  __shared__ int s[128];
  int b = blockIdx.x, t = threadIdx.x;
  s[t] = deg[(b << 7) + t];
  __syncthreads();
  for (int d = 64; d > 0; d >>= 1) {
    if (t < d) s[t] += s[t + d];
    __syncthreads();
  }
  if (t == 0) counts[b] = s[0];
}

__global__ void k_scan(const int* __restrict__ counts, int* __restrict__ offs) {
  __shared__ int s[512];
  int t = threadIdx.x;
  s[t] = counts[t];
  __syncthreads();
  for (int d = 1; d < 512; d <<= 1) {
    int v = (t >= d) ? s[t - d] : 0;
    __syncthreads();
    s[t] += v;
    __syncthreads();
  }
  offs[t] = (t == 0) ? 0 : s[t - 1];
  if (t == 511) offs[512] = s[511];
}

// per-node CSR offsets within each parcel + cursors
__global__ void k_nodeoff(const int* __restrict__ deg, const int* __restrict__ offs,
                          int* __restrict__ nodeoff, int* __restrict__ cursor) {
  __shared__ int s[128];
  int b = blockIdx.x, t = threadIdx.x;
  int base = b << 7;
  int d = deg[base + t];
  s[t] = d;
  __syncthreads();
  for (int dd = 1; dd < 128; dd <<= 1) {
    int v = (t >= dd) ? s[t - dd] : 0;
    __syncthreads();
    s[t] += v;
    __syncthreads();
  }
  int excl = s[t] - d + offs[b];
  nodeoff[base + t] = excl;
  cursor[base + t] = excl;
}

__global__ void k_scatter(const int* __restrict__ src, const int* __restrict__ dst,
                          int* __restrict__ cursor, uint8_t* __restrict__ list8) {
  int e = blockIdx.x * 256 + threadIdx.x;
  if (e >= EE) return;
  int s = src[e], d = dst[e];
  int slot = atomicAdd(&cursor[d], 1);
  list8[slot] = (uint8_t)(s & 127);
}

// ===================== weight prep (GAT folding) =====================
__global__ void k_prep(const float* __restrict__ Wg_in, const float* __restrict__ al_in,
                       const float* __restrict__ ar_in, const float* __restrict__ bg_in,
                       const float* __restrict__ Wpp, const float* __restrict__ bpp,
                       const float* __restrict__ Wg_w, const float* __restrict__ bg_w,
                       float* __restrict__ u, float* __restrict__ wv, float* __restrict__ q,
                       float* __restrict__ ch, float* __restrict__ G,
                       float* __restrict__ g0w, float* __restrict__ g0in) {
  int t = threadIdx.x;
  for (int i = t; i < 384; i += 256) {
    int h = i >> 7, k = i & 127;
    float su = 0.f, sw = 0.f;
#pragma unroll 4
    for (int c = 0; c < 128; ++c) {
      float g = Wg_in[k * 384 + h * 128 + c];
      su += g * al_in[h * 128 + c];
      sw += g * ar_in[h * 128 + c];
    }
    u[i] = su;
    wv[i] = sw;
  }
  __syncthreads();
  for (int i = t; i < 384; i += 256) {
    int h = i >> 7, j = i & 127;
    float s = 0.f;
#pragma unroll 4
    for (int k = 0; k < 128; ++k) s += Wpp[j * 128 + k] * u[h * 128 + k];
    q[i] = s;
  }
  if (t < 3) {
    float s = 0.f;
#pragma unroll 4
    for (int k = 0; k < 128; ++k) s += bpp[k] * u[t * 128 + k];
    ch[t] = s;
  }
  for (int i = t; i < 16384; i += 256) {
    int k = i >> 7, c = i & 127;
    G[i] = (Wg_w[k * 384 + c] + Wg_w[k * 384 + 128 + c] + Wg_w[k * 384 + 256 + c]) * (1.0f / 3.0f);
  }
  if (t < 128) {
    g0w[t] = (bg_w[t] + bg_w[128 + t] + bg_w[256 + t]) * (1.0f / 3.0f);
    g0in[t] = (bg_in[t] + bg_in[128 + t] + bg_in[256 + t]) * (1.0f / 3.0f);
  }
}

// ===================== hrs encoder: 8 rows x K=2048 per block, no atomics ==================
__global__ void __launch_bounds__(256) k_hrs(const float* __restrict__ img,
                                             const float* __restrict__ Whrs,
                                             const float* __restrict__ bhrs,
                                             float* __restrict__ hrs) {
  extern __shared__ float sI[];  // [8][2048]
  int bb = blockIdx.x;
  int t = threadIdx.x;
  int r0 = bb * 8;
  const float4* gsrc = (const float4*)(img + (size_t)r0 * 2048);
  float4* ldst = (float4*)sI;
  for (int i = t; i < 4096; i += 256) ldst[i] = gsrc[i];
  __syncthreads();
  int c = t & 127, rh = t >> 7;
  float a0 = 0.f, a1 = 0.f, a2 = 0.f, a3 = 0.f;
  const float* W = Whrs + c;
  const float* s0 = sI + (rh * 4 + 0) * 2048;
  const float* s1 = sI + (rh * 4 + 1) * 2048;
  const float* s2 = sI + (rh * 4 + 2) * 2048;
  const float* s3 = sI + (rh * 4 + 3) * 2048;
  for (int k = 0; k < 2048; ++k) {
    float w = W[(size_t)k * 128];
    a0 += s0[k] * w;
    a1 += s1[k] * w;
    a2 += s2[k] * w;
    a3 += s3[k] * w;
  }
  float bias = bhrs[c];
  int rb = r0 + rh * 4;
  hrs[(rb + 0) * 128 + c] = a0 + bias;
  hrs[(rb + 1) * 128 + c] = a1 + bias;
  hrs[(rb + 2) * 128 + c] = a2 + bias;
  hrs[(rb + 3) * 128 + c] = a3 + bias;
}

// ===================== generic C[M,128] = X[M,128] @ W[128,128] + bias =====================
__global__ void k_gemm128(const float* __restrict__ X, const float* __restrict__ W,
                          const float* __restrict__ bias, float* __restrict__ C) {
  __shared__ float sX[8 * 128];
  int r0 = blockIdx.x * 8;
  int t = threadIdx.x;
  for (int i = t; i < 1024; i += 256) sX[i] = X[(size_t)r0 * 128 + i];
  __syncthreads();
  int c = t & 127, rh = t >> 7;
  float b = bias[c];
  float a0 = b, a1 = b, a2 = b, a3 = b;
  const float* s = sX + (rh * 4) * 128;
  for (int k = 0; k < 128; ++k) {
    float w = W[k * 128 + c];
    a0 += s[k] * w;
    a1 += s[128 + k] * w;
    a2 += s[256 + k] * w;
    a3 += s[384 + k] * w;
  }
  int rb = r0 + rh * 4;
  C[(size_t)(rb + 0) * 128 + c] = a0;
  C[(size_t)(rb + 1) * 128 + c] = a1;
  C[(size_t)(rb + 2) * 128 + c] = a2;
  C[(size_t)(rb + 3) * 128 + c] = a3;
}

// ===================== er[b,h] = ph[b] . wv_h =====================
__global__ void k_er(const float* __restrict__ ph, const float* __restrict__ wv,
                     float* __restrict__ er) {
  int i = blockIdx.x * 256 + threadIdx.x;
  if (i >= BB * 3) return;
  int b = i / 3, h = i % 3;
  float s = 0.f;
#pragma unroll 4
  for (int k = 0; k < 128; ++k) s += ph[b * 128 + k] * wv[h * 128 + k];
  er[i] = s;
}

// ===================== gather edge passes (no atomics) =====================
template <bool STG>
__device__ __forceinline__ void pass64(const float* sX, float* sAcc, const float* sNorm,
                                       const int* sRow, const uint8_t* sList,
                                       const uint8_t* glist, int wave, int lane) {
  for (int r = wave; r < 128; r += 8) {
    int beg = sRow[r], end = sRow[r + 1];
    float a0 = sX[(r << 6) | (lane ^ (r & 31))];
    int e = beg;
    for (; e + 1 < end; e += 2) {
      int l0 = STG ? (int)sList[e] : (int)glist[e];
      int l1 = STG ? (int)sList[e + 1] : (int)glist[e + 1];
      a0 += sX[(l0 << 6) | (lane ^ (l0 & 31))];
      a0 += sX[(l1 << 6) | (lane ^ (l1 & 31))];
    }
    if (e < end) {
      int l0 = STG ? (int)sList[e] : (int)glist[e];
      a0 += sX[(l0 << 6) | (lane ^ (l0 & 31))];
    }
    sAcc[(r << 6) | (lane ^ (r & 31))] = a0 * sNorm[r];
  }
}

template <bool STG>
__device__ __forceinline__ void pass128(const float* sH, float* sAgg, const float* sNorm,
                                        const int* sRow, const uint8_t* sList,
                                        const uint8_t* glist, int wave, int lane) {
  for (int r = wave; r < 128; r += 8) {
    int beg = sRow[r], end = sRow[r + 1];
    float a0 = sH[(r << 7) | (lane ^ (r & 31))];
    float a1 = sH[(r << 7) | ((lane + 64) ^ (r & 31))];
    int e = beg;
    for (; e + 1 < end; e += 2) {
      int l0 = STG ? (int)sList[e] : (int)glist[e];
      int l1 = STG ? (int)sList[e + 1] : (int)glist[e + 1];
      a0 += sH[(l0 << 7) | (lane ^ (l0 & 31))];
      a1 += sH[(l0 << 7) | ((lane + 64) ^ (l0 & 31))];
      a0 += sH[(l1 << 7) | (lane ^ (l1 & 31))];
      a1 += sH[(l1 << 7) | ((lane + 64) ^ (l1 & 31))];
    }
    if (e < end) {
      int l0 = STG ? (int)sList[e] : (int)glist[e];
      a0 += sH[(l0 << 7) | (lane ^ (l0 & 31))];
      a1 += sH[(l0 << 7) | ((lane + 64) ^ (l0 & 31))];
    }
    float ns = sNorm[r];
    sAgg[(r << 7) | (lane ^ (r & 31))] = a0 * ns;
    sAgg[(r << 7) | ((lane + 64) ^ (r & 31))] = a1 * ns;
  }
}

// ===================== FUSED 2-layer GCN + pool + GAT-in softmax (one block per parcel) ======
__global__ void __launch_bounds__(512) k_gcn_fused(
    const float* __restrict__ x, const float* __restrict__ W1, const float* __restrict__ b1,
    const float* __restrict__ W2, const float* __restrict__ b2,
    const int* __restrict__ deg, const uint8_t* __restrict__ g_list,
    const int* __restrict__ nodeoff, const int* __restrict__ offs,
    const float* __restrict__ q, const float* __restrict__ ch, const float* __restrict__ er,
    float* __restrict__ poi_pool, float* __restrict__ pooled) {
  extern __shared__ float sm[];
  float* sH = sm;                // 16384
  float* sAgg = sm + 16384;      // 16384
  float* sNorm = sm + 32768;     // 128
  float* sQ = sNorm + 128;       // 384
  float* sAl = sQ + 384;         // 384
  float* sEr = sAl + 384;        // 4
  float* sCh = sEr + 4;          // 4
  float* sPool = sCh + 4;        // 128
  int* sRow = (int*)(sPool + 128);            // 132
  uint8_t* sList = (uint8_t*)(sRow + 132);    // 2048 B
  float* sX = sAgg;              // [128][64] swizzled
  float* sAcc = sAgg + 8192;     // [128][64] swizzled

  int b = blockIdx.x, t = threadIdx.x;
  int base = b << 7;
  int e0 = offs[b], e1 = offs[b + 1];
  int cnt = e1 - e0;
  if (t < 128) {
    sNorm[t] = rsqrtf((float)deg[base + t] + 1.0f);
    sPool[t] = 0.f;
    sRow[t] = nodeoff[base + t] - e0;
  }
  if (t == 128) sRow[128] = cnt;
  for (int i = t; i < 384; i += 512) sQ[i] = q[i];
  if (t < 3) {
    sEr[t] = er[b * 3 + t];
    sCh[t] = ch[t];
  }
  int scnt = cnt < LIST_CAP ? cnt : LIST_CAP;
  for (int i = t; i < scnt; i += 512) sList[i] = g_list[e0 + i];
  __syncthreads();

  // ---- load x * norm into sX (self values) ----
  for (int i = t; i < 8192; i += 512) {
    int r = i >> 6, k = i & 63;
    float v = x[(size_t)(base + r) * 64 + k] * sNorm[r];
    sX[(r << 6) | (k ^ (r & 31))] = v;
  }
  __syncthreads();

  int wave = t >> 6, lane = t & 63;

  // ---- edge pass 1 (gather, 64-wide) ----
  if (cnt <= LIST_CAP)
    pass64<true>(sX, sAcc, sNorm, sRow, sList, g_list + e0, wave, lane);
  else
    pass64<false>(sX, sAcc, sNorm, sRow, sList, g_list + e0, wave, lane);
  __syncthreads();

  // ---- matmul 1: h1 = relu(sAcc[128,64] @ W1[64,128] + b1); store h1*norm into sH ----
  int rg = t >> 4, cg = t & 15;
  int r0 = rg * 4, c0 = cg * 8;
  {
    float acc[4][8];
#pragma unroll
    for (int j = 0; j < 8; ++j) {
      float bv = b1[c0 + j];
#pragma unroll
      for (int i = 0; i < 4; ++i) acc[i][j] = bv;
    }
    for (int k = 0; k < 64; ++k) {
      float a[4];
#pragma unroll
      for (int i = 0; i < 4; ++i) a[i] = sAcc[((r0 + i) << 6) | (k ^ ((r0 + i) & 31))];
      float4 w0 = *(const float4*)(&W1[k * 128 + c0]);
      float4 w1 = *(const float4*)(&W1[k * 128 + c0 + 4]);
      float w[8] = {w0.x, w0.y, w0.z, w0.w, w1.x, w1.y, w1.z, w1.w};
#pragma unroll
      for (int i = 0; i < 4; ++i)
#pragma unroll
        for (int j = 0; j < 8; ++j) acc[i][j] += a[i] * w[j];
    }
#pragma unroll
    for (int i = 0; i < 4; ++i) {
      int r = r0 + i;
      float ns = sNorm[r];
#pragma unroll
      for (int j = 0; j < 8; ++j)
        sH[(r << 7) | ((c0 + j) ^ (r & 31))] = fmaxf(acc[i][j], 0.f) * ns;
    }
  }
  __syncthreads();

  // ---- edge pass 2 (gather, 128-wide) ----
  if (cnt <= LIST_CAP)
    pass128<true>(sH, sAgg, sNorm, sRow, sList, g_list + e0, wave, lane);
  else
    pass128<false>(sH, sAgg, sNorm, sRow, sList, g_list + e0, wave, lane);
  __syncthreads();

  // ---- matmul 2: poi_node = sAgg[128,128] @ W2[128,128] + b2 -> overwrite sH ----
  {
    float acc[4][8];
#pragma unroll
    for (int j = 0; j < 8; ++j) {
      float bv = b2[c0 + j];
#pragma unroll
      for (int i = 0; i < 4; ++i) acc[i][j] = bv;
    }
    for (int k = 0; k < 128; ++k) {
      float a[4];
#pragma unroll
      for (int i = 0; i < 4; ++i) a[i] = sAgg[((r0 + i) << 7) | (k ^ ((r0 + i) & 31))];
      float4 w0 = *(const float4*)(&W2[k * 128 + c0]);
      float4 w1 = *(const float4*)(&W2[k * 128 + c0 + 4]);
      float w[8] = {w0.x, w0.y, w0.z, w0.w, w1.x, w1.y, w1.z, w1.w};
#pragma unroll
      for (int i = 0; i < 4; ++i)
#pragma unroll
        for (int j = 0; j < 8; ++j) acc[i][j] += a[i] * w[j];
    }
    __syncthreads();
#pragma unroll
    for (int i = 0; i < 4; ++i) {
      int r = r0 + i;
#pragma unroll
      for (int j = 0; j < 8; ++j) sH[(r << 7) | ((c0 + j) ^ (r & 31))] = acc[i][j];
    }
  }
  __syncthreads();

  // ---- poi_pool partial col sums ----
  {
    int c = t & 127, qd = t >> 7;
    float s = 0.f;
    for (int rr = 0; rr < 32; ++rr) {
      int r = qd * 32 + rr;
      s += sH[(r << 7) | (c ^ (r & 31))];
    }
    atomicAdd(&sPool[c], s);
  }
  __syncthreads();
  if (t < 128) poi_pool[b * 128 + t] = sPool[t] * (1.0f / 128.0f);

  // ---- el per (row, head) ----
  if (t < 384) {
    int r = t & 127, h = t >> 7;
    float d = 0.f;
    const float* qh = &sQ[h * 128];
    for (int c = 0; c < 128; ++c) d += sH[(r << 7) | (c ^ (r & 31))] * qh[c];
    float e = d + sCh[h] + sEr[h];
    sAl[h * 128 + r] = (e > 0.f) ? e : 0.2f * e;
  }
  __syncthreads();

  // ---- per-head softmax over 128 pois ----
  if (t < 192) {
    int h = t >> 6, l = t & 63;
    float v0 = sAl[h * 128 + l], v1 = sAl[h * 128 + 64 + l];
    float m = fmaxf(v0, v1);
    for (int off = 32; off > 0; off >>= 1) m = fmaxf(m, __shfl_xor(m, off));
    float x0 = __expf(v0 - m), x1 = __expf(v1 - m);
    float s = x0 + x1;
    for (int off = 32; off > 0; off >>= 1) s += __shfl_xor(s, off);
    float inv = 1.0f / s;
    sAl[h * 128 + l] = x0 * inv;
    sAl[h * 128 + 64 + l] = x1 * inv;
  }
  __syncthreads();

  // ---- pooled[b,h,:] = sum_r alpha[r,h] * poi_node[r,:] ----
  if (t < 384) {
    int hh = t >> 7, c = t & 127;
    float s = 0.f;
    const float* al = &sAl[hh * 128];
    for (int r = 0; r < 128; ++r) s += al[r] * sH[(r << 7) | (c ^ (r & 31))];
    pooled[((size_t)b * 3 + hh) * 128 + c] = s;
  }
}

// ===================== med pipeline =====================
__global__ void k_mfn(const float* __restrict__ hrs, const float* __restrict__ pool,
                      float* __restrict__ mfn) {
  int r = blockIdx.x, l = threadIdx.x;  // 64 threads
  float v0 = hrs[r * 128 + l], v1 = hrs[r * 128 + 64 + l];
  float v2 = pool[r * 128 + l], v3 = pool[r * 128 + 64 + l];
  float ss = v0 * v0 + v1 * v1 + v2 * v2 + v3 * v3;
  for (int off = 32; off > 0; off >>= 1) ss += __shfl_xor(ss, off);
  float rn = rsqrtf(ss);
  mfn[r * 256 + l] = v0 * rn;
  mfn[r * 256 + 64 + l] = v1 * rn;
  mfn[r * 256 + 128 + l] = v2 * rn;
  mfn[r * 256 + 192 + l] = v3 * rn;
}

__global__ void k_med(const float* __restrict__ mfn, float* __restrict__ med) {
  __shared__ float sI[64 * 64];
  __shared__ float sJ[64 * 64];
  int bi = blockIdx.x >> 3, bj = blockIdx.x & 7;
  int t = threadIdx.x;
  int ti = t >> 4, tj = t & 15;
  float acc[4][4] = {};
  for (int k0 = 0; k0 < 256; k0 += 64) {
    __syncthreads();
    for (int i = t; i < 4096; i += 256) {
      int r = i >> 6, k = i & 63;
      int idx = (r << 6) | (k ^ (r & 31));
      sI[idx] = mfn[(bi * 64 + r) * 256 + k0 + k];
      sJ[idx] = mfn[(bj * 64 + r) * 256 + k0 + k];
    }
    __syncthreads();
    for (int k = 0; k < 64; ++k) {
      float a[4], c4[4];
#pragma unroll
      for (int ii = 0; ii < 4; ++ii) a[ii] = sI[((ti * 4 + ii) << 6) | (k ^ ((ti * 4 + ii) & 31))];
#pragma unroll
      for (int jj = 0; jj < 4; ++jj) c4[jj] = sJ[((tj * 4 + jj) << 6) | (k ^ ((tj * 4 + jj) & 31))];
#pragma unroll
      for (int ii = 0; ii < 4; ++ii)
#pragma unroll
        for (int jj = 0; jj < 4; ++jj) acc[ii][jj] += a[ii] * c4[jj];
    }
  }
#pragma unroll
  for (int ii = 0; ii < 4; ++ii)
#pragma unroll
    for (int jj = 0; jj < 4; ++jj)
      med[(size_t)(bi * 64 + ti * 4 + ii) * 512 + bj * 64 + tj * 4 + jj] =
          (acc[ii][jj] + 1.0f) * 0.5f;
}

__global__ void k_rowsum(const float* __restrict__ med, const float* __restrict__ T0p,
                         float* __restrict__ dinv) {
  int r = blockIdx.x, l = threadIdx.x;  // 64 threads
  float T0 = *T0p;
  float cnt = 0.f;
  for (int j = l; j < 512; j += 64) cnt += ((med[(size_t)r * 512 + j] >= T0) || (j == r)) ? 1.0f : 0.0f;
  for (int off = 32; off > 0; off >>= 1) cnt += __shfl_xor(cnt, off);
  if (l == 0) dinv[r] = rsqrtf(cnt);
}

__global__ void k_Aagg(const float* __restrict__ med, const float* __restrict__ T0p,
                       const float* __restrict__ dinv, const float* __restrict__ hrs,
                       const float* __restrict__ pool, float* __restrict__ t1,
                       float* __restrict__ t2) {
  int i = blockIdx.x, t = threadIdx.x;
  int c = t & 127, half = t >> 7;
  float T0 = *T0p;
  const float* srcm = half ? pool : hrs;
  float acc = 0.f;
  for (int j = 0; j < 512; ++j) {
    float m = med[(size_t)i * 512 + j];
    if (m >= T0 || j == i) acc += dinv[j] * srcm[j * 128 + c];
  }
  float v = acc * dinv[i];
  if (half)
    t2[i * 128 + c] = v;
  else
    t1[i * 128 + c] = v;
}

// ===================== poi2img finish =====================
__global__ void k_poi2img(const float* __restrict__ Y, const float* __restrict__ Wg_in,
                          const float* __restrict__ g0in, float* __restrict__ poi2img) {
  int b = blockIdx.x, c = threadIdx.x;  // 128 threads
  float acc = 0.f;
  for (int h = 0; h < 3; ++h) {
    const float* y = &Y[((size_t)b * 3 + h) * 128];
#pragma unroll 4
    for (int k = 0; k < 128; ++k) acc += y[k] * Wg_in[k * 384 + h * 128 + c];
  }
  poi2img[b * 128 + c] = acc * (1.0f / 3.0f) + g0in[c];
}

// ===================== final fc =====================
__global__ void k_final(const float* __restrict__ img2poi, const float* __restrict__ poi_agg,
                        const float* __restrict__ poi2img, const float* __restrict__ hrs_agg,
                        const float* __restrict__ Wfc, const float* __restrict__ bfc,
                        float* __restrict__ out) {
  int i = blockIdx.x * 256 + threadIdx.x;  // 8192
  int b = i >> 4, o = i & 15;
  float acc = bfc[o];
  const float* srcs[4] = {img2poi, poi_agg, poi2img, hrs_agg};
#pragma unroll
  for (int s = 0; s < 4; ++s) {
    const float* X = srcs[s] + (size_t)b * 128;
    const float* W = Wfc + (size_t)(s * 128) * 16 + o;
#pragma unroll 4
    for (int k = 0; k < 128; ++k) acc += X[k] * W[k * 16];
  }
  out[i] = acc;
}

// ===================== host =====================
extern "C" void kernel_launch(void* const* d_in, const int* in_sizes, int n_in,
                              void* d_out, int out_size, void* d_ws, size_t ws_size,
                              hipStream_t stream) {
  const float* poi_x = (const float*)d_in[0];
  const float* img = (const float*)d_in[1];
  const int* edges = (const int*)d_in[2];
  const float* T0p = (const float*)d_in[4];
  const float* W1 = (const float*)d_in[5];
  const float* b1 = (const float*)d_in[6];
  const float* W2 = (const float*)d_in[7];
  const float* b2 = (const float*)d_in[8];
  const float* Whrs = (const float*)d_in[9];
  const float* bhrs = (const float*)d_in[10];
  const float* Wph = (const float*)d_in[11];
  const float* bph = (const float*)d_in[12];
  const float* Wpp = (const float*)d_in[13];
  const float* bpp = (const float*)d_in[14];
  const float* Wg_in = (const float*)d_in[15];
  const float* al_in = (const float*)d_in[16];
  const float* ar_in = (const float*)d_in[17];
  const float* bg_in = (const float*)d_in[18];
  const float* Wg_w = (const float*)d_in[19];
  const float* bg_w = (const float*)d_in[22];
  const float* Wh1 = (const float*)d_in[23];
  const float* bh1 = (const float*)d_in[24];
  const float* Wp1 = (const float*)d_in[25];
  const float* bp1 = (const float*)d_in[26];
  const float* Wfc = (const float*)d_in[27];
  const float* bfc = (const float*)d_in[28];

  const int* esrc = edges;
  const int* edst = edges + EE;

  char* ws = (char*)d_ws;
  size_t off = 0;
  auto alloc = [&](size_t nbytes) -> char* {
    char* p = ws + off;
    off += (nbytes + 255) & ~(size_t)255;
    return p;
  };
  int* deg = (int*)alloc((size_t)NN * 4);
  int* counts = (int*)alloc(512 * 4);
  int* offs = (int*)alloc(513 * 4);
  int* nodeoff = (int*)alloc((size_t)NN * 4);
  int* cursor = (int*)alloc((size_t)NN * 4);
  uint8_t* list8 = (uint8_t*)alloc((size_t)EE);
  float* hrs = (float*)alloc(512 * 128 * 4);
  float* ph = (float*)alloc(512 * 128 * 4);
  float* er = (float*)alloc(512 * 3 * 4);
  float* u = (float*)alloc(384 * 4);
  float* wv = (float*)alloc(384 * 4);
  float* q = (float*)alloc(384 * 4);
  float* chv = (float*)alloc(16);
  float* G = (float*)alloc(16384 * 4);
  float* g0w = (float*)alloc(128 * 4);
  float* g0in = (float*)alloc(128 * 4);
  float* pool = (float*)alloc(512 * 128 * 4);
  float* pooled = (float*)alloc((size_t)1536 * 128 * 4);
  float* Y = (float*)alloc((size_t)1536 * 128 * 4);
  float* mfn = (float*)alloc(512 * 256 * 4);
  float* dinv = (float*)alloc(512 * 4);
  float* t1b = (float*)alloc(512 * 128 * 4);
  float* t2b = (float*)alloc(512 * 128 * 4);
  float* hrs_agg = (float*)alloc(512 * 128 * 4);
  float* poi_agg = (float*)alloc(512 * 128 * 4);
  float* v_poi2img = (float*)alloc(512 * 128 * 4);
  float* v_img2poi = (float*)alloc(512 * 128 * 4);

  float* out = (float*)d_out;
  float* med = out + 512 * 16;

  hipMemsetAsync(deg, 0, (size_t)NN * 4, stream);

  size_t dynf = (16384 + 16384 + 128 + 384 + 384 + 4 + 4 + 128) * sizeof(float) + 132 * 4 + 2048;
  hipFuncSetAttribute((const void*)k_gcn_fused, hipFuncAttributeMaxDynamicSharedMemorySize,
                      (int)dynf);
  hipFuncSetAttribute((const void*)k_hrs, hipFuncAttributeMaxDynamicSharedMemorySize, 65536);

  k_prep<<<1, 256, 0, stream>>>(Wg_in, al_in, ar_in, bg_in, Wpp, bpp, Wg_w, bg_w, u, wv, q, chv,
                                G, g0w, g0in);
  k_hist<<<EE / 256, 256, 0, stream>>>(edst, deg);
  k_parcsum<<<512, 128, 0, stream>>>(deg, counts);
  k_scan<<<1, 512, 0, stream>>>(counts, offs);
  k_nodeoff<<<512, 128, 0, stream>>>(deg, offs, nodeoff, cursor);
  k_scatter<<<EE / 256, 256, 0, stream>>>(esrc, edst, cursor, list8);
  k_hrs<<<64, 256, 65536, stream>>>(img, Whrs, bhrs, hrs);
  k_gemm128<<<64, 256, 0, stream>>>(hrs, Wph, bph, ph);
  k_er<<<6, 256, 0, stream>>>(ph, wv, er);
  k_gcn_fused<<<512, 512, dynf, stream>>>(poi_x, W1, b1, W2, b2, deg, list8, nodeoff, offs, q,
                                          chv, er, pool, pooled);
  k_mfn<<<512, 64, 0, stream>>>(hrs, pool, mfn);
  k_med<<<64, 256, 0, stream>>>(mfn, med);
  k_rowsum<<<512, 64, 0, stream>>>(med, T0p, dinv);
  k_Aagg<<<512, 256, 0, stream>>>(med, T0p, dinv, hrs, pool, t1b, t2b);
  k_gemm128<<<64, 256, 0, stream>>>(t1b, Wh1, bh1, hrs_agg);
  k_gemm128<<<64, 256, 0, stream>>>(t2b, Wp1, bp1, poi_agg);
  k_gemm128<<<192, 256, 0, stream>>>(pooled, Wpp, bpp, Y);
  k_poi2img<<<512, 128, 0, stream>>>(Y, Wg_in, g0in, v_poi2img);
  k_gemm128<<<64, 256, 0, stream>>>(ph, G, g0w, v_img2poi);
  k_final<<<32, 256, 0, stream>>>(v_img2poi, poi_agg, v_poi2img, hrs_agg, Wfc, bfc, out);

  (void)in_sizes; (void)n_in; (void)out_size; (void)ws_size;
}

// Round 5
// 430.412 us; speedup vs baseline: 2.7841x; 1.1498x over previous
//
#include <hip/hip_runtime.h>
#include <stdint.h>

#define NN 65536
#define EE 524288
#define BB 512
#define LIST_CAP 2048

// ===================== graph prep =====================
__global__ void k_hist(const int* __restrict__ dst, int* __restrict__ deg) {
  int e = blockIdx.x * 256 + threadIdx.x;
  if (e >= EE) return;
  atomicAdd(&deg[dst[e]], 1);
}

__global__ void k_parcsum(const int* __restrict__ deg, int* __restrict__ counts) {
  __shared__ int s[128];
  int b = blockIdx.x, t = threadIdx.x;
  s[t] = deg[(b << 7) + t];
  __syncthreads();
  for (int d = 64; d > 0; d >>= 1) {
    if (t < d) s[t] += s[t + d];
    __syncthreads();
  }
  if (t == 0) counts[b] = s[0];
}

__global__ void k_scan(const int* __restrict__ counts, int* __restrict__ offs) {
  __shared__ int s[512];
  int t = threadIdx.x;
  s[t] = counts[t];
  __syncthreads();
  for (int d = 1; d < 512; d <<= 1) {
    int v = (t >= d) ? s[t - d] : 0;
    __syncthreads();
    s[t] += v;
    __syncthreads();
  }
  offs[t] = (t == 0) ? 0 : s[t - 1];
  if (t == 511) offs[512] = s[511];
}

__global__ void k_nodeoff(const int* __restrict__ deg, const int* __restrict__ offs,
                          int* __restrict__ nodeoff, int* __restrict__ cursor) {
  __shared__ int s[128];
  int b = blockIdx.x, t = threadIdx.x;
  int base = b << 7;
  int d = deg[base + t];
  s[t] = d;
  __syncthreads();
  for (int dd = 1; dd < 128; dd <<= 1) {
    int v = (t >= dd) ? s[t - dd] : 0;
    __syncthreads();
    s[t] += v;
    __syncthreads();
  }
  int excl = s[t] - d + offs[b];
  nodeoff[base + t] = excl;
  cursor[base + t] = excl;
}

__global__ void k_scatter(const int* __restrict__ src, const int* __restrict__ dst,
                          int* __restrict__ cursor, uint8_t* __restrict__ list8) {
  int e = blockIdx.x * 256 + threadIdx.x;
  if (e >= EE) return;
  int s = src[e], d = dst[e];
  int slot = atomicAdd(&cursor[d], 1);
  list8[slot] = (uint8_t)(s & 127);
}

// ===================== weight prep (GAT folding) =====================
__global__ void k_prep(const float* __restrict__ Wg_in, const float* __restrict__ al_in,
                       const float* __restrict__ ar_in, const float* __restrict__ Wpp,
                       const float* __restrict__ bpp, float* __restrict__ u,
                       float* __restrict__ wv, float* __restrict__ q, float* __restrict__ ch) {
  int t = threadIdx.x;
  for (int i = t; i < 384; i += 256) {
    int h = i >> 7, k = i & 127;
    float su = 0.f, sw = 0.f;
#pragma unroll 4
    for (int c = 0; c < 128; ++c) {
      float g = Wg_in[k * 384 + h * 128 + c];
      su += g * al_in[h * 128 + c];
      sw += g * ar_in[h * 128 + c];
    }
    u[i] = su;
    wv[i] = sw;
  }
  __syncthreads();
  for (int i = t; i < 384; i += 256) {
    int h = i >> 7, j = i & 127;
    float s = 0.f;
#pragma unroll 4
    for (int k = 0; k < 128; ++k) s += Wpp[j * 128 + k] * u[h * 128 + k];
    q[i] = s;
  }
  if (t < 3) {
    float s = 0.f;
#pragma unroll 4
    for (int k = 0; k < 128; ++k) s += bpp[k] * u[t * 128 + k];
    ch[t] = s;
  }
}

__global__ void k_prepG(const float* __restrict__ Wg_w, const float* __restrict__ bg_w,
                        const float* __restrict__ bg_in, float* __restrict__ G,
                        float* __restrict__ g0w, float* __restrict__ g0in) {
  int i = blockIdx.x * 256 + threadIdx.x;  // 16384
  int k = i >> 7, c = i & 127;
  G[i] = (Wg_w[k * 384 + c] + Wg_w[k * 384 + 128 + c] + Wg_w[k * 384 + 256 + c]) * (1.0f / 3.0f);
  if (i < 128) {
    g0w[i] = (bg_w[i] + bg_w[128 + i] + bg_w[256 + i]) * (1.0f / 3.0f);
    g0in[i] = (bg_in[i] + bg_in[128 + i] + bg_in[256 + i]) * (1.0f / 3.0f);
  }
}

// ===================== hrs encoder: 2 rows x (K=2048 split 2) per block ====================
__global__ void __launch_bounds__(512) k_hrs(const float* __restrict__ img,
                                             const float* __restrict__ Whrs,
                                             const float* __restrict__ bhrs,
                                             float* __restrict__ hrs) {
  __shared__ float sI[4096];       // 2 rows x 2048
  __shared__ float sRed[4][128];
  int r0 = blockIdx.x * 2;
  int t = threadIdx.x;
  const float4* gsrc = (const float4*)(img + (size_t)r0 * 2048);
  float4* ldst = (float4*)sI;
  for (int i = t; i < 1024; i += 512) ldst[i] = gsrc[i];
  __syncthreads();
  int c = t & 127, g = t >> 7;     // g 0..3
  int row = g & 1, ks = g >> 1;
  const float* s = sI + row * 2048 + ks * 1024;
  const float* W = Whrs + (size_t)(ks * 1024) * 128 + c;
  float a0 = 0.f, a1 = 0.f, a2 = 0.f, a3 = 0.f;
  for (int k = 0; k < 1024; k += 4) {
    a0 += s[k] * W[(size_t)k * 128];
    a1 += s[k + 1] * W[(size_t)(k + 1) * 128];
    a2 += s[k + 2] * W[(size_t)(k + 2) * 128];
    a3 += s[k + 3] * W[(size_t)(k + 3) * 128];
  }
  sRed[g][c] = (a0 + a1) + (a2 + a3);
  __syncthreads();
  if (t < 256) {
    int rr = t >> 7, cc = t & 127;
    hrs[(r0 + rr) * 128 + cc] = sRed[rr][cc] + sRed[rr + 2][cc] + bhrs[cc];
  }
}

// ===================== generic C[M,128] = X[M,128] @ W[128,128] + bias =====================
__global__ void k_gemm128(const float* __restrict__ X, const float* __restrict__ W,
                          const float* __restrict__ bias, float* __restrict__ C) {
  __shared__ float sX[8 * 128];
  int r0 = blockIdx.x * 8;
  int t = threadIdx.x;
  for (int i = t; i < 1024; i += 256) sX[i] = X[(size_t)r0 * 128 + i];
  __syncthreads();
  int c = t & 127, rh = t >> 7;
  float b = bias[c];
  float a0 = b, a1 = b, a2 = b, a3 = b;
  const float* s = sX + (rh * 4) * 128;
  for (int k = 0; k < 128; ++k) {
    float w = W[k * 128 + c];
    a0 += s[k] * w;
    a1 += s[128 + k] * w;
    a2 += s[256 + k] * w;
    a3 += s[384 + k] * w;
  }
  int rb = r0 + rh * 4;
  C[(size_t)(rb + 0) * 128 + c] = a0;
  C[(size_t)(rb + 1) * 128 + c] = a1;
  C[(size_t)(rb + 2) * 128 + c] = a2;
  C[(size_t)(rb + 3) * 128 + c] = a3;
}

// ===================== er[b,h] = ph[b] . wv_h =====================
__global__ void k_er(const float* __restrict__ ph, const float* __restrict__ wv,
                     float* __restrict__ er) {
  int i = blockIdx.x * 256 + threadIdx.x;
  if (i >= BB * 3) return;
  int b = i / 3, h = i % 3;
  float s = 0.f;
#pragma unroll 4
  for (int k = 0; k < 128; ++k) s += ph[b * 128 + k] * wv[h * 128 + k];
  er[i] = s;
}

// ===================== gather edge passes (no atomics) =====================
template <bool STG>
__device__ __forceinline__ void pass64(const float* sX, float* sAcc, const float* sNorm,
                                       const int* sRow, const uint8_t* sList,
                                       const uint8_t* glist, int wave, int lane) {
  for (int r = wave; r < 128; r += 16) {
    int beg = sRow[r], end = sRow[r + 1];
    float a0 = sX[(r << 6) | (lane ^ (r & 31))];
    int e = beg;
    for (; e + 1 < end; e += 2) {
      int l0 = STG ? (int)sList[e] : (int)glist[e];
      int l1 = STG ? (int)sList[e + 1] : (int)glist[e + 1];
      a0 += sX[(l0 << 6) | (lane ^ (l0 & 31))];
      a0 += sX[(l1 << 6) | (lane ^ (l1 & 31))];
    }
    if (e < end) {
      int l0 = STG ? (int)sList[e] : (int)glist[e];
      a0 += sX[(l0 << 6) | (lane ^ (l0 & 31))];
    }
    sAcc[(r << 6) | (lane ^ (r & 31))] = a0 * sNorm[r];
  }
}

template <bool STG>
__device__ __forceinline__ void pass128(const float* sH, float* sAgg, const float* sNorm,
                                        const int* sRow, const uint8_t* sList,
                                        const uint8_t* glist, int wave, int lane) {
  for (int r = wave; r < 128; r += 16) {
    int beg = sRow[r], end = sRow[r + 1];
    float a0 = sH[(r << 7) | (lane ^ (r & 31))];
    float a1 = sH[(r << 7) | ((lane + 64) ^ (r & 31))];
    int e = beg;
    for (; e + 1 < end; e += 2) {
      int l0 = STG ? (int)sList[e] : (int)glist[e];
      int l1 = STG ? (int)sList[e + 1] : (int)glist[e + 1];
      a0 += sH[(l0 << 7) | (lane ^ (l0 & 31))];
      a1 += sH[(l0 << 7) | ((lane + 64) ^ (l0 & 31))];
      a0 += sH[(l1 << 7) | (lane ^ (l1 & 31))];
      a1 += sH[(l1 << 7) | ((lane + 64) ^ (l1 & 31))];
    }
    if (e < end) {
      int l0 = STG ? (int)sList[e] : (int)glist[e];
      a0 += sH[(l0 << 7) | (lane ^ (l0 & 31))];
      a1 += sH[(l0 << 7) | ((lane + 64) ^ (l0 & 31))];
    }
    float ns = sNorm[r];
    sAgg[(r << 7) | (lane ^ (r & 31))] = a0 * ns;
    sAgg[(r << 7) | ((lane + 64) ^ (r & 31))] = a1 * ns;
  }
}

// ===================== FUSED 2-layer GCN + pool + GAT-in softmax + mfn ======================
__global__ void __launch_bounds__(1024) k_gcn_fused(
    const float* __restrict__ x, const float* __restrict__ W1, const float* __restrict__ b1,
    const float* __restrict__ W2, const float* __restrict__ b2,
    const int* __restrict__ deg, const uint8_t* __restrict__ g_list,
    const int* __restrict__ nodeoff, const int* __restrict__ offs,
    const float* __restrict__ q, const float* __restrict__ ch, const float* __restrict__ er,
    const float* __restrict__ hrs, float* __restrict__ poi_pool, float* __restrict__ pooled,
    float* __restrict__ mfn) {
  extern __shared__ float sm[];
  float* sH = sm;                // 16384
  float* sAgg = sm + 16384;      // 16384
  float* sNorm = sm + 32768;     // 128
  float* sQ = sNorm + 128;       // 384 (reused as mfn scratch at end)
  float* sAl = sQ + 384;         // 384
  float* sEr = sAl + 384;        // 4
  float* sCh = sEr + 4;          // 4
  float* sPool = sCh + 4;        // 128
  int* sRow = (int*)(sPool + 128);            // 132
  uint8_t* sList = (uint8_t*)(sRow + 132);    // 2048 B
  float* sX = sAgg;              // [128][64] swizzled
  float* sAcc = sAgg + 8192;     // [128][64] swizzled

  int b = blockIdx.x, t = threadIdx.x;
  int base = b << 7;
  int e0 = offs[b], e1 = offs[b + 1];
  int cnt = e1 - e0;
  if (t < 128) {
    sNorm[t] = rsqrtf((float)deg[base + t] + 1.0f);
    sPool[t] = 0.f;
    sRow[t] = nodeoff[base + t] - e0;
  }
  if (t == 128) sRow[128] = cnt;
  for (int i = t; i < 384; i += 1024) sQ[i] = q[i];
  if (t < 3) {
    sEr[t] = er[b * 3 + t];
    sCh[t] = ch[t];
  }
  int scnt = cnt < LIST_CAP ? cnt : LIST_CAP;
  for (int i = t; i < scnt; i += 1024) sList[i] = g_list[e0 + i];
  __syncthreads();

  // ---- load x * norm into sX ----
  for (int i = t; i < 8192; i += 1024) {
    int r = i >> 6, k = i & 63;
    float v = x[(size_t)(base + r) * 64 + k] * sNorm[r];
    sX[(r << 6) | (k ^ (r & 31))] = v;
  }
  __syncthreads();

  int wave = t >> 6, lane = t & 63;

  // ---- edge pass 1 (gather, 64-wide) ----
  if (cnt <= LIST_CAP)
    pass64<true>(sX, sAcc, sNorm, sRow, sList, g_list + e0, wave, lane);
  else
    pass64<false>(sX, sAcc, sNorm, sRow, sList, g_list + e0, wave, lane);
  __syncthreads();

  // ---- matmul 1: h1 = relu(sAcc[128,64] @ W1 + b1) * norm -> sH ----
  int rg = t >> 4, cg = t & 15;
  int r0 = rg * 2, c0 = cg * 8;
  {
    float acc[2][8];
#pragma unroll
    for (int j = 0; j < 8; ++j) {
      float bv = b1[c0 + j];
      acc[0][j] = bv;
      acc[1][j] = bv;
    }
    for (int k = 0; k < 64; ++k) {
      float a[2];
#pragma unroll
      for (int i = 0; i < 2; ++i) a[i] = sAcc[((r0 + i) << 6) | (k ^ ((r0 + i) & 31))];
      float4 w0 = *(const float4*)(&W1[k * 128 + c0]);
      float4 w1 = *(const float4*)(&W1[k * 128 + c0 + 4]);
      float w[8] = {w0.x, w0.y, w0.z, w0.w, w1.x, w1.y, w1.z, w1.w};
#pragma unroll
      for (int i = 0; i < 2; ++i)
#pragma unroll
        for (int j = 0; j < 8; ++j) acc[i][j] += a[i] * w[j];
    }
#pragma unroll
    for (int i = 0; i < 2; ++i) {
      int r = r0 + i;
      float ns = sNorm[r];
#pragma unroll
      for (int j = 0; j < 8; ++j)
        sH[(r << 7) | ((c0 + j) ^ (r & 31))] = fmaxf(acc[i][j], 0.f) * ns;
    }
  }
  __syncthreads();

  // ---- edge pass 2 (gather, 128-wide) ----
  if (cnt <= LIST_CAP)
    pass128<true>(sH, sAgg, sNorm, sRow, sList, g_list + e0, wave, lane);
  else
    pass128<false>(sH, sAgg, sNorm, sRow, sList, g_list + e0, wave, lane);
  __syncthreads();

  // ---- matmul 2: poi_node = sAgg @ W2 + b2 -> overwrite sH ----
  {
    float acc[2][8];
#pragma unroll
    for (int j = 0; j < 8; ++j) {
      float bv = b2[c0 + j];
      acc[0][j] = bv;
      acc[1][j] = bv;
    }
    for (int k = 0; k < 128; ++k) {
      float a[2];
#pragma unroll
      for (int i = 0; i < 2; ++i) a[i] = sAgg[((r0 + i) << 7) | (k ^ ((r0 + i) & 31))];
      float4 w0 = *(const float4*)(&W2[k * 128 + c0]);
      float4 w1 = *(const float4*)(&W2[k * 128 + c0 + 4]);
      float w[8] = {w0.x, w0.y, w0.z, w0.w, w1.x, w1.y, w1.z, w1.w};
#pragma unroll
      for (int i = 0; i < 2; ++i)
#pragma unroll
        for (int j = 0; j < 8; ++j) acc[i][j] += a[i] * w[j];
    }
    __syncthreads();
#pragma unroll
    for (int i = 0; i < 2; ++i) {
      int r = r0 + i;
#pragma unroll
      for (int j = 0; j < 8; ++j) sH[(r << 7) | ((c0 + j) ^ (r & 31))] = acc[i][j];
    }
  }
  __syncthreads();

  // ---- poi_pool partial col sums ----
  {
    int c = t & 127, qd = t >> 7;  // qd 0..7, 16 rows each
    float s = 0.f;
    for (int rr = 0; rr < 16; ++rr) {
      int r = qd * 16 + rr;
      s += sH[(r << 7) | (c ^ (r & 31))];
    }
    atomicAdd(&sPool[c], s);
  }
  __syncthreads();
  if (t < 128) poi_pool[b * 128 + t] = sPool[t] * (1.0f / 128.0f);

  // ---- el per (row, head) ----
  if (t < 384) {
    int r = t & 127, h = t >> 7;
    float d = 0.f;
    const float* qh = &sQ[h * 128];
    for (int c = 0; c < 128; ++c) d += sH[(r << 7) | (c ^ (r & 31))] * qh[c];
    float e = d + sCh[h] + sEr[h];
    sAl[h * 128 + r] = (e > 0.f) ? e : 0.2f * e;
  }
  __syncthreads();

  // ---- per-head softmax over 128 pois ----
  if (t < 192) {
    int h = t >> 6, l = t & 63;
    float v0 = sAl[h * 128 + l], v1 = sAl[h * 128 + 64 + l];
    float m = fmaxf(v0, v1);
    for (int off = 32; off > 0; off >>= 1) m = fmaxf(m, __shfl_xor(m, off));
    float x0 = __expf(v0 - m), x1 = __expf(v1 - m);
    float s = x0 + x1;
    for (int off = 32; off > 0; off >>= 1) s += __shfl_xor(s, off);
    float inv = 1.0f / s;
    sAl[h * 128 + l] = x0 * inv;
    sAl[h * 128 + 64 + l] = x1 * inv;
  }
  __syncthreads();

  // ---- pooled[b,h,:] = sum_r alpha[r,h] * poi_node[r,:] ----
  if (t < 384) {
    int hh = t >> 7, c = t & 127;
    float s = 0.f;
    const float* al = &sAl[hh * 128];
    for (int r = 0; r < 128; ++r) s += al[r] * sH[(r << 7) | (c ^ (r & 31))];
    pooled[((size_t)b * 3 + hh) * 128 + c] = s;
  }
  __syncthreads();

  // ---- fused mfn: normalized [hrs[b], pool[b]] row (sQ reused as scratch) ----
  float hv = 0.f, pv = 0.f;
  if (t < 128) {
    hv = hrs[base + t];
    pv = sPool[t] * (1.0f / 128.0f);
    sQ[t] = hv * hv + pv * pv;
  }
  __syncthreads();
  if (t < 64) {
    float v = sQ[t] + sQ[t + 64];
    for (int off = 32; off > 0; off >>= 1) v += __shfl_xor(v, off);
    if (t == 0) sQ[0] = rsqrtf(v);
  }
  __syncthreads();
  if (t < 128) {
    float rn = sQ[0];
    mfn[b * 256 + t] = hv * rn;
    mfn[b * 256 + 128 + t] = pv * rn;
  }
}

// ===================== med: 32x32 tiles, 256 blocks =====================
__global__ void k_med(const float* __restrict__ mfn, float* __restrict__ med) {
  __shared__ float sI[32 * 64];
  __shared__ float sJ[32 * 64];
  int bi = blockIdx.x >> 4, bj = blockIdx.x & 15;
  int t = threadIdx.x;
  int ti = t >> 4, tj = t & 15;
  float acc[2][2] = {};
  for (int k0 = 0; k0 < 256; k0 += 64) {
    __syncthreads();
    for (int i = t; i < 2048; i += 256) {
      int r = i >> 6, k = i & 63;
      int idx = (r << 6) | (k ^ (r & 31));
      sI[idx] = mfn[(bi * 32 + r) * 256 + k0 + k];
      sJ[idx] = mfn[(bj * 32 + r) * 256 + k0 + k];
    }
    __syncthreads();
    for (int k = 0; k < 64; ++k) {
      float a[2], c2[2];
#pragma unroll
      for (int ii = 0; ii < 2; ++ii) a[ii] = sI[((ti * 2 + ii) << 6) | (k ^ ((ti * 2 + ii) & 31))];
#pragma unroll
      for (int jj = 0; jj < 2; ++jj) c2[jj] = sJ[((tj * 2 + jj) << 6) | (k ^ ((tj * 2 + jj) & 31))];
#pragma unroll
      for (int ii = 0; ii < 2; ++ii)
#pragma unroll
        for (int jj = 0; jj < 2; ++jj) acc[ii][jj] += a[ii] * c2[jj];
    }
  }
#pragma unroll
  for (int ii = 0; ii < 2; ++ii)
#pragma unroll
    for (int jj = 0; jj < 2; ++jj)
      med[(size_t)(bi * 32 + ti * 2 + ii) * 512 + bj * 32 + tj * 2 + jj] =
          (acc[ii][jj] + 1.0f) * 0.5f;
}

__global__ void k_rowsum(const float* __restrict__ med, const float* __restrict__ T0p,
                         float* __restrict__ dinv) {
  int r = blockIdx.x, l = threadIdx.x;  // 64 threads
  float T0 = *T0p;
  float cnt = 0.f;
  for (int j = l; j < 512; j += 64) cnt += ((med[(size_t)r * 512 + j] >= T0) || (j == r)) ? 1.0f : 0.0f;
  for (int off = 32; off > 0; off >>= 1) cnt += __shfl_xor(cnt, off);
  if (l == 0) dinv[r] = rsqrtf(cnt);
}

__global__ void k_Aagg(const float* __restrict__ med, const float* __restrict__ T0p,
                       const float* __restrict__ dinv, const float* __restrict__ hrs,
                       const float* __restrict__ pool, float* __restrict__ t1,
                       float* __restrict__ t2) {
  int i = blockIdx.x, t = threadIdx.x;
  int c = t & 127, half = t >> 7;
  float T0 = *T0p;
  const float* srcm = half ? pool : hrs;
  float acc = 0.f;
  for (int j = 0; j < 512; ++j) {
    float m = med[(size_t)i * 512 + j];
    if (m >= T0 || j == i) acc += dinv[j] * srcm[j * 128 + c];
  }
  float v = acc * dinv[i];
  if (half)
    t2[i * 128 + c] = v;
  else
    t1[i * 128 + c] = v;
}

// ===================== poi2img finish =====================
__global__ void k_poi2img(const float* __restrict__ Y, const float* __restrict__ Wg_in,
                          const float* __restrict__ g0in, float* __restrict__ poi2img) {
  int b = blockIdx.x, c = threadIdx.x;  // 128 threads
  float acc = 0.f;
  for (int h = 0; h < 3; ++h) {
    const float* y = &Y[((size_t)b * 3 + h) * 128];
#pragma unroll 4
    for (int k = 0; k < 128; ++k) acc += y[k] * Wg_in[k * 384 + h * 128 + c];
  }
  poi2img[b * 128 + c] = acc * (1.0f / 3.0f) + g0in[c];
}

// ===================== final fc =====================
__global__ void k_final(const float* __restrict__ img2poi, const float* __restrict__ poi_agg,
                        const float* __restrict__ poi2img, const float* __restrict__ hrs_agg,
                        const float* __restrict__ Wfc, const float* __restrict__ bfc,
                        float* __restrict__ out) {
  int i = blockIdx.x * 256 + threadIdx.x;  // 8192
  int b = i >> 4, o = i & 15;
  float acc = bfc[o];
  const float* srcs[4] = {img2poi, poi_agg, poi2img, hrs_agg};
#pragma unroll
  for (int s = 0; s < 4; ++s) {
    const float* X = srcs[s] + (size_t)b * 128;
    const float* W = Wfc + (size_t)(s * 128) * 16 + o;
#pragma unroll 4
    for (int k = 0; k < 128; ++k) acc += X[k] * W[k * 16];
  }
  out[i] = acc;
}

// ===================== host =====================
extern "C" void kernel_launch(void* const* d_in, const int* in_sizes, int n_in,
                              void* d_out, int out_size, void* d_ws, size_t ws_size,
                              hipStream_t stream) {
  const float* poi_x = (const float*)d_in[0];
  const float* img = (const float*)d_in[1];
  const int* edges = (const int*)d_in[2];
  const float* T0p = (const float*)d_in[4];
  const float* W1 = (const float*)d_in[5];
  const float* b1 = (const float*)d_in[6];
  const float* W2 = (const float*)d_in[7];
  const float* b2 = (const float*)d_in[8];
  const float* Whrs = (const float*)d_in[9];
  const float* bhrs = (const float*)d_in[10];
  const float* Wph = (const float*)d_in[11];
  const float* bph = (const float*)d_in[12];
  const float* Wpp = (const float*)d_in[13];
  const float* bpp = (const float*)d_in[14];
  const float* Wg_in = (const float*)d_in[15];
  const float* al_in = (const float*)d_in[16];
  const float* ar_in = (const float*)d_in[17];
  const float* bg_in = (const float*)d_in[18];
  const float* Wg_w = (const float*)d_in[19];
  const float* bg_w = (const float*)d_in[22];
  const float* Wh1 = (const float*)d_in[23];
  const float* bh1 = (const float*)d_in[24];
  const float* Wp1 = (const float*)d_in[25];
  const float* bp1 = (const float*)d_in[26];
  const float* Wfc = (const float*)d_in[27];
  const float* bfc = (const float*)d_in[28];

  const int* esrc = edges;
  const int* edst = edges + EE;

  char* ws = (char*)d_ws;
  size_t off = 0;
  auto alloc = [&](size_t nbytes) -> char* {
    char* p = ws + off;
    off += (nbytes + 255) & ~(size_t)255;
    return p;
  };
  int* deg = (int*)alloc((size_t)NN * 4);
  int* counts = (int*)alloc(512 * 4);
  int* offs = (int*)alloc(513 * 4);
  int* nodeoff = (int*)alloc((size_t)NN * 4);
  int* cursor = (int*)alloc((size_t)NN * 4);
  uint8_t* list8 = (uint8_t*)alloc((size_t)EE);
  float* hrs = (float*)alloc(512 * 128 * 4);
  float* ph = (float*)alloc(512 * 128 * 4);
  float* er = (float*)alloc(512 * 3 * 4);
  float* u = (float*)alloc(384 * 4);
  float* wv = (float*)alloc(384 * 4);
  float* q = (float*)alloc(384 * 4);
  float* chv = (float*)alloc(16);
  float* G = (float*)alloc(16384 * 4);
  float* g0w = (float*)alloc(128 * 4);
  float* g0in = (float*)alloc(128 * 4);
  float* pool = (float*)alloc(512 * 128 * 4);
  float* pooled = (float*)alloc((size_t)1536 * 128 * 4);
  float* Y = (float*)alloc((size_t)1536 * 128 * 4);
  float* mfn = (float*)alloc(512 * 256 * 4);
  float* dinv = (float*)alloc(512 * 4);
  float* t1b = (float*)alloc(512 * 128 * 4);
  float* t2b = (float*)alloc(512 * 128 * 4);
  float* hrs_agg = (float*)alloc(512 * 128 * 4);
  float* poi_agg = (float*)alloc(512 * 128 * 4);
  float* v_poi2img = (float*)alloc(512 * 128 * 4);
  float* v_img2poi = (float*)alloc(512 * 128 * 4);

  float* out = (float*)d_out;
  float* med = out + 512 * 16;

  hipMemsetAsync(deg, 0, (size_t)NN * 4, stream);

  size_t dynf = (16384 + 16384 + 128 + 384 + 384 + 4 + 4 + 128) * sizeof(float) + 132 * 4 + 2048;
  hipFuncSetAttribute((const void*)k_gcn_fused, hipFuncAttributeMaxDynamicSharedMemorySize,
                      (int)dynf);

  k_prep<<<1, 256, 0, stream>>>(Wg_in, al_in, ar_in, Wpp, bpp, u, wv, q, chv);
  k_prepG<<<64, 256, 0, stream>>>(Wg_w, bg_w, bg_in, G, g0w, g0in);
  k_hist<<<EE / 256, 256, 0, stream>>>(edst, deg);
  k_parcsum<<<512, 128, 0, stream>>>(deg, counts);
  k_scan<<<1, 512, 0, stream>>>(counts, offs);
  k_nodeoff<<<512, 128, 0, stream>>>(deg, offs, nodeoff, cursor);
  k_scatter<<<EE / 256, 256, 0, stream>>>(esrc, edst, cursor, list8);
  k_hrs<<<256, 512, 0, stream>>>(img, Whrs, bhrs, hrs);
  k_gemm128<<<64, 256, 0, stream>>>(hrs, Wph, bph, ph);
  k_er<<<6, 256, 0, stream>>>(ph, wv, er);
  k_gcn_fused<<<512, 1024, dynf, stream>>>(poi_x, W1, b1, W2, b2, deg, list8, nodeoff, offs, q,
                                           chv, er, hrs, pool, pooled, mfn);
  k_med<<<256, 256, 0, stream>>>(mfn, med);
  k_rowsum<<<512, 64, 0, stream>>>(med, T0p, dinv);
  k_Aagg<<<512, 256, 0, stream>>>(med, T0p, dinv, hrs, pool, t1b, t2b);
  k_gemm128<<<64, 256, 0, stream>>>(t1b, Wh1, bh1, hrs_agg);
  k_gemm128<<<64, 256, 0, stream>>>(t2b, Wp1, bp1, poi_agg);
  k_gemm128<<<192, 256, 0, stream>>>(pooled, Wpp, bpp, Y);
  k_poi2img<<<512, 128, 0, stream>>>(Y, Wg_in, g0in, v_poi2img);
  k_gemm128<<<64, 256, 0, stream>>>(ph, G, g0w, v_img2poi);
  k_final<<<32, 256, 0, stream>>>(v_img2poi, poi_agg, v_poi2img, hrs_agg, Wfc, bfc, out);

  (void)in_sizes; (void)n_in; (void)out_size; (void)ws_size;
}

// Round 6
// 325.849 us; speedup vs baseline: 3.6774x; 1.3209x over previous
//
#include <hip/hip_runtime.h>
#include <stdint.h>

#define NN 65536
#define EE 524288
#define BB 512

typedef unsigned short u16;
typedef __attribute__((ext_vector_type(8))) short s8v;    // 8 bf16 (4 VGPRs)
typedef __attribute__((ext_vector_type(4))) float f32x4;  // MFMA acc

__device__ __forceinline__ u16 f2b(float f) {
  union { float f; uint32_t u; } a{f};
  uint32_t r = a.u + 0x7fff + ((a.u >> 16) & 1);
  return (u16)(r >> 16);
}
__device__ __forceinline__ float b2f(u16 v) {
  union { uint32_t u; float f; } a{(uint32_t)v << 16};
  return a.f;
}
__device__ __forceinline__ int swz128(int r, int c) { return r * 128 + (c ^ ((r & 7) << 3)); }
__device__ __forceinline__ int swz64(int r, int c) { return r * 64 + (c ^ ((r & 7) << 3)); }

// ===================== graph prep =====================
__global__ void k_hist(const int* __restrict__ dst, int* __restrict__ deg) {
  int e = blockIdx.x * 256 + threadIdx.x;
  if (e >= EE) return;
  atomicAdd(&deg[dst[e]], 1);
}

__global__ void k_parcsum(const int* __restrict__ deg, int* __restrict__ counts) {
  __shared__ int s[128];
  int b = blockIdx.x, t = threadIdx.x;
  s[t] = deg[(b << 7) + t];
  __syncthreads();
  for (int d = 64; d > 0; d >>= 1) {
    if (t < d) s[t] += s[t + d];
    __syncthreads();
  }
  if (t == 0) counts[b] = s[0];
}

__global__ void k_scan(const int* __restrict__ counts, int* __restrict__ offs) {
  __shared__ int s[512];
  int t = threadIdx.x;
  s[t] = counts[t];
  __syncthreads();
  for (int d = 1; d < 512; d <<= 1) {
    int v = (t >= d) ? s[t - d] : 0;
    __syncthreads();
    s[t] += v;
    __syncthreads();
  }
  offs[t] = (t == 0) ? 0 : s[t - 1];
  if (t == 511) offs[512] = s[511];
}

__global__ void k_nodeoff(const int* __restrict__ deg, const int* __restrict__ offs,
                          int* __restrict__ nodeoff, int* __restrict__ cursor) {
  __shared__ int s[128];
  int b = blockIdx.x, t = threadIdx.x;
  int base = b << 7;
  int d = deg[base + t];
  s[t] = d;
  __syncthreads();
  for (int dd = 1; dd < 128; dd <<= 1) {
    int v = (t >= dd) ? s[t - dd] : 0;
    __syncthreads();
    s[t] += v;
    __syncthreads();
  }
  int excl = s[t] - d + offs[b];
  nodeoff[base + t] = excl;
  cursor[base + t] = excl;
}

__global__ void k_scatter(const int* __restrict__ src, const int* __restrict__ dst,
                          int* __restrict__ cursor, uint8_t* __restrict__ list8) {
  int e = blockIdx.x * 256 + threadIdx.x;
  if (e >= EE) return;
  int s = src[e], d = dst[e];
  int slot = atomicAdd(&cursor[d], 1);
  list8[slot] = (uint8_t)(s & 127);
}

// ===================== weight prep =====================
__global__ void k_prep(const float* __restrict__ Wg_in, const float* __restrict__ al_in,
                       const float* __restrict__ ar_in, const float* __restrict__ Wpp,
                       const float* __restrict__ bpp, float* __restrict__ u,
                       float* __restrict__ wv, float* __restrict__ q, float* __restrict__ ch) {
  int t = threadIdx.x;
  for (int i = t; i < 384; i += 256) {
    int h = i >> 7, k = i & 127;
    float su = 0.f, sw = 0.f;
#pragma unroll 4
    for (int c = 0; c < 128; ++c) {
      float g = Wg_in[k * 384 + h * 128 + c];
      su += g * al_in[h * 128 + c];
      sw += g * ar_in[h * 128 + c];
    }
    u[i] = su;
    wv[i] = sw;
  }
  __syncthreads();
  for (int i = t; i < 384; i += 256) {
    int h = i >> 7, j = i & 127;
    float s = 0.f;
#pragma unroll 4
    for (int k = 0; k < 128; ++k) s += Wpp[j * 128 + k] * u[h * 128 + k];
    q[i] = s;
  }
  if (t < 3) {
    float s = 0.f;
#pragma unroll 4
    for (int k = 0; k < 128; ++k) s += bpp[k] * u[t * 128 + k];
    ch[t] = s;
  }
}

__global__ void k_prepG(const float* __restrict__ Wg_w, const float* __restrict__ bg_w,
                        const float* __restrict__ bg_in, float* __restrict__ G,
                        float* __restrict__ g0w, float* __restrict__ g0in) {
  int i = blockIdx.x * 256 + threadIdx.x;  // 16384
  int k = i >> 7, c = i & 127;
  G[i] = (Wg_w[k * 384 + c] + Wg_w[k * 384 + 128 + c] + Wg_w[k * 384 + 256 + c]) * (1.0f / 3.0f);
  if (i < 128) {
    g0w[i] = (bg_w[i] + bg_w[128 + i] + bg_w[256 + i]) * (1.0f / 3.0f);
    g0in[i] = (bg_in[i] + bg_in[128 + i] + bg_in[256 + i]) * (1.0f / 3.0f);
  }
}

// transposed bf16 weights: w1t[n][k] (128x64), w2t[n][k] (128x128)
__global__ void k_prepW(const float* __restrict__ W1, const float* __restrict__ W2,
                        u16* __restrict__ w1t, u16* __restrict__ w2t) {
  int i = blockIdx.x * 256 + threadIdx.x;  // 96*256 = 24576
  if (i < 8192) {
    int n = i >> 6, k = i & 63;
    w1t[i] = f2b(W1[k * 128 + n]);
  } else if (i < 24576) {
    int j = i - 8192;
    int n = j >> 7, k = j & 127;
    w2t[j] = f2b(W2[k * 128 + n]);
  }
}

// ===================== hrs encoder =====================
__global__ void __launch_bounds__(512) k_hrs(const float* __restrict__ img,
                                             const float* __restrict__ Whrs,
                                             const float* __restrict__ bhrs,
                                             float* __restrict__ hrs) {
  __shared__ float sI[4096];
  __shared__ float sRed[4][128];
  int r0 = blockIdx.x * 2;
  int t = threadIdx.x;
  const float4* gsrc = (const float4*)(img + (size_t)r0 * 2048);
  float4* ldst = (float4*)sI;
  for (int i = t; i < 1024; i += 512) ldst[i] = gsrc[i];
  __syncthreads();
  int c = t & 127, g = t >> 7;
  int row = g & 1, ks = g >> 1;
  const float* s = sI + row * 2048 + ks * 1024;
  const float* W = Whrs + (size_t)(ks * 1024) * 128 + c;
  float a0 = 0.f, a1 = 0.f, a2 = 0.f, a3 = 0.f;
  for (int k = 0; k < 1024; k += 4) {
    a0 += s[k] * W[(size_t)k * 128];
    a1 += s[k + 1] * W[(size_t)(k + 1) * 128];
    a2 += s[k + 2] * W[(size_t)(k + 2) * 128];
    a3 += s[k + 3] * W[(size_t)(k + 3) * 128];
  }
  sRed[g][c] = (a0 + a1) + (a2 + a3);
  __syncthreads();
  if (t < 256) {
    int rr = t >> 7, cc = t & 127;
    hrs[(r0 + rr) * 128 + cc] = sRed[rr][cc] + sRed[rr + 2][cc] + bhrs[cc];
  }
}

// ===================== generic C[M,128] = X[M,128] @ W[128,128] + bias =====================
__global__ void k_gemm128(const float* __restrict__ X, const float* __restrict__ W,
                          const float* __restrict__ bias, float* __restrict__ C) {
  __shared__ float sX[8 * 128];
  int r0 = blockIdx.x * 8;
  int t = threadIdx.x;
  for (int i = t; i < 1024; i += 256) sX[i] = X[(size_t)r0 * 128 + i];
  __syncthreads();
  int c = t & 127, rh = t >> 7;
  float b = bias[c];
  float a0 = b, a1 = b, a2 = b, a3 = b;
  const float* s = sX + (rh * 4) * 128;
  for (int k = 0; k < 128; ++k) {
    float w = W[k * 128 + c];
    a0 += s[k] * w;
    a1 += s[128 + k] * w;
    a2 += s[256 + k] * w;
    a3 += s[384 + k] * w;
  }
  int rb = r0 + rh * 4;
  C[(size_t)(rb + 0) * 128 + c] = a0;
  C[(size_t)(rb + 1) * 128 + c] = a1;
  C[(size_t)(rb + 2) * 128 + c] = a2;
  C[(size_t)(rb + 3) * 128 + c] = a3;
}

__global__ void k_er(const float* __restrict__ ph, const float* __restrict__ wv,
                     float* __restrict__ er) {
  int i = blockIdx.x * 256 + threadIdx.x;
  if (i >= BB * 3) return;
  int b = i / 3, h = i % 3;
  float s = 0.f;
#pragma unroll 4
  for (int k = 0; k < 128; ++k) s += ph[b * 128 + k] * wv[h * 128 + k];
  er[i] = s;
}

// ===================== FUSED GCN via dense S' + MFMA (one block per parcel) =================
// S'[r][s] = norm[r]*norm[s]*(cnt(s->r) + [r==s]);  agg = S' @ X  (all norms/self-loop folded)
// LDS byte offsets:
//   0      sS    u16[16384]  S' (later sP = poi_node bf16)
//   32768  sB2   u16[16384]  h1^T (feature-major)
//   65536  sXt   u16[8192]   X^T bf16   } later sAgg2 u16[16384] spans 65536..98304
//   81920  sAgg1 u16[8192]
//   98304  sW1t  u16[8192]
//   114688 sXrm  f32[8320]   staging [128][65]; later sW2t u16[16384]
//   147968 sNorm f32[128]; 148480 sQ f32[384]; 150016 sAl f32[384];
//   151552 sPool f32[128]; 152064 sEr f32[4]; 152080 sCh f32[4]
__global__ void __launch_bounds__(512) k_gcn_fused(
    const float* __restrict__ x, const float* __restrict__ b1, const float* __restrict__ b2,
    const int* __restrict__ deg, const uint8_t* __restrict__ g_list,
    const int* __restrict__ nodeoff, const float* __restrict__ q, const float* __restrict__ ch,
    const float* __restrict__ er, const float* __restrict__ hrs,
    const u16* __restrict__ w1t, const u16* __restrict__ w2t, float* __restrict__ poi_pool,
    float* __restrict__ pooled, float* __restrict__ mfn) {
  extern __shared__ char sm[];
  u16* sS = (u16*)sm;
  u16* sB2 = (u16*)(sm + 32768);
  u16* sXt = (u16*)(sm + 65536);
  u16* sAgg1 = (u16*)(sm + 81920);
  u16* sW1t = (u16*)(sm + 98304);
  float* sXrm = (float*)(sm + 114688);
  u16* sW2t = (u16*)(sm + 114688);
  u16* sAgg2 = (u16*)(sm + 65536);
  u16* sP = (u16*)sm;
  float* sNorm = (float*)(sm + 147968);
  float* sQ = (float*)(sm + 148480);
  float* sAl = (float*)(sm + 150016);
  float* sPool = (float*)(sm + 151552);
  float* sEr = (float*)(sm + 152064);
  float* sCh = (float*)(sm + 152080);

  int b = blockIdx.x, t = threadIdx.x;
  int base = b << 7;
  int l = t & 63, w = t >> 6;

  // ---- phase 0: norms, zero S, stage Xrm (row-major f32, pad 65), W1t, q/er/ch ----
  if (t < 128) sNorm[t] = rsqrtf((float)deg[base + t] + 1.0f);
  for (int i = t; i < 8192; i += 512) ((uint32_t*)sS)[i] = 0;
  for (int i = t; i < 8192; i += 512) {
    int s = i >> 6, f = i & 63;
    sXrm[s * 65 + f] = x[(size_t)(base + s) * 64 + f];
  }
  for (int g = t; g < 1024; g += 512) {
    int n = g >> 3, blk = g & 7;
    *(uint4*)(sW1t + n * 64 + ((blk ^ (n & 7)) << 3)) = ((const uint4*)w1t)[g];
  }
  for (int i = t; i < 384; i += 512) sQ[i] = q[i];
  if (t < 3) {
    sEr[t] = er[b * 3 + t];
    sCh[t] = ch[t];
  }
  __syncthreads();

  // ---- phase 1: S counts (one thread per row, no races) + X transpose->bf16 (norm folded) --
  if (t < 128) {
    int r = t;
    int st = nodeoff[base + r];
    int dg = deg[base + r];
    int sw = (r & 7) << 3;
    for (int e = st; e < st + dg; ++e) {
      int ls = (int)g_list[e];
      sS[r * 128 + (ls ^ sw)] += 1;  // raw int count in u16
    }
  }
  for (int i = t; i < 4096; i += 512) {
    int f = i >> 6, s = (i & 63) * 2;
    float v0 = sXrm[s * 65 + f] * sNorm[s];
    float v1 = sXrm[(s + 1) * 65 + f] * sNorm[s + 1];
    uint32_t pk = (uint32_t)f2b(v0) | ((uint32_t)f2b(v1) << 16);
    *(uint32_t*)(sXt + (f * 128 + (s ^ ((f & 7) << 3)))) = pk;
  }
  __syncthreads();

  // ---- phase 2: scale S' to bf16; stage W2t (over dead sXrm) ----
  for (int i = t; i < 16384; i += 512) {
    int r = i >> 7, cp = i & 127;
    int s = cp ^ ((r & 7) << 3);
    float val = ((float)sS[i] + (r == s ? 1.f : 0.f)) * sNorm[r] * sNorm[s];
    sS[i] = f2b(val);
  }
  for (int g = t; g < 2048; g += 512) {
    int n = g >> 4, blk = g & 15;
    *(uint4*)(sW2t + n * 128 + ((blk ^ (n & 7)) << 3)) = ((const uint4*)w2t)[g];
  }
  __syncthreads();

  int mrow = w * 16 + (l & 15);
  int kblk = (l >> 4) * 8;
  int rbase = w * 16 + (l >> 4) * 4;

  // ---- phase 3: agg1 = S'(128x128) @ X(128x64) -> sAgg1 bf16 ----
  for (int nt = 0; nt < 4; ++nt) {
    f32x4 acc = {0.f, 0.f, 0.f, 0.f};
    int cg = nt * 16 + (l & 15);
#pragma unroll
    for (int ks = 0; ks < 4; ++ks) {
      int kc = ks * 32 + kblk;
      s8v a = *(const s8v*)(sS + swz128(mrow, kc));
      s8v bf = *(const s8v*)(sXt + swz128(cg, kc));
      acc = __builtin_amdgcn_mfma_f32_16x16x32_bf16(a, bf, acc, 0, 0, 0);
    }
#pragma unroll
    for (int rg = 0; rg < 4; ++rg) sAgg1[swz64(rbase + rg, cg)] = f2b(acc[rg]);
  }
  __syncthreads();

  // ---- phase 4: h1 = relu(agg1(128x64) @ W1 + b1) -> transposed bf16 into sB2 ----
  for (int nt = 0; nt < 8; ++nt) {
    int cg = nt * 16 + (l & 15);
    float bv = b1[cg];
    f32x4 acc = {bv, bv, bv, bv};
#pragma unroll
    for (int ks = 0; ks < 2; ++ks) {
      int kc = ks * 32 + kblk;
      s8v a = *(const s8v*)(sAgg1 + swz64(mrow, kc));
      s8v bf = *(const s8v*)(sW1t + swz64(cg, kc));
      acc = __builtin_amdgcn_mfma_f32_16x16x32_bf16(a, bf, acc, 0, 0, 0);
    }
    u16 h0 = f2b(fmaxf(acc[0], 0.f)), h1v = f2b(fmaxf(acc[1], 0.f));
    u16 h2 = f2b(fmaxf(acc[2], 0.f)), h3 = f2b(fmaxf(acc[3], 0.f));
    uint2 pk;
    pk.x = (uint32_t)h0 | ((uint32_t)h1v << 16);
    pk.y = (uint32_t)h2 | ((uint32_t)h3 << 16);
    *(uint2*)(sB2 + swz128(cg, rbase)) = pk;  // h1t[n][m..m+3]
  }
  __syncthreads();

  // ---- phase 5: agg2 = S' @ h1 (B = h1t) -> sAgg2 bf16 (over dead sXt+sAgg1) ----
  for (int nt = 0; nt < 8; ++nt) {
    f32x4 acc = {0.f, 0.f, 0.f, 0.f};
    int cg = nt * 16 + (l & 15);
#pragma unroll
    for (int ks = 0; ks < 4; ++ks) {
      int kc = ks * 32 + kblk;
      s8v a = *(const s8v*)(sS + swz128(mrow, kc));
      s8v bf = *(const s8v*)(sB2 + swz128(cg, kc));
      acc = __builtin_amdgcn_mfma_f32_16x16x32_bf16(a, bf, acc, 0, 0, 0);
    }
#pragma unroll
    for (int rg = 0; rg < 4; ++rg) sAgg2[swz128(rbase + rg, cg)] = f2b(acc[rg]);
  }
  __syncthreads();

  // ---- phase 6: poi = agg2 @ W2 + b2 -> sP (over dead sS) ----
  for (int nt = 0; nt < 8; ++nt) {
    int cg = nt * 16 + (l & 15);
    float bv = b2[cg];
    f32x4 acc = {bv, bv, bv, bv};
#pragma unroll
    for (int ks = 0; ks < 4; ++ks) {
      int kc = ks * 32 + kblk;
      s8v a = *(const s8v*)(sAgg2 + swz128(mrow, kc));
      s8v bf = *(const s8v*)(sW2t + swz128(cg, kc));
      acc = __builtin_amdgcn_mfma_f32_16x16x32_bf16(a, bf, acc, 0, 0, 0);
    }
#pragma unroll
    for (int rg = 0; rg < 4; ++rg) sP[swz128(rbase + rg, cg)] = f2b(acc[rg]);
  }
  __syncthreads();

  // ---- tail: pool + el ----
  if (t < 128) {
    float s = 0.f;
    for (int r = 0; r < 128; ++r) s += b2f(sP[r * 128 + (t ^ ((r & 7) << 3))]);
    sPool[t] = s;
    poi_pool[b * 128 + t] = s * (1.0f / 128.0f);
  }
  if (t < 384) {
    int r = t & 127, h = t >> 7;
    int sw = (r & 7) << 3;
    float d = 0.f;
    const float* qh = &sQ[h * 128];
    for (int c = 0; c < 128; ++c) d += b2f(sP[r * 128 + (c ^ sw)]) * qh[c];
    float e = d + sCh[h] + sEr[h];
    sAl[h * 128 + r] = (e > 0.f) ? e : 0.2f * e;
  }
  __syncthreads();

  if (t < 192) {
    int h = t >> 6, ll = t & 63;
    float v0 = sAl[h * 128 + ll], v1 = sAl[h * 128 + 64 + ll];
    float m = fmaxf(v0, v1);
    for (int off = 32; off > 0; off >>= 1) m = fmaxf(m, __shfl_xor(m, off));
    float x0 = __expf(v0 - m), x1 = __expf(v1 - m);
    float s = x0 + x1;
    for (int off = 32; off > 0; off >>= 1) s += __shfl_xor(s, off);
    float inv = 1.0f / s;
    sAl[h * 128 + ll] = x0 * inv;
    sAl[h * 128 + 64 + ll] = x1 * inv;
  }
  __syncthreads();

  if (t < 384) {
    int hh = t >> 7, c = t & 127;
    float s = 0.f;
    const float* al = &sAl[hh * 128];
    for (int r = 0; r < 128; ++r) s += al[r] * b2f(sP[r * 128 + (c ^ ((r & 7) << 3))]);
    pooled[((size_t)b * 3 + hh) * 128 + c] = s;
  }
  __syncthreads();

  // ---- fused mfn ----
  float hv = 0.f, pv = 0.f;
  if (t < 128) {
    hv = hrs[base + t];
    pv = sPool[t] * (1.0f / 128.0f);
    sQ[t] = hv * hv + pv * pv;
  }
  __syncthreads();
  if (t < 64) {
    float v = sQ[t] + sQ[t + 64];
    for (int off = 32; off > 0; off >>= 1) v += __shfl_xor(v, off);
    if (t == 0) sQ[0] = rsqrtf(v);
  }
  __syncthreads();
  if (t < 128) {
    float rn = sQ[0];
    mfn[b * 256 + t] = hv * rn;
    mfn[b * 256 + 128 + t] = pv * rn;
  }
}

// ===================== med pipeline =====================
__global__ void k_med(const float* __restrict__ mfn, float* __restrict__ med) {
  __shared__ float sI[32 * 64];
  __shared__ float sJ[32 * 64];
  int bi = blockIdx.x >> 4, bj = blockIdx.x & 15;
  int t = threadIdx.x;
  int ti = t >> 4, tj = t & 15;
  float acc[2][2] = {};
  for (int k0 = 0; k0 < 256; k0 += 64) {
    __syncthreads();
    for (int i = t; i < 2048; i += 256) {
      int r = i >> 6, k = i & 63;
      int idx = (r << 6) | (k ^ (r & 31));
      sI[idx] = mfn[(bi * 32 + r) * 256 + k0 + k];
      sJ[idx] = mfn[(bj * 32 + r) * 256 + k0 + k];
    }
    __syncthreads();
    for (int k = 0; k < 64; ++k) {
      float a[2], c2[2];
#pragma unroll
      for (int ii = 0; ii < 2; ++ii) a[ii] = sI[((ti * 2 + ii) << 6) | (k ^ ((ti * 2 + ii) & 31))];
#pragma unroll
      for (int jj = 0; jj < 2; ++jj) c2[jj] = sJ[((tj * 2 + jj) << 6) | (k ^ ((tj * 2 + jj) & 31))];
#pragma unroll
      for (int ii = 0; ii < 2; ++ii)
#pragma unroll
        for (int jj = 0; jj < 2; ++jj) acc[ii][jj] += a[ii] * c2[jj];
    }
  }
#pragma unroll
  for (int ii = 0; ii < 2; ++ii)
#pragma unroll
    for (int jj = 0; jj < 2; ++jj)
      med[(size_t)(bi * 32 + ti * 2 + ii) * 512 + bj * 32 + tj * 2 + jj] =
          (acc[ii][jj] + 1.0f) * 0.5f;
}

__global__ void k_rowsum(const float* __restrict__ med, const float* __restrict__ T0p,
                         float* __restrict__ dinv) {
  int r = blockIdx.x, l = threadIdx.x;
  float T0 = *T0p;
  float cnt = 0.f;
  for (int j = l; j < 512; j += 64) cnt += ((med[(size_t)r * 512 + j] >= T0) || (j == r)) ? 1.0f : 0.0f;
  for (int off = 32; off > 0; off >>= 1) cnt += __shfl_xor(cnt, off);
  if (l == 0) dinv[r] = rsqrtf(cnt);
}

__global__ void k_Aagg(const float* __restrict__ med, const float* __restrict__ T0p,
                       const float* __restrict__ dinv, const float* __restrict__ hrs,
                       const float* __restrict__ pool, float* __restrict__ t1,
                       float* __restrict__ t2) {
  int i = blockIdx.x, t = threadIdx.x;
  int c = t & 127, half = t >> 7;
  float T0 = *T0p;
  const float* srcm = half ? pool : hrs;
  float acc = 0.f;
  for (int j = 0; j < 512; ++j) {
    float m = med[(size_t)i * 512 + j];
    if (m >= T0 || j == i) acc += dinv[j] * srcm[j * 128 + c];
  }
  float v = acc * dinv[i];
  if (half)
    t2[i * 128 + c] = v;
  else
    t1[i * 128 + c] = v;
}

__global__ void k_poi2img(const float* __restrict__ Y, const float* __restrict__ Wg_in,
                          const float* __restrict__ g0in, float* __restrict__ poi2img) {
  int b = blockIdx.x, c = threadIdx.x;
  float acc = 0.f;
  for (int h = 0; h < 3; ++h) {
    const float* y = &Y[((size_t)b * 3 + h) * 128];
#pragma unroll 4
    for (int k = 0; k < 128; ++k) acc += y[k] * Wg_in[k * 384 + h * 128 + c];
  }
  poi2img[b * 128 + c] = acc * (1.0f / 3.0f) + g0in[c];
}

__global__ void k_final(const float* __restrict__ img2poi, const float* __restrict__ poi_agg,
                        const float* __restrict__ poi2img, const float* __restrict__ hrs_agg,
                        const float* __restrict__ Wfc, const float* __restrict__ bfc,
                        float* __restrict__ out) {
  int i = blockIdx.x * 256 + threadIdx.x;
  int b = i >> 4, o = i & 15;
  float acc = bfc[o];
  const float* srcs[4] = {img2poi, poi_agg, poi2img, hrs_agg};
#pragma unroll
  for (int s = 0; s < 4; ++s) {
    const float* X = srcs[s] + (size_t)b * 128;
    const float* W = Wfc + (size_t)(s * 128) * 16 + o;
#pragma unroll 4
    for (int k = 0; k < 128; ++k) acc += X[k] * W[k * 16];
  }
  out[i] = acc;
}

// ===================== host =====================
extern "C" void kernel_launch(void* const* d_in, const int* in_sizes, int n_in,
                              void* d_out, int out_size, void* d_ws, size_t ws_size,
                              hipStream_t stream) {
  const float* poi_x = (const float*)d_in[0];
  const float* img = (const float*)d_in[1];
  const int* edges = (const int*)d_in[2];
  const float* T0p = (const float*)d_in[4];
  const float* W1 = (const float*)d_in[5];
  const float* b1 = (const float*)d_in[6];
  const float* W2 = (const float*)d_in[7];
  const float* b2 = (const float*)d_in[8];
  const float* Whrs = (const float*)d_in[9];
  const float* bhrs = (const float*)d_in[10];
  const float* Wph = (const float*)d_in[11];
  const float* bph = (const float*)d_in[12];
  const float* Wpp = (const float*)d_in[13];
  const float* bpp = (const float*)d_in[14];
  const float* Wg_in = (const float*)d_in[15];
  const float* al_in = (const float*)d_in[16];
  const float* ar_in = (const float*)d_in[17];
  const float* bg_in = (const float*)d_in[18];
  const float* Wg_w = (const float*)d_in[19];
  const float* bg_w = (const float*)d_in[22];
  const float* Wh1 = (const float*)d_in[23];
  const float* bh1 = (const float*)d_in[24];
  const float* Wp1 = (const float*)d_in[25];
  const float* bp1 = (const float*)d_in[26];
  const float* Wfc = (const float*)d_in[27];
  const float* bfc = (const float*)d_in[28];

  const int* esrc = edges;
  const int* edst = edges + EE;

  char* ws = (char*)d_ws;
  size_t off = 0;
  auto alloc = [&](size_t nbytes) -> char* {
    char* p = ws + off;
    off += (nbytes + 255) & ~(size_t)255;
    return p;
  };
  int* deg = (int*)alloc((size_t)NN * 4);
  int* counts = (int*)alloc(512 * 4);
  int* offs = (int*)alloc(513 * 4);
  int* nodeoff = (int*)alloc((size_t)NN * 4);
  int* cursor = (int*)alloc((size_t)NN * 4);
  uint8_t* list8 = (uint8_t*)alloc((size_t)EE);
  u16* w1t = (u16*)alloc(8192 * 2);
  u16* w2t = (u16*)alloc(16384 * 2);
  float* hrs = (float*)alloc(512 * 128 * 4);
  float* ph = (float*)alloc(512 * 128 * 4);
  float* er = (float*)alloc(512 * 3 * 4);
  float* u = (float*)alloc(384 * 4);
  float* wv = (float*)alloc(384 * 4);
  float* q = (float*)alloc(384 * 4);
  float* chv = (float*)alloc(16);
  float* G = (float*)alloc(16384 * 4);
  float* g0w = (float*)alloc(128 * 4);
  float* g0in = (float*)alloc(128 * 4);
  float* pool = (float*)alloc(512 * 128 * 4);
  float* pooled = (float*)alloc((size_t)1536 * 128 * 4);
  float* Y = (float*)alloc((size_t)1536 * 128 * 4);
  float* mfn = (float*)alloc(512 * 256 * 4);
  float* dinv = (float*)alloc(512 * 4);
  float* t1b = (float*)alloc(512 * 128 * 4);
  float* t2b = (float*)alloc(512 * 128 * 4);
  float* hrs_agg = (float*)alloc(512 * 128 * 4);
  float* poi_agg = (float*)alloc(512 * 128 * 4);
  float* v_poi2img = (float*)alloc(512 * 128 * 4);
  float* v_img2poi = (float*)alloc(512 * 128 * 4);

  float* out = (float*)d_out;
  float* med = out + 512 * 16;

  hipMemsetAsync(deg, 0, (size_t)NN * 4, stream);

  size_t dynf = 152096;
  hipFuncSetAttribute((const void*)k_gcn_fused, hipFuncAttributeMaxDynamicSharedMemorySize,
                      (int)dynf);

  k_prep<<<1, 256, 0, stream>>>(Wg_in, al_in, ar_in, Wpp, bpp, u, wv, q, chv);
  k_prepG<<<64, 256, 0, stream>>>(Wg_w, bg_w, bg_in, G, g0w, g0in);
  k_prepW<<<96, 256, 0, stream>>>(W1, W2, w1t, w2t);
  k_hist<<<EE / 256, 256, 0, stream>>>(edst, deg);
  k_parcsum<<<512, 128, 0, stream>>>(deg, counts);
  k_scan<<<1, 512, 0, stream>>>(counts, offs);
  k_nodeoff<<<512, 128, 0, stream>>>(deg, offs, nodeoff, cursor);
  k_scatter<<<EE / 256, 256, 0, stream>>>(esrc, edst, cursor, list8);
  k_hrs<<<256, 512, 0, stream>>>(img, Whrs, bhrs, hrs);
  k_gemm128<<<64, 256, 0, stream>>>(hrs, Wph, bph, ph);
  k_er<<<6, 256, 0, stream>>>(ph, wv, er);
  k_gcn_fused<<<512, 512, dynf, stream>>>(poi_x, b1, b2, deg, list8, nodeoff, q, chv, er, hrs,
                                          w1t, w2t, pool, pooled, mfn);
  k_med<<<256, 256, 0, stream>>>(mfn, med);
  k_rowsum<<<512, 64, 0, stream>>>(med, T0p, dinv);
  k_Aagg<<<512, 256, 0, stream>>>(med, T0p, dinv, hrs, pool, t1b, t2b);
  k_gemm128<<<64, 256, 0, stream>>>(t1b, Wh1, bh1, hrs_agg);
  k_gemm128<<<64, 256, 0, stream>>>(t2b, Wp1, bp1, poi_agg);
  k_gemm128<<<192, 256, 0, stream>>>(pooled, Wpp, bpp, Y);
  k_poi2img<<<512, 128, 0, stream>>>(Y, Wg_in, g0in, v_poi2img);
  k_gemm128<<<64, 256, 0, stream>>>(ph, G, g0w, v_img2poi);
  k_final<<<32, 256, 0, stream>>>(v_img2poi, poi_agg, v_poi2img, hrs_agg, Wfc, bfc, out);

  (void)in_sizes; (void)n_in; (void)out_size; (void)ws_size;
}

// Round 7
// 268.545 us; speedup vs baseline: 4.4622x; 1.2134x over previous
//
#include <hip/hip_runtime.h>
#include <stdint.h>

#define NN 65536
#define EE 524288
#define BB 512

typedef unsigned short u16;
typedef __attribute__((ext_vector_type(8))) short s8v;    // 8 bf16 (4 VGPRs)
typedef __attribute__((ext_vector_type(4))) float f32x4;  // MFMA acc

__device__ __forceinline__ u16 f2b(float f) {
  union { float f; uint32_t u; } a{f};
  uint32_t r = a.u + 0x7fff + ((a.u >> 16) & 1);
  return (u16)(r >> 16);
}
__device__ __forceinline__ float b2f(u16 v) {
  union { uint32_t u; float f; } a{(uint32_t)v << 16};
  return a.f;
}
__device__ __forceinline__ int swz128(int r, int c) { return r * 128 + (c ^ ((r & 7) << 3)); }
__device__ __forceinline__ int swz64(int r, int c) { return r * 64 + (c ^ ((r & 7) << 3)); }

// ===================== graph prep =====================
__global__ void k_hist(const int* __restrict__ dst, int* __restrict__ deg) {
  int e = blockIdx.x * 256 + threadIdx.x;
  if (e >= EE) return;
  atomicAdd(&deg[dst[e]], 1);
}

__global__ void k_parcsum(const int* __restrict__ deg, int* __restrict__ counts) {
  __shared__ int s[128];
  int b = blockIdx.x, t = threadIdx.x;
  s[t] = deg[(b << 7) + t];
  __syncthreads();
  for (int d = 64; d > 0; d >>= 1) {
    if (t < d) s[t] += s[t + d];
    __syncthreads();
  }
  if (t == 0) counts[b] = s[0];
}

__global__ void k_scan(const int* __restrict__ counts, int* __restrict__ offs) {
  __shared__ int s[512];
  int t = threadIdx.x;
  s[t] = counts[t];
  __syncthreads();
  for (int d = 1; d < 512; d <<= 1) {
    int v = (t >= d) ? s[t - d] : 0;
    __syncthreads();
    s[t] += v;
    __syncthreads();
  }
  offs[t] = (t == 0) ? 0 : s[t - 1];
  if (t == 511) offs[512] = s[511];
}

__global__ void k_nodeoff(const int* __restrict__ deg, const int* __restrict__ offs,
                          int* __restrict__ nodeoff, int* __restrict__ cursor) {
  __shared__ int s[128];
  int b = blockIdx.x, t = threadIdx.x;
  int base = b << 7;
  int d = deg[base + t];
  s[t] = d;
  __syncthreads();
  for (int dd = 1; dd < 128; dd <<= 1) {
    int v = (t >= dd) ? s[t - dd] : 0;
    __syncthreads();
    s[t] += v;
    __syncthreads();
  }
  int excl = s[t] - d + offs[b];
  nodeoff[base + t] = excl;
  cursor[base + t] = excl;
}

__global__ void k_scatter(const int* __restrict__ src, const int* __restrict__ dst,
                          int* __restrict__ cursor, uint8_t* __restrict__ list8) {
  int e = blockIdx.x * 256 + threadIdx.x;
  if (e >= EE) return;
  int s = src[e], d = dst[e];
  int slot = atomicAdd(&cursor[d], 1);
  list8[slot] = (uint8_t)(s & 127);
}

// ===================== merged weight prep =====================
// blocks 0..63: G mean; blocks 64..159: W1/W2 transpose->bf16; block 160: u/wv/q/ch
__global__ void k_prepAll(const float* __restrict__ Wg_w, const float* __restrict__ bg_w,
                          const float* __restrict__ bg_in, const float* __restrict__ W1,
                          const float* __restrict__ W2, const float* __restrict__ Wg_in,
                          const float* __restrict__ al_in, const float* __restrict__ ar_in,
                          const float* __restrict__ Wpp, const float* __restrict__ bpp,
                          float* __restrict__ G, float* __restrict__ g0w,
                          float* __restrict__ g0in, u16* __restrict__ w1t,
                          u16* __restrict__ w2t, float* __restrict__ u, float* __restrict__ wv,
                          float* __restrict__ q, float* __restrict__ ch) {
  int blk = blockIdx.x, t = threadIdx.x;
  if (blk < 64) {
    int i = blk * 256 + t;  // 16384
    int k = i >> 7, c = i & 127;
    G[i] = (Wg_w[k * 384 + c] + Wg_w[k * 384 + 128 + c] + Wg_w[k * 384 + 256 + c]) *
           (1.0f / 3.0f);
    if (i < 128) {
      g0w[i] = (bg_w[i] + bg_w[128 + i] + bg_w[256 + i]) * (1.0f / 3.0f);
      g0in[i] = (bg_in[i] + bg_in[128 + i] + bg_in[256 + i]) * (1.0f / 3.0f);
    }
  } else if (blk < 160) {
    int i = (blk - 64) * 256 + t;  // 24576
    if (i < 8192) {
      int n = i >> 6, k = i & 63;
      w1t[i] = f2b(W1[k * 128 + n]);
    } else {
      int j = i - 8192;
      int n = j >> 7, k = j & 127;
      w2t[j] = f2b(W2[k * 128 + n]);
    }
  } else {
    __shared__ float su[384];
    for (int i = t; i < 384; i += 256) {
      int h = i >> 7, k = i & 127;
      float s = 0.f, sw = 0.f;
#pragma unroll 4
      for (int c = 0; c < 128; ++c) {
        float g = Wg_in[k * 384 + h * 128 + c];
        s += g * al_in[h * 128 + c];
        sw += g * ar_in[h * 128 + c];
      }
      su[i] = s;
      u[i] = s;
      wv[i] = sw;
    }
    __syncthreads();
    for (int i = t; i < 384; i += 256) {
      int h = i >> 7, j = i & 127;
      float s = 0.f;
#pragma unroll 4
      for (int k = 0; k < 128; ++k) s += Wpp[j * 128 + k] * su[h * 128 + k];
      q[i] = s;
    }
    if (t < 3) {
      float s = 0.f;
#pragma unroll 4
      for (int k = 0; k < 128; ++k) s += bpp[k] * su[t * 128 + k];
      ch[t] = s;
    }
  }
}

// ===================== hrs encoder + ph + er (fused) =====================
__global__ void __launch_bounds__(512) k_hrs(const float* __restrict__ img,
                                             const float* __restrict__ Whrs,
                                             const float* __restrict__ bhrs,
                                             const float* __restrict__ Wph,
                                             const float* __restrict__ bph,
                                             const float* __restrict__ wv,
                                             float* __restrict__ hrs, float* __restrict__ ph,
                                             float* __restrict__ er) {
  __shared__ float sI[4096];
  __shared__ float sRed[4][128];
  __shared__ float sHrs[2][128];
  __shared__ float sPh[2][128];
  int r0 = blockIdx.x * 2;
  int t = threadIdx.x;
  const float4* gsrc = (const float4*)(img + (size_t)r0 * 2048);
  float4* ldst = (float4*)sI;
  for (int i = t; i < 1024; i += 512) ldst[i] = gsrc[i];
  __syncthreads();
  int c = t & 127, g = t >> 7;
  int row = g & 1, ks = g >> 1;
  const float* s = sI + row * 2048 + ks * 1024;
  const float* W = Whrs + (size_t)(ks * 1024) * 128 + c;
  float a0 = 0.f, a1 = 0.f, a2 = 0.f, a3 = 0.f;
  for (int k = 0; k < 1024; k += 4) {
    a0 += s[k] * W[(size_t)k * 128];
    a1 += s[k + 1] * W[(size_t)(k + 1) * 128];
    a2 += s[k + 2] * W[(size_t)(k + 2) * 128];
    a3 += s[k + 3] * W[(size_t)(k + 3) * 128];
  }
  sRed[g][c] = (a0 + a1) + (a2 + a3);
  __syncthreads();
  if (t < 256) {
    int rr = t >> 7, cc = t & 127;
    float v = sRed[rr][cc] + sRed[rr + 2][cc] + bhrs[cc];
    hrs[(r0 + rr) * 128 + cc] = v;
    sHrs[rr][cc] = v;
  }
  __syncthreads();
  if (t < 256) {
    int rr = t >> 7, cc = t & 127;
    float acc = bph[cc];
#pragma unroll 4
    for (int k = 0; k < 128; ++k) acc += sHrs[rr][k] * Wph[k * 128 + cc];
    sPh[rr][cc] = acc;
    ph[(r0 + rr) * 128 + cc] = acc;
  }
  __syncthreads();
  if (t < 6) {
    int rr = t / 3, h = t % 3;
    float s2 = 0.f;
#pragma unroll 4
    for (int k = 0; k < 128; ++k) s2 += sPh[rr][k] * wv[h * 128 + k];
    er[(r0 + rr) * 3 + h] = s2;
  }
}

// ===================== FUSED GCN via dense S' + MFMA =====================
// LDS byte offsets:
//   0      sScnt u16[128*132] (count phase, pad-132) / sS u16[16384] swizzled bf16 / sP
//   32768  sB2  u16[16384] h1^T, later sPt (P^T)
//   65536  sXt  u16[8192]; 65536.. sAgg2 u16[16384]
//   81920  sAgg1 u16[8192]
//   98304  sW1t u16[8192]
//   114688 sXrm f32[8320] staging; later sW2t u16[16384]
//   147968 sNorm f32[128]; 148480 sQ f32[384]; 150016 sAl f32[384];
//   151552 sPool f32[128]; 152064 sEr f32[4]; 152080 sCh f32[4]
__global__ void __launch_bounds__(512) k_gcn_fused(
    const float* __restrict__ x, const float* __restrict__ b1, const float* __restrict__ b2,
    const int* __restrict__ deg, const uint8_t* __restrict__ g_list,
    const int* __restrict__ nodeoff, const float* __restrict__ q, const float* __restrict__ ch,
    const float* __restrict__ er, const float* __restrict__ hrs,
    const u16* __restrict__ w1t, const u16* __restrict__ w2t, float* __restrict__ poi_pool,
    float* __restrict__ pooled, float* __restrict__ mfn) {
  extern __shared__ char sm[];
  u16* sS = (u16*)sm;
  u16* sScnt = (u16*)sm;  // pad-132 layout during counting
  u16* sB2 = (u16*)(sm + 32768);
  u16* sPt = (u16*)(sm + 32768);
  u16* sXt = (u16*)(sm + 65536);
  u16* sAgg1 = (u16*)(sm + 81920);
  u16* sW1t = (u16*)(sm + 98304);
  float* sXrm = (float*)(sm + 114688);
  u16* sW2t = (u16*)(sm + 114688);
  u16* sAgg2 = (u16*)(sm + 65536);
  u16* sP = (u16*)sm;
  float* sNorm = (float*)(sm + 147968);
  float* sQ = (float*)(sm + 148480);
  float* sAl = (float*)(sm + 150016);
  float* sPool = (float*)(sm + 151552);
  float* sEr = (float*)(sm + 152064);
  float* sCh = (float*)(sm + 152080);

  int b = blockIdx.x, t = threadIdx.x;
  int base = b << 7;
  int l = t & 63, w = t >> 6;

  // ---- phase 0: norms, zero counts, stage Xrm, W1t, q/er/ch ----
  if (t < 128) sNorm[t] = rsqrtf((float)deg[base + t] + 1.0f);
  for (int i = t; i < 8448; i += 512) ((uint32_t*)sScnt)[i] = 0;  // 128*132 u16
  for (int i = t; i < 8192; i += 512) {
    int s = i >> 6, f = i & 63;
    sXrm[s * 65 + f] = x[(size_t)(base + s) * 64 + f];
  }
  for (int g = t; g < 1024; g += 512) {
    int n = g >> 3, blk = g & 7;
    *(uint4*)(sW1t + n * 64 + ((blk ^ (n & 7)) << 3)) = ((const uint4*)w1t)[g];
  }
  for (int i = t; i < 384; i += 512) sQ[i] = q[i];
  if (t < 3) {
    sEr[t] = er[b * 3 + t];
    sCh[t] = ch[t];
  }
  __syncthreads();

  // ---- phase 1: counts (pad-132, one thread/row) + X transpose->bf16 ----
  if (t < 128) {
    int r = t;
    int st = nodeoff[base + r];
    int dg = deg[base + r];
    u16* rowp = sScnt + r * 132;
    for (int e = st; e < st + dg; ++e) rowp[(int)g_list[e]] += 1;
  }
  for (int i = t; i < 4096; i += 512) {
    int f = i >> 6, s = (i & 63) * 2;
    float v0 = sXrm[s * 65 + f] * sNorm[s];
    float v1 = sXrm[(s + 1) * 65 + f] * sNorm[s + 1];
    uint32_t pk = (uint32_t)f2b(v0) | ((uint32_t)f2b(v1) << 16);
    *(uint32_t*)(sXt + (f * 128 + (s ^ ((f & 7) << 3)))) = pk;
  }
  __syncthreads();

  // ---- phase 2: counts -> regs -> swizzled bf16 S'; stage W2t ----
  u16 creg[32];
#pragma unroll
  for (int j = 0; j < 32; ++j) {
    int i = j * 512 + t;
    creg[j] = sScnt[(i >> 7) * 132 + (i & 127)];
  }
  __syncthreads();
#pragma unroll
  for (int j = 0; j < 32; ++j) {
    int i = j * 512 + t;
    int r = i >> 7, s = i & 127;
    float val = ((float)creg[j] + (r == s ? 1.f : 0.f)) * sNorm[r] * sNorm[s];
    sS[r * 128 + (s ^ ((r & 7) << 3))] = f2b(val);
  }
  for (int g = t; g < 2048; g += 512) {
    int n = g >> 4, blk = g & 15;
    *(uint4*)(sW2t + n * 128 + ((blk ^ (n & 7)) << 3)) = ((const uint4*)w2t)[g];
  }
  __syncthreads();

  int mrow = w * 16 + (l & 15);
  int kblk = (l >> 4) * 8;
  int rbase = w * 16 + (l >> 4) * 4;

  // ---- phase 3: agg1 = S' @ X -> sAgg1 ----
  for (int nt = 0; nt < 4; ++nt) {
    f32x4 acc = {0.f, 0.f, 0.f, 0.f};
    int cg = nt * 16 + (l & 15);
#pragma unroll
    for (int ks = 0; ks < 4; ++ks) {
      int kc = ks * 32 + kblk;
      s8v a = *(const s8v*)(sS + swz128(mrow, kc));
      s8v bf = *(const s8v*)(sXt + swz128(cg, kc));
      acc = __builtin_amdgcn_mfma_f32_16x16x32_bf16(a, bf, acc, 0, 0, 0);
    }
#pragma unroll
    for (int rg = 0; rg < 4; ++rg) sAgg1[swz64(rbase + rg, cg)] = f2b(acc[rg]);
  }
  __syncthreads();

  // ---- phase 4: h1 = relu(agg1 @ W1 + b1) -> h1^T into sB2 ----
  for (int nt = 0; nt < 8; ++nt) {
    int cg = nt * 16 + (l & 15);
    float bv = b1[cg];
    f32x4 acc = {bv, bv, bv, bv};
#pragma unroll
    for (int ks = 0; ks < 2; ++ks) {
      int kc = ks * 32 + kblk;
      s8v a = *(const s8v*)(sAgg1 + swz64(mrow, kc));
      s8v bf = *(const s8v*)(sW1t + swz64(cg, kc));
      acc = __builtin_amdgcn_mfma_f32_16x16x32_bf16(a, bf, acc, 0, 0, 0);
    }
    u16 h0 = f2b(fmaxf(acc[0], 0.f)), h1v = f2b(fmaxf(acc[1], 0.f));
    u16 h2 = f2b(fmaxf(acc[2], 0.f)), h3 = f2b(fmaxf(acc[3], 0.f));
    uint2 pk;
    pk.x = (uint32_t)h0 | ((uint32_t)h1v << 16);
    pk.y = (uint32_t)h2 | ((uint32_t)h3 << 16);
    *(uint2*)(sB2 + swz128(cg, rbase)) = pk;
  }
  __syncthreads();

  // ---- phase 5: agg2 = S' @ h1 -> sAgg2 ----
  for (int nt = 0; nt < 8; ++nt) {
    f32x4 acc = {0.f, 0.f, 0.f, 0.f};
    int cg = nt * 16 + (l & 15);
#pragma unroll
    for (int ks = 0; ks < 4; ++ks) {
      int kc = ks * 32 + kblk;
      s8v a = *(const s8v*)(sS + swz128(mrow, kc));
      s8v bf = *(const s8v*)(sB2 + swz128(cg, kc));
      acc = __builtin_amdgcn_mfma_f32_16x16x32_bf16(a, bf, acc, 0, 0, 0);
    }
#pragma unroll
    for (int rg = 0; rg < 4; ++rg) sAgg2[swz128(rbase + rg, cg)] = f2b(acc[rg]);
  }
  __syncthreads();

  // ---- phase 6: poi = agg2 @ W2 + b2 -> sP (rows) AND sPt (cols) ----
  for (int nt = 0; nt < 8; ++nt) {
    int cg = nt * 16 + (l & 15);
    float bv = b2[cg];
    f32x4 acc = {bv, bv, bv, bv};
#pragma unroll
    for (int ks = 0; ks < 4; ++ks) {
      int kc = ks * 32 + kblk;
      s8v a = *(const s8v*)(sAgg2 + swz128(mrow, kc));
      s8v bf = *(const s8v*)(sW2t + swz128(cg, kc));
      acc = __builtin_amdgcn_mfma_f32_16x16x32_bf16(a, bf, acc, 0, 0, 0);
    }
    u16 p0 = f2b(acc[0]), p1 = f2b(acc[1]), p2 = f2b(acc[2]), p3 = f2b(acc[3]);
#pragma unroll
    for (int rg = 0; rg < 4; ++rg)
      sP[swz128(rbase + rg, cg)] = (rg == 0) ? p0 : (rg == 1) ? p1 : (rg == 2) ? p2 : p3;
    uint2 pk;
    pk.x = (uint32_t)p0 | ((uint32_t)p1 << 16);
    pk.y = (uint32_t)p2 | ((uint32_t)p3 << 16);
    *(uint2*)(sPt + swz128(cg, rbase)) = pk;
  }
  __syncthreads();

  // ---- tail: pool from Pt rows (contiguous, swizzled) ----
  if (t < 128) {
    int c = t;
    float s = 0.f;
    const u16* rowp = sPt + c * 128;
    int sw = (c & 7) << 3;
#pragma unroll
    for (int k8 = 0; k8 < 16; ++k8) {
      s8v v = *(const s8v*)(rowp + ((k8 * 8) ^ sw));
#pragma unroll
      for (int j = 0; j < 8; ++j) s += b2f((u16)v[j]);
    }
    sPool[c] = s;
    poi_pool[b * 128 + c] = s * (1.0f / 128.0f);
  }
  // ---- el from P rows ----
  if (t < 384) {
    int r = t & 127, h = t >> 7;
    int sw = (r & 7) << 3;
    const u16* rowp = sP + r * 128;
    const float* qh = &sQ[h * 128];
    float d = 0.f;
#pragma unroll
    for (int k8 = 0; k8 < 16; ++k8) {
      int c8 = (k8 * 8) ^ sw;
      s8v v = *(const s8v*)(rowp + c8);
#pragma unroll
      for (int j = 0; j < 8; ++j) d += b2f((u16)v[j]) * qh[c8 + j];
    }
    float e = d + sCh[h] + sEr[h];
    sAl[h * 128 + r] = (e > 0.f) ? e : 0.2f * e;
  }
  __syncthreads();

  if (t < 192) {
    int h = t >> 6, ll = t & 63;
    float v0 = sAl[h * 128 + ll], v1 = sAl[h * 128 + 64 + ll];
    float m = fmaxf(v0, v1);
    for (int off = 32; off > 0; off >>= 1) m = fmaxf(m, __shfl_xor(m, off));
    float x0 = __expf(v0 - m), x1 = __expf(v1 - m);
    float s = x0 + x1;
    for (int off = 32; off > 0; off >>= 1) s += __shfl_xor(s, off);
    float inv = 1.0f / s;
    sAl[h * 128 + ll] = x0 * inv;
    sAl[h * 128 + 64 + ll] = x1 * inv;
  }
  __syncthreads();

  // ---- pooled from Pt rows ----
  if (t < 384) {
    int hh = t >> 7, c = t & 127;
    int sw = (c & 7) << 3;
    const u16* rowp = sPt + c * 128;
    const float* al = &sAl[hh * 128];
    float s = 0.f;
#pragma unroll
    for (int k8 = 0; k8 < 16; ++k8) {
      int r8 = (k8 * 8) ^ sw;
      s8v v = *(const s8v*)(rowp + r8);
#pragma unroll
      for (int j = 0; j < 8; ++j) s += b2f((u16)v[j]) * al[r8 + j];
    }
    pooled[((size_t)b * 3 + hh) * 128 + c] = s;
  }
  __syncthreads();

  // ---- fused mfn ----
  float hv = 0.f, pv = 0.f;
  if (t < 128) {
    hv = hrs[base + t];
    pv = sPool[t] * (1.0f / 128.0f);
    sQ[t] = hv * hv + pv * pv;
  }
  __syncthreads();
  if (t < 64) {
    float v = sQ[t] + sQ[t + 64];
    for (int off = 32; off > 0; off >>= 1) v += __shfl_xor(v, off);
    if (t == 0) sQ[0] = rsqrtf(v);
  }
  __syncthreads();
  if (t < 128) {
    float rn = sQ[0];
    mfn[b * 256 + t] = hv * rn;
    mfn[b * 256 + 128 + t] = pv * rn;
  }
}

// ===================== med =====================
__global__ void k_med(const float* __restrict__ mfn, float* __restrict__ med) {
  __shared__ float sI[32 * 64];
  __shared__ float sJ[32 * 64];
  int bi = blockIdx.x >> 4, bj = blockIdx.x & 15;
  int t = threadIdx.x;
  int ti = t >> 4, tj = t & 15;
  float acc[2][2] = {};
  for (int k0 = 0; k0 < 256; k0 += 64) {
    __syncthreads();
    for (int i = t; i < 2048; i += 256) {
      int r = i >> 6, k = i & 63;
      int idx = (r << 6) | (k ^ (r & 31));
      sI[idx] = mfn[(bi * 32 + r) * 256 + k0 + k];
      sJ[idx] = mfn[(bj * 32 + r) * 256 + k0 + k];
    }
    __syncthreads();
    for (int k = 0; k < 64; ++k) {
      float a[2], c2[2];
#pragma unroll
      for (int ii = 0; ii < 2; ++ii) a[ii] = sI[((ti * 2 + ii) << 6) | (k ^ ((ti * 2 + ii) & 31))];
#pragma unroll
      for (int jj = 0; jj < 2; ++jj) c2[jj] = sJ[((tj * 2 + jj) << 6) | (k ^ ((tj * 2 + jj) & 31))];
#pragma unroll
      for (int ii = 0; ii < 2; ++ii)
#pragma unroll
        for (int jj = 0; jj < 2; ++jj) acc[ii][jj] += a[ii] * c2[jj];
    }
  }
#pragma unroll
  for (int ii = 0; ii < 2; ++ii)
#pragma unroll
    for (int jj = 0; jj < 2; ++jj)
      med[(size_t)(bi * 32 + ti * 2 + ii) * 512 + bj * 32 + tj * 2 + jj] =
          (acc[ii][jj] + 1.0f) * 0.5f;
}

__global__ void k_rowsum(const float* __restrict__ med, const float* __restrict__ T0p,
                         float* __restrict__ dinv) {
  int r = blockIdx.x, l = threadIdx.x;
  float T0 = *T0p;
  float cnt = 0.f;
  for (int j = l; j < 512; j += 64) cnt += ((med[(size_t)r * 512 + j] >= T0) || (j == r)) ? 1.0f : 0.0f;
  for (int off = 32; off > 0; off >>= 1) cnt += __shfl_xor(cnt, off);
  if (l == 0) dinv[r] = rsqrtf(cnt);
}

// ===================== epilogue: Aagg + all small mat-vecs + final (one block/parcel) =======
__global__ void __launch_bounds__(256) k_epilogue(
    const float* __restrict__ med, const float* __restrict__ T0p,
    const float* __restrict__ dinv, const float* __restrict__ hrs,
    const float* __restrict__ pool, const float* __restrict__ pooled,
    const float* __restrict__ ph, const float* __restrict__ Wh1, const float* __restrict__ bh1,
    const float* __restrict__ Wp1, const float* __restrict__ bp1,
    const float* __restrict__ Wpp, const float* __restrict__ bpp,
    const float* __restrict__ Wg_in, const float* __restrict__ g0in,
    const float* __restrict__ G, const float* __restrict__ g0w,
    const float* __restrict__ Wfc, const float* __restrict__ bfc, float* __restrict__ out) {
  __shared__ float sT[2][128];     // t1 (hrs-side), t2 (pool-side)
  __shared__ float sPld[3][128];   // pooled rows
  __shared__ float sPh[128];       // ph row
  __shared__ float sY[3][128];
  __shared__ float sC[4][128];     // concat: img2poi, poi_agg, poi2img, hrs_agg
  int i = blockIdx.x, t = threadIdx.x;
  int c = t & 127, half = t >> 7;

  // stage pooled + ph
  for (int k = t; k < 384; k += 256) sPld[k >> 7][k & 127] = pooled[(size_t)i * 384 + k];
  if (t < 128) sPh[t] = ph[i * 128 + t];

  // Aagg
  {
    float T0 = *T0p;
    const float* srcm = half ? pool : hrs;
    float acc = 0.f;
    for (int j = 0; j < 512; ++j) {
      float m = med[(size_t)i * 512 + j];
      if (m >= T0 || j == i) acc += dinv[j] * srcm[j * 128 + c];
    }
    sT[half][c] = acc * dinv[i];
  }
  __syncthreads();

  // hrs_agg / poi_agg
  {
    const float* Wm = half ? Wp1 : Wh1;
    const float* bm = half ? bp1 : bh1;
    const float* xr = sT[half];
    float acc = bm[c];
#pragma unroll 4
    for (int k = 0; k < 128; ++k) acc += xr[k] * Wm[k * 128 + c];
    sC[half ? 1 : 3][c] = acc;
  }
  // Y = pooled @ Wpp + bpp (3 rows)
  for (int task = t; task < 384; task += 256) {
    int h = task >> 7, cc = task & 127;
    float acc = bpp[cc];
#pragma unroll 4
    for (int k = 0; k < 128; ++k) acc += sPld[h][k] * Wpp[k * 128 + cc];
    sY[h][cc] = acc;
  }
  __syncthreads();

  if (half == 0) {
    // poi2img = mean_h Y[h] @ Wg_in_h + g0in
    float acc = 0.f;
    for (int h = 0; h < 3; ++h) {
      const float* y = sY[h];
      const float* Wc = Wg_in + h * 128 + c;
#pragma unroll 4
      for (int k = 0; k < 128; ++k) acc += y[k] * Wc[k * 384];
    }
    sC[2][c] = acc * (1.0f / 3.0f) + g0in[c];
  } else {
    // img2poi = ph @ G + g0w
    float acc = g0w[c];
#pragma unroll 4
    for (int k = 0; k < 128; ++k) acc += sPh[k] * G[k * 128 + c];
    sC[0][c] = acc;
  }
  __syncthreads();

  // final: out[i,o] = concat . Wfc[:,o] + bfc[o]  (128 threads: o = t>>3, chunk = t&7)
  __shared__ float sRed[16][8];
  if (t < 128) {
    int o = t >> 3, chunk = t & 7;
    float acc = 0.f;
    const float* cv = &sC[0][0] + chunk * 64;
    const float* Wv = Wfc + (size_t)(chunk * 64) * 16 + o;
#pragma unroll 4
    for (int k = 0; k < 64; ++k) acc += cv[k] * Wv[k * 16];
    sRed[o][chunk] = acc;
  }
  __syncthreads();
  if (t < 16) {
    float acc = bfc[t];
#pragma unroll
    for (int j = 0; j < 8; ++j) acc += sRed[t][j];
    out[i * 16 + t] = acc;
  }
}

// ===================== host =====================
extern "C" void kernel_launch(void* const* d_in, const int* in_sizes, int n_in,
                              void* d_out, int out_size, void* d_ws, size_t ws_size,
                              hipStream_t stream) {
  const float* poi_x = (const float*)d_in[0];
  const float* img = (const float*)d_in[1];
  const int* edges = (const int*)d_in[2];
  const float* T0p = (const float*)d_in[4];
  const float* W1 = (const float*)d_in[5];
  const float* b1 = (const float*)d_in[6];
  const float* W2 = (const float*)d_in[7];
  const float* b2 = (const float*)d_in[8];
  const float* Whrs = (const float*)d_in[9];
  const float* bhrs = (const float*)d_in[10];
  const float* Wph = (const float*)d_in[11];
  const float* bph = (const float*)d_in[12];
  const float* Wpp = (const float*)d_in[13];
  const float* bpp = (const float*)d_in[14];
  const float* Wg_in = (const float*)d_in[15];
  const float* al_in = (const float*)d_in[16];
  const float* ar_in = (const float*)d_in[17];
  const float* bg_in = (const float*)d_in[18];
  const float* Wg_w = (const float*)d_in[19];
  const float* bg_w = (const float*)d_in[22];
  const float* Wh1 = (const float*)d_in[23];
  const float* bh1 = (const float*)d_in[24];
  const float* Wp1 = (const float*)d_in[25];
  const float* bp1 = (const float*)d_in[26];
  const float* Wfc = (const float*)d_in[27];
  const float* bfc = (const float*)d_in[28];

  const int* esrc = edges;
  const int* edst = edges + EE;

  char* ws = (char*)d_ws;
  size_t off = 0;
  auto alloc = [&](size_t nbytes) -> char* {
    char* p = ws + off;
    off += (nbytes + 255) & ~(size_t)255;
    return p;
  };
  int* deg = (int*)alloc((size_t)NN * 4);
  int* counts = (int*)alloc(512 * 4);
  int* offs = (int*)alloc(513 * 4);
  int* nodeoff = (int*)alloc((size_t)NN * 4);
  int* cursor = (int*)alloc((size_t)NN * 4);
  uint8_t* list8 = (uint8_t*)alloc((size_t)EE);
  u16* w1t = (u16*)alloc(8192 * 2);
  u16* w2t = (u16*)alloc(16384 * 2);
  float* hrs = (float*)alloc(512 * 128 * 4);
  float* phb = (float*)alloc(512 * 128 * 4);
  float* er = (float*)alloc(512 * 3 * 4);
  float* u = (float*)alloc(384 * 4);
  float* wv = (float*)alloc(384 * 4);
  float* q = (float*)alloc(384 * 4);
  float* chv = (float*)alloc(16);
  float* G = (float*)alloc(16384 * 4);
  float* g0w = (float*)alloc(128 * 4);
  float* g0in = (float*)alloc(128 * 4);
  float* pool = (float*)alloc(512 * 128 * 4);
  float* pooled = (float*)alloc((size_t)1536 * 128 * 4);
  float* mfn = (float*)alloc(512 * 256 * 4);
  float* dinv = (float*)alloc(512 * 4);

  float* out = (float*)d_out;
  float* med = out + 512 * 16;

  hipMemsetAsync(deg, 0, (size_t)NN * 4, stream);

  size_t dynf = 152096;
  hipFuncSetAttribute((const void*)k_gcn_fused, hipFuncAttributeMaxDynamicSharedMemorySize,
                      (int)dynf);

  k_prepAll<<<161, 256, 0, stream>>>(Wg_w, bg_w, bg_in, W1, W2, Wg_in, al_in, ar_in, Wpp, bpp,
                                     G, g0w, g0in, w1t, w2t, u, wv, q, chv);
  k_hist<<<EE / 256, 256, 0, stream>>>(edst, deg);
  k_parcsum<<<512, 128, 0, stream>>>(deg, counts);
  k_scan<<<1, 512, 0, stream>>>(counts, offs);
  k_nodeoff<<<512, 128, 0, stream>>>(deg, offs, nodeoff, cursor);
  k_scatter<<<EE / 256, 256, 0, stream>>>(esrc, edst, cursor, list8);
  k_hrs<<<256, 512, 0, stream>>>(img, Whrs, bhrs, Wph, bph, wv, hrs, phb, er);
  k_gcn_fused<<<512, 512, dynf, stream>>>(poi_x, b1, b2, deg, list8, nodeoff, q, chv, er, hrs,
                                          w1t, w2t, pool, pooled, mfn);
  k_med<<<256, 256, 0, stream>>>(mfn, med);
  k_rowsum<<<512, 64, 0, stream>>>(med, T0p, dinv);
  k_epilogue<<<512, 256, 0, stream>>>(med, T0p, dinv, hrs, pool, pooled, phb, Wh1, bh1, Wp1,
                                      bp1, Wpp, bpp, Wg_in, g0in, G, g0w, Wfc, bfc, out);

  (void)in_sizes; (void)n_in; (void)out_size; (void)ws_size;
}

// Round 8
// 245.092 us; speedup vs baseline: 4.8892x; 1.0957x over previous
//
#include <hip/hip_runtime.h>
#include <stdint.h>

#define NN 65536
#define EE 524288
#define BB 512

typedef unsigned short u16;
typedef __attribute__((ext_vector_type(8))) short s8v;    // 8 bf16 (4 VGPRs)
typedef __attribute__((ext_vector_type(4))) float f32x4;  // MFMA acc

__device__ __forceinline__ u16 f2b(float f) {
  union { float f; uint32_t u; } a{f};
  uint32_t r = a.u + 0x7fff + ((a.u >> 16) & 1);
  return (u16)(r >> 16);
}
__device__ __forceinline__ float b2f(u16 v) {
  union { uint32_t u; float f; } a{(uint32_t)v << 16};
  return a.f;
}
__device__ __forceinline__ int swz128(int r, int c) { return r * 128 + (c ^ ((r & 7) << 3)); }
__device__ __forceinline__ int swz64(int r, int c) { return r * 64 + (c ^ ((r & 7) << 3)); }

// ===================== graph prep =====================
__global__ void k_hist(const int* __restrict__ dst, int* __restrict__ deg) {
  int e = blockIdx.x * 256 + threadIdx.x;
  if (e >= EE) return;
  atomicAdd(&deg[dst[e]], 1);
}

__global__ void k_parcsum(const int* __restrict__ deg, int* __restrict__ counts) {
  __shared__ int s[128];
  int b = blockIdx.x, t = threadIdx.x;
  s[t] = deg[(b << 7) + t];
  __syncthreads();
  for (int d = 64; d > 0; d >>= 1) {
    if (t < d) s[t] += s[t + d];
    __syncthreads();
  }
  if (t == 0) counts[b] = s[0];
}

__global__ void k_scan(const int* __restrict__ counts, int* __restrict__ offs) {
  __shared__ int s[512];
  int t = threadIdx.x;
  s[t] = counts[t];
  __syncthreads();
  for (int d = 1; d < 512; d <<= 1) {
    int v = (t >= d) ? s[t - d] : 0;
    __syncthreads();
    s[t] += v;
    __syncthreads();
  }
  offs[t] = (t == 0) ? 0 : s[t - 1];
  if (t == 511) offs[512] = s[511];
}

__global__ void k_nodeoff(const int* __restrict__ deg, const int* __restrict__ offs,
                          int* __restrict__ nodeoff, int* __restrict__ cursor) {
  __shared__ int s[128];
  int b = blockIdx.x, t = threadIdx.x;
  int base = b << 7;
  int d = deg[base + t];
  s[t] = d;
  __syncthreads();
  for (int dd = 1; dd < 128; dd <<= 1) {
    int v = (t >= dd) ? s[t - dd] : 0;
    __syncthreads();
    s[t] += v;
    __syncthreads();
  }
  int excl = s[t] - d + offs[b];
  nodeoff[base + t] = excl;
  cursor[base + t] = excl;
}

__global__ void k_scatter(const int* __restrict__ src, const int* __restrict__ dst,
                          int* __restrict__ cursor, uint8_t* __restrict__ list8) {
  int e = blockIdx.x * 256 + threadIdx.x;
  if (e >= EE) return;
  int s = src[e], d = dst[e];
  int slot = atomicAdd(&cursor[d], 1);
  list8[slot] = (uint8_t)(s & 127);
}

// ===================== merged weight prep =====================
__global__ void k_prepAll(const float* __restrict__ Wg_w, const float* __restrict__ bg_w,
                          const float* __restrict__ bg_in, const float* __restrict__ W1,
                          const float* __restrict__ W2, const float* __restrict__ Wg_in,
                          const float* __restrict__ al_in, const float* __restrict__ ar_in,
                          const float* __restrict__ Wpp, const float* __restrict__ bpp,
                          float* __restrict__ G, float* __restrict__ g0w,
                          float* __restrict__ g0in, u16* __restrict__ w1t,
                          u16* __restrict__ w2t, float* __restrict__ u, float* __restrict__ wv,
                          float* __restrict__ q, float* __restrict__ ch) {
  int blk = blockIdx.x, t = threadIdx.x;
  if (blk < 64) {
    int i = blk * 256 + t;  // 16384
    int k = i >> 7, c = i & 127;
    G[i] = (Wg_w[k * 384 + c] + Wg_w[k * 384 + 128 + c] + Wg_w[k * 384 + 256 + c]) *
           (1.0f / 3.0f);
    if (i < 128) {
      g0w[i] = (bg_w[i] + bg_w[128 + i] + bg_w[256 + i]) * (1.0f / 3.0f);
      g0in[i] = (bg_in[i] + bg_in[128 + i] + bg_in[256 + i]) * (1.0f / 3.0f);
    }
  } else if (blk < 160) {
    int i = (blk - 64) * 256 + t;  // 24576
    if (i < 8192) {
      int n = i >> 6, k = i & 63;
      w1t[i] = f2b(W1[k * 128 + n]);
    } else {
      int j = i - 8192;
      int n = j >> 7, k = j & 127;
      w2t[j] = f2b(W2[k * 128 + n]);
    }
  } else {
    __shared__ float su[384];
    for (int i = t; i < 384; i += 256) {
      int h = i >> 7, k = i & 127;
      float s = 0.f, sw = 0.f;
#pragma unroll 4
      for (int c = 0; c < 128; ++c) {
        float g = Wg_in[k * 384 + h * 128 + c];
        s += g * al_in[h * 128 + c];
        sw += g * ar_in[h * 128 + c];
      }
      su[i] = s;
      u[i] = s;
      wv[i] = sw;
    }
    __syncthreads();
    for (int i = t; i < 384; i += 256) {
      int h = i >> 7, j = i & 127;
      float s = 0.f;
#pragma unroll 4
      for (int k = 0; k < 128; ++k) s += Wpp[j * 128 + k] * su[h * 128 + k];
      q[i] = s;
    }
    if (t < 3) {
      float s = 0.f;
#pragma unroll 4
      for (int k = 0; k < 128; ++k) s += bpp[k] * su[t * 128 + k];
      ch[t] = s;
    }
  }
}

// ===================== hrs encoder + ph + er (fused) =====================
__global__ void __launch_bounds__(512) k_hrs(const float* __restrict__ img,
                                             const float* __restrict__ Whrs,
                                             const float* __restrict__ bhrs,
                                             const float* __restrict__ Wph,
                                             const float* __restrict__ bph,
                                             const float* __restrict__ wv,
                                             float* __restrict__ hrs, float* __restrict__ ph,
                                             float* __restrict__ er) {
  __shared__ float sI[4096];
  __shared__ float sRed[4][128];
  __shared__ float sHrs[2][128];
  __shared__ float sPh[2][128];
  int r0 = blockIdx.x * 2;
  int t = threadIdx.x;
  const float4* gsrc = (const float4*)(img + (size_t)r0 * 2048);
  float4* ldst = (float4*)sI;
  for (int i = t; i < 1024; i += 512) ldst[i] = gsrc[i];
  __syncthreads();
  int c = t & 127, g = t >> 7;
  int row = g & 1, ks = g >> 1;
  const float* s = sI + row * 2048 + ks * 1024;
  const float* W = Whrs + (size_t)(ks * 1024) * 128 + c;
  float a0 = 0.f, a1 = 0.f, a2 = 0.f, a3 = 0.f;
  for (int k = 0; k < 1024; k += 4) {
    a0 += s[k] * W[(size_t)k * 128];
    a1 += s[k + 1] * W[(size_t)(k + 1) * 128];
    a2 += s[k + 2] * W[(size_t)(k + 2) * 128];
    a3 += s[k + 3] * W[(size_t)(k + 3) * 128];
  }
  sRed[g][c] = (a0 + a1) + (a2 + a3);
  __syncthreads();
  if (t < 256) {
    int rr = t >> 7, cc = t & 127;
    float v = sRed[rr][cc] + sRed[rr + 2][cc] + bhrs[cc];
    hrs[(r0 + rr) * 128 + cc] = v;
    sHrs[rr][cc] = v;
  }
  __syncthreads();
  if (t < 256) {
    int rr = t >> 7, cc = t & 127;
    float acc = bph[cc];
#pragma unroll 4
    for (int k = 0; k < 128; ++k) acc += sHrs[rr][k] * Wph[k * 128 + cc];
    sPh[rr][cc] = acc;
    ph[(r0 + rr) * 128 + cc] = acc;
  }
  __syncthreads();
  if (t < 6) {
    int rr = t / 3, h = t % 3;
    float s2 = 0.f;
#pragma unroll 4
    for (int k = 0; k < 128; ++k) s2 += sPh[rr][k] * wv[h * 128 + k];
    er[(r0 + rr) * 3 + h] = s2;
  }
}

// ===================== FUSED GCN via dense S' + MFMA =====================
__global__ void __launch_bounds__(512) k_gcn_fused(
    const float* __restrict__ x, const float* __restrict__ b1, const float* __restrict__ b2,
    const int* __restrict__ deg, const uint8_t* __restrict__ g_list,
    const int* __restrict__ nodeoff, const float* __restrict__ q, const float* __restrict__ ch,
    const float* __restrict__ er, const float* __restrict__ hrs,
    const u16* __restrict__ w1t, const u16* __restrict__ w2t, float* __restrict__ poi_pool,
    float* __restrict__ pooled, float* __restrict__ mfn) {
  extern __shared__ char sm[];
  u16* sS = (u16*)sm;
  u16* sScnt = (u16*)sm;  // pad-132 layout during counting
  u16* sB2 = (u16*)(sm + 32768);
  u16* sPt = (u16*)(sm + 32768);
  u16* sXt = (u16*)(sm + 65536);
  u16* sAgg1 = (u16*)(sm + 81920);
  u16* sW1t = (u16*)(sm + 98304);
  float* sXrm = (float*)(sm + 114688);
  u16* sW2t = (u16*)(sm + 114688);
  u16* sAgg2 = (u16*)(sm + 65536);
  u16* sP = (u16*)sm;
  float* sNorm = (float*)(sm + 147968);
  float* sQ = (float*)(sm + 148480);
  float* sAl = (float*)(sm + 150016);
  float* sPool = (float*)(sm + 151552);
  float* sEr = (float*)(sm + 152064);
  float* sCh = (float*)(sm + 152080);

  int b = blockIdx.x, t = threadIdx.x;
  int base = b << 7;
  int l = t & 63, w = t >> 6;

  // ---- phase 0 ----
  if (t < 128) sNorm[t] = rsqrtf((float)deg[base + t] + 1.0f);
  for (int i = t; i < 8448; i += 512) ((uint32_t*)sScnt)[i] = 0;
  for (int i = t; i < 8192; i += 512) {
    int s = i >> 6, f = i & 63;
    sXrm[s * 65 + f] = x[(size_t)(base + s) * 64 + f];
  }
  for (int g = t; g < 1024; g += 512) {
    int n = g >> 3, blk = g & 7;
    *(uint4*)(sW1t + n * 64 + ((blk ^ (n & 7)) << 3)) = ((const uint4*)w1t)[g];
  }
  for (int i = t; i < 384; i += 512) sQ[i] = q[i];
  if (t < 3) {
    sEr[t] = er[b * 3 + t];
    sCh[t] = ch[t];
  }
  __syncthreads();

  // ---- phase 1: counts (pad-132) + X transpose->bf16 ----
  if (t < 128) {
    int r = t;
    int st = nodeoff[base + r];
    int dg = deg[base + r];
    u16* rowp = sScnt + r * 132;
    for (int e = st; e < st + dg; ++e) rowp[(int)g_list[e]] += 1;
  }
  for (int i = t; i < 4096; i += 512) {
    int f = i >> 6, s = (i & 63) * 2;
    float v0 = sXrm[s * 65 + f] * sNorm[s];
    float v1 = sXrm[(s + 1) * 65 + f] * sNorm[s + 1];
    uint32_t pk = (uint32_t)f2b(v0) | ((uint32_t)f2b(v1) << 16);
    *(uint32_t*)(sXt + (f * 128 + (s ^ ((f & 7) << 3)))) = pk;
  }
  __syncthreads();

  // ---- phase 2: counts -> regs -> swizzled bf16 S'; stage W2t ----
  u16 creg[32];
#pragma unroll
  for (int j = 0; j < 32; ++j) {
    int i = j * 512 + t;
    creg[j] = sScnt[(i >> 7) * 132 + (i & 127)];
  }
  __syncthreads();
#pragma unroll
  for (int j = 0; j < 32; ++j) {
    int i = j * 512 + t;
    int r = i >> 7, s = i & 127;
    float val = ((float)creg[j] + (r == s ? 1.f : 0.f)) * sNorm[r] * sNorm[s];
    sS[r * 128 + (s ^ ((r & 7) << 3))] = f2b(val);
  }
  for (int g = t; g < 2048; g += 512) {
    int n = g >> 4, blk = g & 15;
    *(uint4*)(sW2t + n * 128 + ((blk ^ (n & 7)) << 3)) = ((const uint4*)w2t)[g];
  }
  __syncthreads();

  int mrow = w * 16 + (l & 15);
  int kblk = (l >> 4) * 8;
  int rbase = w * 16 + (l >> 4) * 4;

  // ---- phase 3: agg1 = S' @ X ----
  for (int nt = 0; nt < 4; ++nt) {
    f32x4 acc = {0.f, 0.f, 0.f, 0.f};
    int cg = nt * 16 + (l & 15);
#pragma unroll
    for (int ks = 0; ks < 4; ++ks) {
      int kc = ks * 32 + kblk;
      s8v a = *(const s8v*)(sS + swz128(mrow, kc));
      s8v bf = *(const s8v*)(sXt + swz128(cg, kc));
      acc = __builtin_amdgcn_mfma_f32_16x16x32_bf16(a, bf, acc, 0, 0, 0);
    }
#pragma unroll
    for (int rg = 0; rg < 4; ++rg) sAgg1[swz64(rbase + rg, cg)] = f2b(acc[rg]);
  }
  __syncthreads();

  // ---- phase 4: h1 = relu(agg1 @ W1 + b1) -> h1^T ----
  for (int nt = 0; nt < 8; ++nt) {
    int cg = nt * 16 + (l & 15);
    float bv = b1[cg];
    f32x4 acc = {bv, bv, bv, bv};
#pragma unroll
    for (int ks = 0; ks < 2; ++ks) {
      int kc = ks * 32 + kblk;
      s8v a = *(const s8v*)(sAgg1 + swz64(mrow, kc));
      s8v bf = *(const s8v*)(sW1t + swz64(cg, kc));
      acc = __builtin_amdgcn_mfma_f32_16x16x32_bf16(a, bf, acc, 0, 0, 0);
    }
    u16 h0 = f2b(fmaxf(acc[0], 0.f)), h1v = f2b(fmaxf(acc[1], 0.f));
    u16 h2 = f2b(fmaxf(acc[2], 0.f)), h3 = f2b(fmaxf(acc[3], 0.f));
    uint2 pk;
    pk.x = (uint32_t)h0 | ((uint32_t)h1v << 16);
    pk.y = (uint32_t)h2 | ((uint32_t)h3 << 16);
    *(uint2*)(sB2 + swz128(cg, rbase)) = pk;
  }
  __syncthreads();

  // ---- phase 5: agg2 = S' @ h1 ----
  for (int nt = 0; nt < 8; ++nt) {
    f32x4 acc = {0.f, 0.f, 0.f, 0.f};
    int cg = nt * 16 + (l & 15);
#pragma unroll
    for (int ks = 0; ks < 4; ++ks) {
      int kc = ks * 32 + kblk;
      s8v a = *(const s8v*)(sS + swz128(mrow, kc));
      s8v bf = *(const s8v*)(sB2 + swz128(cg, kc));
      acc = __builtin_amdgcn_mfma_f32_16x16x32_bf16(a, bf, acc, 0, 0, 0);
    }
#pragma unroll
    for (int rg = 0; rg < 4; ++rg) sAgg2[swz128(rbase + rg, cg)] = f2b(acc[rg]);
  }
  __syncthreads();

  // ---- phase 6: poi = agg2 @ W2 + b2 -> sP + sPt ----
  for (int nt = 0; nt < 8; ++nt) {
    int cg = nt * 16 + (l & 15);
    float bv = b2[cg];
    f32x4 acc = {bv, bv, bv, bv};
#pragma unroll
    for (int ks = 0; ks < 4; ++ks) {
      int kc = ks * 32 + kblk;
      s8v a = *(const s8v*)(sAgg2 + swz128(mrow, kc));
      s8v bf = *(const s8v*)(sW2t + swz128(cg, kc));
      acc = __builtin_amdgcn_mfma_f32_16x16x32_bf16(a, bf, acc, 0, 0, 0);
    }
    u16 p0 = f2b(acc[0]), p1 = f2b(acc[1]), p2 = f2b(acc[2]), p3 = f2b(acc[3]);
#pragma unroll
    for (int rg = 0; rg < 4; ++rg)
      sP[swz128(rbase + rg, cg)] = (rg == 0) ? p0 : (rg == 1) ? p1 : (rg == 2) ? p2 : p3;
    uint2 pk;
    pk.x = (uint32_t)p0 | ((uint32_t)p1 << 16);
    pk.y = (uint32_t)p2 | ((uint32_t)p3 << 16);
    *(uint2*)(sPt + swz128(cg, rbase)) = pk;
  }
  __syncthreads();

  // ---- tail: pool from Pt rows ----
  if (t < 128) {
    int c = t;
    float s = 0.f;
    const u16* rowp = sPt + c * 128;
    int sw = (c & 7) << 3;
#pragma unroll
    for (int k8 = 0; k8 < 16; ++k8) {
      s8v v = *(const s8v*)(rowp + ((k8 * 8) ^ sw));
#pragma unroll
      for (int j = 0; j < 8; ++j) s += b2f((u16)v[j]);
    }
    sPool[c] = s;
    poi_pool[b * 128 + c] = s * (1.0f / 128.0f);
  }
  if (t < 384) {
    int r = t & 127, h = t >> 7;
    int sw = (r & 7) << 3;
    const u16* rowp = sP + r * 128;
    const float* qh = &sQ[h * 128];
    float d = 0.f;
#pragma unroll
    for (int k8 = 0; k8 < 16; ++k8) {
      int c8 = (k8 * 8) ^ sw;
      s8v v = *(const s8v*)(rowp + c8);
#pragma unroll
      for (int j = 0; j < 8; ++j) d += b2f((u16)v[j]) * qh[c8 + j];
    }
    float e = d + sCh[h] + sEr[h];
    sAl[h * 128 + r] = (e > 0.f) ? e : 0.2f * e;
  }
  __syncthreads();

  if (t < 192) {
    int h = t >> 6, ll = t & 63;
    float v0 = sAl[h * 128 + ll], v1 = sAl[h * 128 + 64 + ll];
    float m = fmaxf(v0, v1);
    for (int off = 32; off > 0; off >>= 1) m = fmaxf(m, __shfl_xor(m, off));
    float x0 = __expf(v0 - m), x1 = __expf(v1 - m);
    float s = x0 + x1;
    for (int off = 32; off > 0; off >>= 1) s += __shfl_xor(s, off);
    float inv = 1.0f / s;
    sAl[h * 128 + ll] = x0 * inv;
    sAl[h * 128 + 64 + ll] = x1 * inv;
  }
  __syncthreads();

  if (t < 384) {
    int hh = t >> 7, c = t & 127;
    int sw = (c & 7) << 3;
    const u16* rowp = sPt + c * 128;
    const float* al = &sAl[hh * 128];
    float s = 0.f;
#pragma unroll
    for (int k8 = 0; k8 < 16; ++k8) {
      int r8 = (k8 * 8) ^ sw;
      s8v v = *(const s8v*)(rowp + r8);
#pragma unroll
      for (int j = 0; j < 8; ++j) s += b2f((u16)v[j]) * al[r8 + j];
    }
    pooled[((size_t)b * 3 + hh) * 128 + c] = s;
  }
  __syncthreads();

  // ---- fused mfn ----
  float hv = 0.f, pv = 0.f;
  if (t < 128) {
    hv = hrs[base + t];
    pv = sPool[t] * (1.0f / 128.0f);
    sQ[t] = hv * hv + pv * pv;
  }
  __syncthreads();
  if (t < 64) {
    float v = sQ[t] + sQ[t + 64];
    for (int off = 32; off > 0; off >>= 1) v += __shfl_xor(v, off);
    if (t == 0) sQ[0] = rsqrtf(v);
  }
  __syncthreads();
  if (t < 128) {
    float rn = sQ[0];
    mfn[b * 256 + t] = hv * rn;
    mfn[b * 256 + 128 + t] = pv * rn;
  }
}

// ===================== med =====================
__global__ void k_med(const float* __restrict__ mfn, float* __restrict__ med) {
  __shared__ float sI[32 * 64];
  __shared__ float sJ[32 * 64];
  int bi = blockIdx.x >> 4, bj = blockIdx.x & 15;
  int t = threadIdx.x;
  int ti = t >> 4, tj = t & 15;
  float acc[2][2] = {};
  for (int k0 = 0; k0 < 256; k0 += 64) {
    __syncthreads();
    for (int i = t; i < 2048; i += 256) {
      int r = i >> 6, k = i & 63;
      int idx = (r << 6) | (k ^ (r & 31));
      sI[idx] = mfn[(bi * 32 + r) * 256 + k0 + k];
      sJ[idx] = mfn[(bj * 32 + r) * 256 + k0 + k];
    }
    __syncthreads();
    for (int k = 0; k < 64; ++k) {
      float a[2], c2[2];
#pragma unroll
      for (int ii = 0; ii < 2; ++ii) a[ii] = sI[((ti * 2 + ii) << 6) | (k ^ ((ti * 2 + ii) & 31))];
#pragma unroll
      for (int jj = 0; jj < 2; ++jj) c2[jj] = sJ[((tj * 2 + jj) << 6) | (k ^ ((tj * 2 + jj) & 31))];
#pragma unroll
      for (int ii = 0; ii < 2; ++ii)
#pragma unroll
        for (int jj = 0; jj < 2; ++jj) acc[ii][jj] += a[ii] * c2[jj];
    }
  }
#pragma unroll
  for (int ii = 0; ii < 2; ++ii)
#pragma unroll
    for (int jj = 0; jj < 2; ++jj)
      med[(size_t)(bi * 32 + ti * 2 + ii) * 512 + bj * 32 + tj * 2 + jj] =
          (acc[ii][jj] + 1.0f) * 0.5f;
}

__global__ void k_rowsum(const float* __restrict__ med, const float* __restrict__ T0p,
                         float* __restrict__ dinv) {
  int r = blockIdx.x, l = threadIdx.x;
  float T0 = *T0p;
  float cnt = 0.f;
  for (int j = l; j < 512; j += 64) cnt += ((med[(size_t)r * 512 + j] >= T0) || (j == r)) ? 1.0f : 0.0f;
  for (int off = 32; off > 0; off >>= 1) cnt += __shfl_xor(cnt, off);
  if (l == 0) dinv[r] = rsqrtf(cnt);
}

// ===================== epilogue: sparse-neighbor Aagg + mat-vecs + final =====================
__global__ void __launch_bounds__(256) k_epilogue(
    const float* __restrict__ med, const float* __restrict__ T0p,
    const float* __restrict__ dinv, const float* __restrict__ hrs,
    const float* __restrict__ pool, const float* __restrict__ pooled,
    const float* __restrict__ ph, const float* __restrict__ Wh1, const float* __restrict__ bh1,
    const float* __restrict__ Wp1, const float* __restrict__ bp1,
    const float* __restrict__ Wpp, const float* __restrict__ bpp,
    const float* __restrict__ Wg_in, const float* __restrict__ g0in,
    const float* __restrict__ G, const float* __restrict__ g0w,
    const float* __restrict__ Wfc, const float* __restrict__ bfc, float* __restrict__ out) {
  __shared__ float sMedRow[512];
  __shared__ float sT[2][128];
  __shared__ float sPld[3][128];
  __shared__ float sPh[128];
  __shared__ float sY[3][128];
  __shared__ float sC[4][128];
  __shared__ int sNbr[64];
  __shared__ float sDw[64];
  __shared__ int sNnz;
  int i = blockIdx.x, t = threadIdx.x;
  int c = t & 127, half = t >> 7;
  float T0 = *T0p;

  // stage med row (coalesced), pooled, ph
  for (int j = t; j < 512; j += 256) sMedRow[j] = med[(size_t)i * 512 + j];
  for (int k = t; k < 384; k += 256) sPld[k >> 7][k & 127] = pooled[(size_t)i * 384 + k];
  if (t < 128) sPh[t] = ph[i * 128 + t];
  __syncthreads();

  // deterministic neighbor-list build: wave 0, lane j handles js [8j, 8j+8)
  if (t < 64) {
    int cnt = 0, flags = 0;
#pragma unroll
    for (int k = 0; k < 8; ++k) {
      int j = t * 8 + k;
      if (sMedRow[j] >= T0 || j == i) {
        flags |= 1 << k;
        ++cnt;
      }
    }
    int off = cnt;
    for (int d = 1; d < 64; d <<= 1) {
      int v = __shfl_up(off, d);
      if (t >= d) off += v;
    }
    off -= cnt;  // exclusive
    int pos = off;
#pragma unroll
    for (int k = 0; k < 8; ++k)
      if (flags & (1 << k)) {
        int j = t * 8 + k;
        if (pos < 64) {
          sNbr[pos] = j;
          sDw[pos] = dinv[j];
        }
        ++pos;
      }
    if (t == 63) sNnz = off + cnt;
  }
  __syncthreads();

  // Aagg: sparse path (ascending-j order, deterministic); dense fallback if overflow
  {
    float di = dinv[i];
    const float* srcm = half ? pool : hrs;
    float acc = 0.f;
    int nnz = sNnz;
    if (nnz <= 64) {
      for (int n = 0; n < nnz; ++n) acc += sDw[n] * srcm[sNbr[n] * 128 + c];
    } else {
      for (int j = 0; j < 512; ++j)
        if (sMedRow[j] >= T0 || j == i) acc += dinv[j] * srcm[j * 128 + c];
    }
    sT[half][c] = acc * di;
  }
  __syncthreads();

  // hrs_agg / poi_agg
  {
    const float* Wm = half ? Wp1 : Wh1;
    const float* bm = half ? bp1 : bh1;
    const float* xr = sT[half];
    float acc = bm[c];
#pragma unroll 4
    for (int k = 0; k < 128; ++k) acc += xr[k] * Wm[k * 128 + c];
    sC[half ? 1 : 3][c] = acc;
  }
  // Y = pooled @ Wpp + bpp
  for (int task = t; task < 384; task += 256) {
    int h = task >> 7, cc = task & 127;
    float acc = bpp[cc];
#pragma unroll 4
    for (int k = 0; k < 128; ++k) acc += sPld[h][k] * Wpp[k * 128 + cc];
    sY[h][cc] = acc;
  }
  __syncthreads();

  if (half == 0) {
    float acc = 0.f;
    for (int h = 0; h < 3; ++h) {
      const float* y = sY[h];
      const float* Wc = Wg_in + h * 128 + c;
#pragma unroll 4
      for (int k = 0; k < 128; ++k) acc += y[k] * Wc[k * 384];
    }
    sC[2][c] = acc * (1.0f / 3.0f) + g0in[c];
  } else {
    float acc = g0w[c];
#pragma unroll 4
    for (int k = 0; k < 128; ++k) acc += sPh[k] * G[k * 128 + c];
    sC[0][c] = acc;
  }
  __syncthreads();

  __shared__ float sRed[16][8];
  if (t < 128) {
    int o = t >> 3, chunk = t & 7;
    float acc = 0.f;
    const float* cv = &sC[0][0] + chunk * 64;
    const float* Wv = Wfc + (size_t)(chunk * 64) * 16 + o;
#pragma unroll 4
    for (int k = 0; k < 64; ++k) acc += cv[k] * Wv[k * 16];
    sRed[o][chunk] = acc;
  }
  __syncthreads();
  if (t < 16) {
    float acc = bfc[t];
#pragma unroll
    for (int j = 0; j < 8; ++j) acc += sRed[t][j];
    out[i * 16 + t] = acc;
  }
}

// ===================== host =====================
extern "C" void kernel_launch(void* const* d_in, const int* in_sizes, int n_in,
                              void* d_out, int out_size, void* d_ws, size_t ws_size,
                              hipStream_t stream) {
  const float* poi_x = (const float*)d_in[0];
  const float* img = (const float*)d_in[1];
  const int* edges = (const int*)d_in[2];
  const float* T0p = (const float*)d_in[4];
  const float* W1 = (const float*)d_in[5];
  const float* b1 = (const float*)d_in[6];
  const float* W2 = (const float*)d_in[7];
  const float* b2 = (const float*)d_in[8];
  const float* Whrs = (const float*)d_in[9];
  const float* bhrs = (const float*)d_in[10];
  const float* Wph = (const float*)d_in[11];
  const float* bph = (const float*)d_in[12];
  const float* Wpp = (const float*)d_in[13];
  const float* bpp = (const float*)d_in[14];
  const float* Wg_in = (const float*)d_in[15];
  const float* al_in = (const float*)d_in[16];
  const float* ar_in = (const float*)d_in[17];
  const float* bg_in = (const float*)d_in[18];
  const float* Wg_w = (const float*)d_in[19];
  const float* bg_w = (const float*)d_in[22];
  const float* Wh1 = (const float*)d_in[23];
  const float* bh1 = (const float*)d_in[24];
  const float* Wp1 = (const float*)d_in[25];
  const float* bp1 = (const float*)d_in[26];
  const float* Wfc = (const float*)d_in[27];
  const float* bfc = (const float*)d_in[28];

  const int* esrc = edges;
  const int* edst = edges + EE;

  char* ws = (char*)d_ws;
  size_t off = 0;
  auto alloc = [&](size_t nbytes) -> char* {
    char* p = ws + off;
    off += (nbytes + 255) & ~(size_t)255;
    return p;
  };
  int* deg = (int*)alloc((size_t)NN * 4);
  int* counts = (int*)alloc(512 * 4);
  int* offs = (int*)alloc(513 * 4);
  int* nodeoff = (int*)alloc((size_t)NN * 4);
  int* cursor = (int*)alloc((size_t)NN * 4);
  uint8_t* list8 = (uint8_t*)alloc((size_t)EE);
  u16* w1t = (u16*)alloc(8192 * 2);
  u16* w2t = (u16*)alloc(16384 * 2);
  float* hrs = (float*)alloc(512 * 128 * 4);
  float* phb = (float*)alloc(512 * 128 * 4);
  float* er = (float*)alloc(512 * 3 * 4);
  float* u = (float*)alloc(384 * 4);
  float* wv = (float*)alloc(384 * 4);
  float* q = (float*)alloc(384 * 4);
  float* chv = (float*)alloc(16);
  float* G = (float*)alloc(16384 * 4);
  float* g0w = (float*)alloc(128 * 4);
  float* g0in = (float*)alloc(128 * 4);
  float* pool = (float*)alloc(512 * 128 * 4);
  float* pooled = (float*)alloc((size_t)1536 * 128 * 4);
  float* mfn = (float*)alloc(512 * 256 * 4);
  float* dinv = (float*)alloc(512 * 4);

  float* out = (float*)d_out;
  float* med = out + 512 * 16;

  hipMemsetAsync(deg, 0, (size_t)NN * 4, stream);

  size_t dynf = 152096;
  hipFuncSetAttribute((const void*)k_gcn_fused, hipFuncAttributeMaxDynamicSharedMemorySize,
                      (int)dynf);

  k_prepAll<<<161, 256, 0, stream>>>(Wg_w, bg_w, bg_in, W1, W2, Wg_in, al_in, ar_in, Wpp, bpp,
                                     G, g0w, g0in, w1t, w2t, u, wv, q, chv);
  k_hist<<<EE / 256, 256, 0, stream>>>(edst, deg);
  k_parcsum<<<512, 128, 0, stream>>>(deg, counts);
  k_scan<<<1, 512, 0, stream>>>(counts, offs);
  k_nodeoff<<<512, 128, 0, stream>>>(deg, offs, nodeoff, cursor);
  k_scatter<<<EE / 256, 256, 0, stream>>>(esrc, edst, cursor, list8);
  k_hrs<<<256, 512, 0, stream>>>(img, Whrs, bhrs, Wph, bph, wv, hrs, phb, er);
  k_gcn_fused<<<512, 512, dynf, stream>>>(poi_x, b1, b2, deg, list8, nodeoff, q, chv, er, hrs,
                                          w1t, w2t, pool, pooled, mfn);
  k_med<<<256, 256, 0, stream>>>(mfn, med);
  k_rowsum<<<512, 64, 0, stream>>>(med, T0p, dinv);
  k_epilogue<<<512, 256, 0, stream>>>(med, T0p, dinv, hrs, pool, pooled, phb, Wh1, bh1, Wp1,
                                      bp1, Wpp, bpp, Wg_in, g0in, G, g0w, Wfc, bfc, out);

  (void)in_sizes; (void)n_in; (void)out_size; (void)ws_size;
}

// Round 9
// 209.108 us; speedup vs baseline: 5.7305x; 1.1721x over previous
//
#include <hip/hip_runtime.h>
#include <stdint.h>

#define NN 65536
#define EE 524288
#define BB 512

typedef unsigned short u16;
typedef __attribute__((ext_vector_type(8))) short s8v;    // 8 bf16 (4 VGPRs)
typedef __attribute__((ext_vector_type(4))) float f32x4;  // MFMA acc

__device__ __forceinline__ u16 f2b(float f) {
  union { float f; uint32_t u; } a{f};
  uint32_t r = a.u + 0x7fff + ((a.u >> 16) & 1);
  return (u16)(r >> 16);
}
__device__ __forceinline__ float b2f(u16 v) {
  union { uint32_t u; float f; } a{(uint32_t)v << 16};
  return a.f;
}
__device__ __forceinline__ int swz128(int r, int c) { return r * 128 + (c ^ ((r & 7) << 3)); }
__device__ __forceinline__ int swz64(int r, int c) { return r * 64 + (c ^ ((r & 7) << 3)); }

// ===================== graph prep: dense per-parcel count matrix =====================
__global__ void k_scatterS(const int* __restrict__ src, const int* __restrict__ dst,
                           uint32_t* __restrict__ Sg) {
  int e = blockIdx.x * 256 + threadIdx.x;
  if (e >= EE) return;
  int s = src[e], d = dst[e];
  atomicAdd(&Sg[(size_t)d * 128 + (s & 127)], 1u);
}

// ===================== merged weight prep =====================
__global__ void k_prepAll(const float* __restrict__ Wg_w, const float* __restrict__ bg_w,
                          const float* __restrict__ bg_in, const float* __restrict__ W1,
                          const float* __restrict__ W2, const float* __restrict__ Wg_in,
                          const float* __restrict__ al_in, const float* __restrict__ ar_in,
                          const float* __restrict__ Wpp, const float* __restrict__ bpp,
                          float* __restrict__ G, float* __restrict__ g0w,
                          float* __restrict__ g0in, u16* __restrict__ w1t,
                          u16* __restrict__ w2t, float* __restrict__ u, float* __restrict__ wv,
                          float* __restrict__ q, float* __restrict__ ch) {
  int blk = blockIdx.x, t = threadIdx.x;
  if (blk < 64) {
    int i = blk * 256 + t;  // 16384
    int k = i >> 7, c = i & 127;
    G[i] = (Wg_w[k * 384 + c] + Wg_w[k * 384 + 128 + c] + Wg_w[k * 384 + 256 + c]) *
           (1.0f / 3.0f);
    if (i < 128) {
      g0w[i] = (bg_w[i] + bg_w[128 + i] + bg_w[256 + i]) * (1.0f / 3.0f);
      g0in[i] = (bg_in[i] + bg_in[128 + i] + bg_in[256 + i]) * (1.0f / 3.0f);
    }
  } else if (blk < 160) {
    int i = (blk - 64) * 256 + t;  // 24576
    if (i < 8192) {
      int n = i >> 6, k = i & 63;
      w1t[i] = f2b(W1[k * 128 + n]);
    } else {
      int j = i - 8192;
      int n = j >> 7, k = j & 127;
      w2t[j] = f2b(W2[k * 128 + n]);
    }
  } else {
    __shared__ float su[384];
    for (int i = t; i < 384; i += 256) {
      int h = i >> 7, k = i & 127;
      float s = 0.f, sw = 0.f;
#pragma unroll 4
      for (int c = 0; c < 128; ++c) {
        float g = Wg_in[k * 384 + h * 128 + c];
        s += g * al_in[h * 128 + c];
        sw += g * ar_in[h * 128 + c];
      }
      su[i] = s;
      u[i] = s;
      wv[i] = sw;
    }
    __syncthreads();
    for (int i = t; i < 384; i += 256) {
      int h = i >> 7, j = i & 127;
      float s = 0.f;
#pragma unroll 4
      for (int k = 0; k < 128; ++k) s += Wpp[j * 128 + k] * su[h * 128 + k];
      q[i] = s;
    }
    if (t < 3) {
      float s = 0.f;
#pragma unroll 4
      for (int k = 0; k < 128; ++k) s += bpp[k] * su[t * 128 + k];
      ch[t] = s;
    }
  }
}

// ===================== hrs encoder + ph + er (fused) =====================
__global__ void __launch_bounds__(512) k_hrs(const float* __restrict__ img,
                                             const float* __restrict__ Whrs,
                                             const float* __restrict__ bhrs,
                                             const float* __restrict__ Wph,
                                             const float* __restrict__ bph,
                                             const float* __restrict__ wv,
                                             float* __restrict__ hrs, float* __restrict__ ph,
                                             float* __restrict__ er) {
  __shared__ float sI[4096];
  __shared__ float sRed[4][128];
  __shared__ float sHrs[2][128];
  __shared__ float sPh[2][128];
  int r0 = blockIdx.x * 2;
  int t = threadIdx.x;
  const float4* gsrc = (const float4*)(img + (size_t)r0 * 2048);
  float4* ldst = (float4*)sI;
  for (int i = t; i < 1024; i += 512) ldst[i] = gsrc[i];
  __syncthreads();
  int c = t & 127, g = t >> 7;
  int row = g & 1, ks = g >> 1;
  const float* s = sI + row * 2048 + ks * 1024;
  const float* W = Whrs + (size_t)(ks * 1024) * 128 + c;
  float a0 = 0.f, a1 = 0.f, a2 = 0.f, a3 = 0.f;
  for (int k = 0; k < 1024; k += 4) {
    a0 += s[k] * W[(size_t)k * 128];
    a1 += s[k + 1] * W[(size_t)(k + 1) * 128];
    a2 += s[k + 2] * W[(size_t)(k + 2) * 128];
    a3 += s[k + 3] * W[(size_t)(k + 3) * 128];
  }
  sRed[g][c] = (a0 + a1) + (a2 + a3);
  __syncthreads();
  if (t < 256) {
    int rr = t >> 7, cc = t & 127;
    float v = sRed[rr][cc] + sRed[rr + 2][cc] + bhrs[cc];
    hrs[(r0 + rr) * 128 + cc] = v;
    sHrs[rr][cc] = v;
  }
  __syncthreads();
  if (t < 256) {
    int rr = t >> 7, cc = t & 127;
    float acc = bph[cc];
#pragma unroll 4
    for (int k = 0; k < 128; ++k) acc += sHrs[rr][k] * Wph[k * 128 + cc];
    sPh[rr][cc] = acc;
    ph[(r0 + rr) * 128 + cc] = acc;
  }
  __syncthreads();
  if (t < 6) {
    int rr = t / 3, h = t % 3;
    float s2 = 0.f;
#pragma unroll 4
    for (int k = 0; k < 128; ++k) s2 += sPh[rr][k] * wv[h * 128 + k];
    er[(r0 + rr) * 3 + h] = s2;
  }
}

// ===================== FUSED GCN via dense S' + MFMA =====================
// LDS byte offsets:
//   0      sS    u16[16384] swizzled bf16 S' / later sP
//   32768  sB2   u16[16384] h1^T, later sPt (P^T)
//   65536  sXt   u16[8192]; 65536.. sAgg2 u16[16384]
//   81920  sAgg1 u16[8192]
//   98304  sW1t  u16[8192]
//   114688 sXrm  f32[8320] staging; later sW2t u16[16384]
//   147968 sNorm f32[128]; 148480 sQ f32[384]; 150016 sAl f32[384];
//   151552 sPool f32[128]; 152064 sEr f32[4]; 152080 sCh f32[4]
__global__ void __launch_bounds__(512) k_gcn_fused(
    const float* __restrict__ x, const float* __restrict__ b1, const float* __restrict__ b2,
    const uint32_t* __restrict__ Sg, const float* __restrict__ q, const float* __restrict__ ch,
    const float* __restrict__ er, const float* __restrict__ hrs,
    const u16* __restrict__ w1t, const u16* __restrict__ w2t, float* __restrict__ poi_pool,
    float* __restrict__ pooled, u16* __restrict__ mfnb) {
  extern __shared__ char sm[];
  u16* sS = (u16*)sm;
  u16* sB2 = (u16*)(sm + 32768);
  u16* sPt = (u16*)(sm + 32768);
  u16* sXt = (u16*)(sm + 65536);
  u16* sAgg1 = (u16*)(sm + 81920);
  u16* sW1t = (u16*)(sm + 98304);
  float* sXrm = (float*)(sm + 114688);
  u16* sW2t = (u16*)(sm + 114688);
  u16* sAgg2 = (u16*)(sm + 65536);
  u16* sP = (u16*)sm;
  float* sNorm = (float*)(sm + 147968);
  float* sQ = (float*)(sm + 148480);
  float* sAl = (float*)(sm + 150016);
  float* sPool = (float*)(sm + 151552);
  float* sEr = (float*)(sm + 152064);
  float* sCh = (float*)(sm + 152080);

  int b = blockIdx.x, t = threadIdx.x;
  int base = b << 7;
  int l = t & 63, w = t >> 6;
  const uint32_t* Sgb = Sg + (size_t)base * 128;

  // ---- phase 0: norms from Sg row-sums; stage Xrm, W1t, q/er/ch ----
  if (t < 128) {
    const uint4* rp = (const uint4*)(Sgb + (size_t)t * 128);
    uint32_t s = 0;
#pragma unroll
    for (int k = 0; k < 32; ++k) {
      uint4 v = rp[k];
      s += v.x + v.y + v.z + v.w;
    }
    sNorm[t] = rsqrtf((float)s + 1.0f);
  }
  for (int i = t; i < 8192; i += 512) {
    int s = i >> 6, f = i & 63;
    sXrm[s * 65 + f] = x[(size_t)(base + s) * 64 + f];
  }
  for (int g = t; g < 1024; g += 512) {
    int n = g >> 3, blk = g & 7;
    *(uint4*)(sW1t + n * 64 + ((blk ^ (n & 7)) << 3)) = ((const uint4*)w1t)[g];
  }
  for (int i = t; i < 384; i += 512) sQ[i] = q[i];
  if (t < 3) {
    sEr[t] = er[b * 3 + t];
    sCh[t] = ch[t];
  }
  __syncthreads();

  // ---- phase 1: S' from global counts (coalesced) + X transpose->bf16 ----
  for (int i = t; i < 16384; i += 512) {
    int r = i >> 7, s = i & 127;
    uint32_t cnt = Sgb[i];
    float val = ((float)cnt + (r == s ? 1.f : 0.f)) * sNorm[r] * sNorm[s];
    sS[r * 128 + (s ^ ((r & 7) << 3))] = f2b(val);
  }
  for (int i = t; i < 4096; i += 512) {
    int f = i >> 6, s = (i & 63) * 2;
    float v0 = sXrm[s * 65 + f] * sNorm[s];
    float v1 = sXrm[(s + 1) * 65 + f] * sNorm[s + 1];
    uint32_t pk = (uint32_t)f2b(v0) | ((uint32_t)f2b(v1) << 16);
    *(uint32_t*)(sXt + (f * 128 + (s ^ ((f & 7) << 3)))) = pk;
  }
  __syncthreads();

  int mrow = w * 16 + (l & 15);
  int kblk = (l >> 4) * 8;
  int rbase = w * 16 + (l >> 4) * 4;

  // ---- phase 3: agg1 = S' @ X ; stage W2t (over dead sXrm) ----
  for (int nt = 0; nt < 4; ++nt) {
    f32x4 acc = {0.f, 0.f, 0.f, 0.f};
    int cg = nt * 16 + (l & 15);
#pragma unroll
    for (int ks = 0; ks < 4; ++ks) {
      int kc = ks * 32 + kblk;
      s8v a = *(const s8v*)(sS + swz128(mrow, kc));
      s8v bf = *(const s8v*)(sXt + swz128(cg, kc));
      acc = __builtin_amdgcn_mfma_f32_16x16x32_bf16(a, bf, acc, 0, 0, 0);
    }
#pragma unroll
    for (int rg = 0; rg < 4; ++rg) sAgg1[swz64(rbase + rg, cg)] = f2b(acc[rg]);
  }
  for (int g = t; g < 2048; g += 512) {
    int n = g >> 4, blk = g & 15;
    *(uint4*)(sW2t + n * 128 + ((blk ^ (n & 7)) << 3)) = ((const uint4*)w2t)[g];
  }
  __syncthreads();

  // ---- phase 4: h1 = relu(agg1 @ W1 + b1) -> h1^T ----
  for (int nt = 0; nt < 8; ++nt) {
    int cg = nt * 16 + (l & 15);
    float bv = b1[cg];
    f32x4 acc = {bv, bv, bv, bv};
#pragma unroll
    for (int ks = 0; ks < 2; ++ks) {
      int kc = ks * 32 + kblk;
      s8v a = *(const s8v*)(sAgg1 + swz64(mrow, kc));
      s8v bf = *(const s8v*)(sW1t + swz64(cg, kc));
      acc = __builtin_amdgcn_mfma_f32_16x16x32_bf16(a, bf, acc, 0, 0, 0);
    }
    u16 h0 = f2b(fmaxf(acc[0], 0.f)), h1v = f2b(fmaxf(acc[1], 0.f));
    u16 h2 = f2b(fmaxf(acc[2], 0.f)), h3 = f2b(fmaxf(acc[3], 0.f));
    uint2 pk;
    pk.x = (uint32_t)h0 | ((uint32_t)h1v << 16);
    pk.y = (uint32_t)h2 | ((uint32_t)h3 << 16);
    *(uint2*)(sB2 + swz128(cg, rbase)) = pk;
  }
  __syncthreads();

  // ---- phase 5: agg2 = S' @ h1 ----
  for (int nt = 0; nt < 8; ++nt) {
    f32x4 acc = {0.f, 0.f, 0.f, 0.f};
    int cg = nt * 16 + (l & 15);
#pragma unroll
    for (int ks = 0; ks < 4; ++ks) {
      int kc = ks * 32 + kblk;
      s8v a = *(const s8v*)(sS + swz128(mrow, kc));
      s8v bf = *(const s8v*)(sB2 + swz128(cg, kc));
      acc = __builtin_amdgcn_mfma_f32_16x16x32_bf16(a, bf, acc, 0, 0, 0);
    }
#pragma unroll
    for (int rg = 0; rg < 4; ++rg) sAgg2[swz128(rbase + rg, cg)] = f2b(acc[rg]);
  }
  __syncthreads();

  // ---- phase 6: poi = agg2 @ W2 + b2 -> sP + sPt ----
  for (int nt = 0; nt < 8; ++nt) {
    int cg = nt * 16 + (l & 15);
    float bv = b2[cg];
    f32x4 acc = {bv, bv, bv, bv};
#pragma unroll
    for (int ks = 0; ks < 4; ++ks) {
      int kc = ks * 32 + kblk;
      s8v a = *(const s8v*)(sAgg2 + swz128(mrow, kc));
      s8v bf = *(const s8v*)(sW2t + swz128(cg, kc));
      acc = __builtin_amdgcn_mfma_f32_16x16x32_bf16(a, bf, acc, 0, 0, 0);
    }
    u16 p0 = f2b(acc[0]), p1 = f2b(acc[1]), p2 = f2b(acc[2]), p3 = f2b(acc[3]);
#pragma unroll
    for (int rg = 0; rg < 4; ++rg)
      sP[swz128(rbase + rg, cg)] = (rg == 0) ? p0 : (rg == 1) ? p1 : (rg == 2) ? p2 : p3;
    uint2 pk;
    pk.x = (uint32_t)p0 | ((uint32_t)p1 << 16);
    pk.y = (uint32_t)p2 | ((uint32_t)p3 << 16);
    *(uint2*)(sPt + swz128(cg, rbase)) = pk;
  }
  __syncthreads();

  // ---- tail: pool from Pt rows ----
  if (t < 128) {
    int c = t;
    float s = 0.f;
    const u16* rowp = sPt + c * 128;
    int sw = (c & 7) << 3;
#pragma unroll
    for (int k8 = 0; k8 < 16; ++k8) {
      s8v v = *(const s8v*)(rowp + ((k8 * 8) ^ sw));
#pragma unroll
      for (int j = 0; j < 8; ++j) s += b2f((u16)v[j]);
    }
    sPool[c] = s;
    poi_pool[b * 128 + c] = s * (1.0f / 128.0f);
  }
  if (t < 384) {
    int r = t & 127, h = t >> 7;
    int sw = (r & 7) << 3;
    const u16* rowp = sP + r * 128;
    const float* qh = &sQ[h * 128];
    float d = 0.f;
#pragma unroll
    for (int k8 = 0; k8 < 16; ++k8) {
      int c8 = (k8 * 8) ^ sw;
      s8v v = *(const s8v*)(rowp + c8);
#pragma unroll
      for (int j = 0; j < 8; ++j) d += b2f((u16)v[j]) * qh[c8 + j];
    }
    float e = d + sCh[h] + sEr[h];
    sAl[h * 128 + r] = (e > 0.f) ? e : 0.2f * e;
  }
  __syncthreads();

  if (t < 192) {
    int h = t >> 6, ll = t & 63;
    float v0 = sAl[h * 128 + ll], v1 = sAl[h * 128 + 64 + ll];
    float m = fmaxf(v0, v1);
    for (int off = 32; off > 0; off >>= 1) m = fmaxf(m, __shfl_xor(m, off));
    float x0 = __expf(v0 - m), x1 = __expf(v1 - m);
    float s = x0 + x1;
    for (int off = 32; off > 0; off >>= 1) s += __shfl_xor(s, off);
    float inv = 1.0f / s;
    sAl[h * 128 + ll] = x0 * inv;
    sAl[h * 128 + 64 + ll] = x1 * inv;
  }
  __syncthreads();

  if (t < 384) {
    int hh = t >> 7, c = t & 127;
    int sw = (c & 7) << 3;
    const u16* rowp = sPt + c * 128;
    const float* al = &sAl[hh * 128];
    float s = 0.f;
#pragma unroll
    for (int k8 = 0; k8 < 16; ++k8) {
      int r8 = (k8 * 8) ^ sw;
      s8v v = *(const s8v*)(rowp + r8);
#pragma unroll
      for (int j = 0; j < 8; ++j) s += b2f((u16)v[j]) * al[r8 + j];
    }
    pooled[((size_t)b * 3 + hh) * 128 + c] = s;
  }
  __syncthreads();

  // ---- fused mfn (bf16 out) ----
  float hv = 0.f, pv = 0.f;
  if (t < 128) {
    hv = hrs[base + t];
    pv = sPool[t] * (1.0f / 128.0f);
    sQ[t] = hv * hv + pv * pv;
  }
  __syncthreads();
  if (t < 64) {
    float v = sQ[t] + sQ[t + 64];
    for (int off = 32; off > 0; off >>= 1) v += __shfl_xor(v, off);
    if (t == 0) sQ[0] = rsqrtf(v);
  }
  __syncthreads();
  if (t < 128) {
    float rn = sQ[0];
    mfnb[b * 256 + t] = f2b(hv * rn);
    mfnb[b * 256 + 128 + t] = f2b(pv * rn);
  }
}

// ===================== med via MFMA: med = (mfn @ mfn^T + 1)/2 =====================
__global__ void __launch_bounds__(256) k_med(const u16* __restrict__ mfnb,
                                             float* __restrict__ med) {
  __shared__ u16 sA[32 * 256];
  __shared__ u16 sB[32 * 256];
  int bi = blockIdx.x >> 4, bj = blockIdx.x & 15;
  int t = threadIdx.x;
  const uint4* srcA = (const uint4*)(mfnb + (size_t)bi * 32 * 256);
  const uint4* srcB = (const uint4*)(mfnb + (size_t)bj * 32 * 256);
  for (int g = t; g < 1024; g += 256) {
    int r = g >> 5, blk = g & 31;
    int db = (blk & 24) | ((blk ^ (r & 7)) & 7);
    uint4 va = srcA[g];
    uint4 vb = srcB[g];
    *(uint4*)(sA + r * 256 + db * 8) = va;
    *(uint4*)(sB + r * 256 + db * 8) = vb;
  }
  __syncthreads();
  int l = t & 63, w = t >> 6;
  int wr = w >> 1, wc = w & 1;
  int arow = wr * 16 + (l & 15);
  int brow = wc * 16 + (l & 15);
  int kblk = (l >> 4) * 8;
  f32x4 acc = {0.f, 0.f, 0.f, 0.f};
#pragma unroll
  for (int ks = 0; ks < 8; ++ks) {
    int kc = ks * 32 + kblk;
    s8v a = *(const s8v*)(sA + arow * 256 + (kc ^ ((arow & 7) << 3)));
    s8v bb = *(const s8v*)(sB + brow * 256 + (kc ^ ((brow & 7) << 3)));
    acc = __builtin_amdgcn_mfma_f32_16x16x32_bf16(a, bb, acc, 0, 0, 0);
  }
  int row0 = bi * 32 + wr * 16 + (l >> 4) * 4;
  int col = bj * 32 + wc * 16 + (l & 15);
#pragma unroll
  for (int rg = 0; rg < 4; ++rg)
    med[(size_t)(row0 + rg) * 512 + col] = (acc[rg] + 1.0f) * 0.5f;
}

__global__ void k_rowsum(const float* __restrict__ med, const float* __restrict__ T0p,
                         float* __restrict__ dinv) {
  int r = blockIdx.x, l = threadIdx.x;
  float T0 = *T0p;
  float cnt = 0.f;
  for (int j = l; j < 512; j += 64) cnt += ((med[(size_t)r * 512 + j] >= T0) || (j == r)) ? 1.0f : 0.0f;
  for (int off = 32; off > 0; off >>= 1) cnt += __shfl_xor(cnt, off);
  if (l == 0) dinv[r] = rsqrtf(cnt);
}

// ===================== epilogue: sparse-neighbor Aagg + mat-vecs + final =====================
__global__ void __launch_bounds__(256) k_epilogue(
    const float* __restrict__ med, const float* __restrict__ T0p,
    const float* __restrict__ dinv, const float* __restrict__ hrs,
    const float* __restrict__ pool, const float* __restrict__ pooled,
    const float* __restrict__ ph, const float* __restrict__ Wh1, const float* __restrict__ bh1,
    const float* __restrict__ Wp1, const float* __restrict__ bp1,
    const float* __restrict__ Wpp, const float* __restrict__ bpp,
    const float* __restrict__ Wg_in, const float* __restrict__ g0in,
    const float* __restrict__ G, const float* __restrict__ g0w,
    const float* __restrict__ Wfc, const float* __restrict__ bfc, float* __restrict__ out) {
  __shared__ float sMedRow[512];
  __shared__ float sT[2][128];
  __shared__ float sPld[3][128];
  __shared__ float sPh[128];
  __shared__ float sY[3][128];
  __shared__ float sC[4][128];
  __shared__ int sNbr[64];
  __shared__ float sDw[64];
  __shared__ int sNnz;
  int i = blockIdx.x, t = threadIdx.x;
  int c = t & 127, half = t >> 7;
  float T0 = *T0p;

  for (int j = t; j < 512; j += 256) sMedRow[j] = med[(size_t)i * 512 + j];
  for (int k = t; k < 384; k += 256) sPld[k >> 7][k & 127] = pooled[(size_t)i * 384 + k];
  if (t < 128) sPh[t] = ph[i * 128 + t];
  __syncthreads();

  if (t < 64) {
    int cnt = 0, flags = 0;
#pragma unroll
    for (int k = 0; k < 8; ++k) {
      int j = t * 8 + k;
      if (sMedRow[j] >= T0 || j == i) {
        flags |= 1 << k;
        ++cnt;
      }
    }
    int off = cnt;
    for (int d = 1; d < 64; d <<= 1) {
      int v = __shfl_up(off, d);
      if (t >= d) off += v;
    }
    off -= cnt;
    int pos = off;
#pragma unroll
    for (int k = 0; k < 8; ++k)
      if (flags & (1 << k)) {
        int j = t * 8 + k;
        if (pos < 64) {
          sNbr[pos] = j;
          sDw[pos] = dinv[j];
        }
        ++pos;
      }
    if (t == 63) sNnz = off + cnt;
  }
  __syncthreads();

  {
    float di = dinv[i];
    const float* srcm = half ? pool : hrs;
    float acc = 0.f;
    int nnz = sNnz;
    if (nnz <= 64) {
      for (int n = 0; n < nnz; ++n) acc += sDw[n] * srcm[sNbr[n] * 128 + c];
    } else {
      for (int j = 0; j < 512; ++j)
        if (sMedRow[j] >= T0 || j == i) acc += dinv[j] * srcm[j * 128 + c];
    }
    sT[half][c] = acc * di;
  }
  __syncthreads();

  {
    const float* Wm = half ? Wp1 : Wh1;
    const float* bm = half ? bp1 : bh1;
    const float* xr = sT[half];
    float acc = bm[c];
#pragma unroll 4
    for (int k = 0; k < 128; ++k) acc += xr[k] * Wm[k * 128 + c];
    sC[half ? 1 : 3][c] = acc;
  }
  for (int task = t; task < 384; task += 256) {
    int h = task >> 7, cc = task & 127;
    float acc = bpp[cc];
#pragma unroll 4
    for (int k = 0; k < 128; ++k) acc += sPld[h][k] * Wpp[k * 128 + cc];
    sY[h][cc] = acc;
  }
  __syncthreads();

  if (half == 0) {
    float acc = 0.f;
    for (int h = 0; h < 3; ++h) {
      const float* y = sY[h];
      const float* Wc = Wg_in + h * 128 + c;
#pragma unroll 4
      for (int k = 0; k < 128; ++k) acc += y[k] * Wc[k * 384];
    }
    sC[2][c] = acc * (1.0f / 3.0f) + g0in[c];
  } else {
    float acc = g0w[c];
#pragma unroll 4
    for (int k = 0; k < 128; ++k) acc += sPh[k] * G[k * 128 + c];
    sC[0][c] = acc;
  }
  __syncthreads();

  __shared__ float sRed[16][8];
  if (t < 128) {
    int o = t >> 3, chunk = t & 7;
    float acc = 0.f;
    const float* cv = &sC[0][0] + chunk * 64;
    const float* Wv = Wfc + (size_t)(chunk * 64) * 16 + o;
#pragma unroll 4
    for (int k = 0; k < 64; ++k) acc += cv[k] * Wv[k * 16];
    sRed[o][chunk] = acc;
  }
  __syncthreads();
  if (t < 16) {
    float acc = bfc[t];
#pragma unroll
    for (int j = 0; j < 8; ++j) acc += sRed[t][j];
    out[i * 16 + t] = acc;
  }
}

// ===================== host =====================
extern "C" void kernel_launch(void* const* d_in, const int* in_sizes, int n_in,
                              void* d_out, int out_size, void* d_ws, size_t ws_size,
                              hipStream_t stream) {
  const float* poi_x = (const float*)d_in[0];
  const float* img = (const float*)d_in[1];
  const int* edges = (const int*)d_in[2];
  const float* T0p = (const float*)d_in[4];
  const float* W1 = (const float*)d_in[5];
  const float* b1 = (const float*)d_in[6];
  const float* W2 = (const float*)d_in[7];
  const float* b2 = (const float*)d_in[8];
  const float* Whrs = (const float*)d_in[9];
  const float* bhrs = (const float*)d_in[10];
  const float* Wph = (const float*)d_in[11];
  const float* bph = (const float*)d_in[12];
  const float* Wpp = (const float*)d_in[13];
  const float* bpp = (const float*)d_in[14];
  const float* Wg_in = (const float*)d_in[15];
  const float* al_in = (const float*)d_in[16];
  const float* ar_in = (const float*)d_in[17];
  const float* bg_in = (const float*)d_in[18];
  const float* Wg_w = (const float*)d_in[19];
  const float* bg_w = (const float*)d_in[22];
  const float* Wh1 = (const float*)d_in[23];
  const float* bh1 = (const float*)d_in[24];
  const float* Wp1 = (const float*)d_in[25];
  const float* bp1 = (const float*)d_in[26];
  const float* Wfc = (const float*)d_in[27];
  const float* bfc = (const float*)d_in[28];

  const int* esrc = edges;
  const int* edst = edges + EE;

  char* ws = (char*)d_ws;
  size_t off = 0;
  auto alloc = [&](size_t nbytes) -> char* {
    char* p = ws + off;
    off += (nbytes + 255) & ~(size_t)255;
    return p;
  };
  uint32_t* Sg = (uint32_t*)alloc((size_t)NN * 128 * 4);  // 33.5 MB dense count matrix
  u16* w1t = (u16*)alloc(8192 * 2);
  u16* w2t = (u16*)alloc(16384 * 2);
  float* hrs = (float*)alloc(512 * 128 * 4);
  float* phb = (float*)alloc(512 * 128 * 4);
  float* er = (float*)alloc(512 * 3 * 4);
  float* u = (float*)alloc(384 * 4);
  float* wv = (float*)alloc(384 * 4);
  float* q = (float*)alloc(384 * 4);
  float* chv = (float*)alloc(16);
  float* G = (float*)alloc(16384 * 4);
  float* g0w = (float*)alloc(128 * 4);
  float* g0in = (float*)alloc(128 * 4);
  float* pool = (float*)alloc(512 * 128 * 4);
  float* pooled = (float*)alloc((size_t)1536 * 128 * 4);
  u16* mfnb = (u16*)alloc(512 * 256 * 2);
  float* dinv = (float*)alloc(512 * 4);

  float* out = (float*)d_out;
  float* med = out + 512 * 16;

  hipMemsetAsync(Sg, 0, (size_t)NN * 128 * 4, stream);

  size_t dynf = 152096;
  hipFuncSetAttribute((const void*)k_gcn_fused, hipFuncAttributeMaxDynamicSharedMemorySize,
                      (int)dynf);

  k_prepAll<<<161, 256, 0, stream>>>(Wg_w, bg_w, bg_in, W1, W2, Wg_in, al_in, ar_in, Wpp, bpp,
                                     G, g0w, g0in, w1t, w2t, u, wv, q, chv);
  k_scatterS<<<EE / 256, 256, 0, stream>>>(esrc, edst, Sg);
  k_hrs<<<256, 512, 0, stream>>>(img, Whrs, bhrs, Wph, bph, wv, hrs, phb, er);
  k_gcn_fused<<<512, 512, dynf, stream>>>(poi_x, b1, b2, Sg, q, chv, er, hrs, w1t, w2t, pool,
                                          pooled, mfnb);
  k_med<<<256, 256, 0, stream>>>(mfnb, med);
  k_rowsum<<<512, 64, 0, stream>>>(med, T0p, dinv);
  k_epilogue<<<512, 256, 0, stream>>>(med, T0p, dinv, hrs, pool, pooled, phb, Wh1, bh1, Wp1,
                                      bp1, Wpp, bpp, Wg_in, g0in, G, g0w, Wfc, bfc, out);

  (void)in_sizes; (void)n_in; (void)out_size; (void)ws_size;
}

// Round 10
// 172.515 us; speedup vs baseline: 6.9460x; 1.2121x over previous
//
#include <hip/hip_runtime.h>
#include <stdint.h>

#define NN 65536
#define EE 524288
#define BB 512

typedef unsigned short u16;
typedef __attribute__((ext_vector_type(8))) short s8v;    // 8 bf16 (4 VGPRs)
typedef __attribute__((ext_vector_type(4))) float f32x4;  // MFMA acc

__device__ __forceinline__ u16 f2b(float f) {
  union { float f; uint32_t u; } a{f};
  uint32_t r = a.u + 0x7fff + ((a.u >> 16) & 1);
  return (u16)(r >> 16);
}
__device__ __forceinline__ float b2f(u16 v) {
  union { uint32_t u; float f; } a{(uint32_t)v << 16};
  return a.f;
}
__device__ __forceinline__ int swz128(int r, int c) { return r * 128 + (c ^ ((r & 7) << 3)); }
__device__ __forceinline__ int swz64(int r, int c) { return r * 64 + (c ^ ((r & 7) << 3)); }

// ===================== graph prep: dense per-parcel u8 count matrix =====================
__global__ void k_scatterS(const int* __restrict__ src, const int* __restrict__ dst,
                           uint32_t* __restrict__ Sg) {
  int e = blockIdx.x * 256 + threadIdx.x;
  if (e >= EE) return;
  int s = src[e] & 127, d = dst[e];
  atomicAdd(&Sg[((size_t)d * 128 + s) >> 2], 1u << ((s & 3) * 8));
}

// ===================== merged weight prep =====================
__global__ void k_prepAll(const float* __restrict__ Wg_w, const float* __restrict__ bg_w,
                          const float* __restrict__ bg_in, const float* __restrict__ W1,
                          const float* __restrict__ W2, const float* __restrict__ Wg_in,
                          const float* __restrict__ al_in, const float* __restrict__ ar_in,
                          const float* __restrict__ Wpp, const float* __restrict__ bpp,
                          float* __restrict__ G, float* __restrict__ g0w,
                          float* __restrict__ g0in, u16* __restrict__ w1t,
                          u16* __restrict__ w2t, float* __restrict__ u, float* __restrict__ wv,
                          float* __restrict__ q, float* __restrict__ ch) {
  int blk = blockIdx.x, t = threadIdx.x;
  if (blk < 64) {
    int i = blk * 256 + t;  // 16384
    int k = i >> 7, c = i & 127;
    G[i] = (Wg_w[k * 384 + c] + Wg_w[k * 384 + 128 + c] + Wg_w[k * 384 + 256 + c]) *
           (1.0f / 3.0f);
    if (i < 128) {
      g0w[i] = (bg_w[i] + bg_w[128 + i] + bg_w[256 + i]) * (1.0f / 3.0f);
      g0in[i] = (bg_in[i] + bg_in[128 + i] + bg_in[256 + i]) * (1.0f / 3.0f);
    }
  } else if (blk < 160) {
    int i = (blk - 64) * 256 + t;  // 24576
    if (i < 8192) {
      int n = i >> 6, k = i & 63;
      w1t[i] = f2b(W1[k * 128 + n]);
    } else {
      int j = i - 8192;
      int n = j >> 7, k = j & 127;
      w2t[j] = f2b(W2[k * 128 + n]);
    }
  } else {
    __shared__ float su[384];
    for (int i = t; i < 384; i += 256) {
      int h = i >> 7, k = i & 127;
      float s = 0.f, sw = 0.f;
#pragma unroll 4
      for (int c = 0; c < 128; ++c) {
        float g = Wg_in[k * 384 + h * 128 + c];
        s += g * al_in[h * 128 + c];
        sw += g * ar_in[h * 128 + c];
      }
      su[i] = s;
      u[i] = s;
      wv[i] = sw;
    }
    __syncthreads();
    for (int i = t; i < 384; i += 256) {
      int h = i >> 7, j = i & 127;
      float s = 0.f;
#pragma unroll 4
      for (int k = 0; k < 128; ++k) s += Wpp[j * 128 + k] * su[h * 128 + k];
      q[i] = s;
    }
    if (t < 3) {
      float s = 0.f;
#pragma unroll 4
      for (int k = 0; k < 128; ++k) s += bpp[k] * su[t * 128 + k];
      ch[t] = s;
    }
  }
}

// ===================== hrs encoder + ph + er (fused) =====================
__global__ void __launch_bounds__(512) k_hrs(const float* __restrict__ img,
                                             const float* __restrict__ Whrs,
                                             const float* __restrict__ bhrs,
                                             const float* __restrict__ Wph,
                                             const float* __restrict__ bph,
                                             const float* __restrict__ wv,
                                             float* __restrict__ hrs, float* __restrict__ ph,
                                             float* __restrict__ er) {
  __shared__ float sI[4096];
  __shared__ float sRed[4][128];
  __shared__ float sHrs[2][128];
  __shared__ float sPh[2][128];
  int r0 = blockIdx.x * 2;
  int t = threadIdx.x;
  const float4* gsrc = (const float4*)(img + (size_t)r0 * 2048);
  float4* ldst = (float4*)sI;
  for (int i = t; i < 1024; i += 512) ldst[i] = gsrc[i];
  __syncthreads();
  int c = t & 127, g = t >> 7;
  int row = g & 1, ks = g >> 1;
  const float* s = sI + row * 2048 + ks * 1024;
  const float* W = Whrs + (size_t)(ks * 1024) * 128 + c;
  float a0 = 0.f, a1 = 0.f, a2 = 0.f, a3 = 0.f;
  for (int k = 0; k < 1024; k += 4) {
    a0 += s[k] * W[(size_t)k * 128];
    a1 += s[k + 1] * W[(size_t)(k + 1) * 128];
    a2 += s[k + 2] * W[(size_t)(k + 2) * 128];
    a3 += s[k + 3] * W[(size_t)(k + 3) * 128];
  }
  sRed[g][c] = (a0 + a1) + (a2 + a3);
  __syncthreads();
  if (t < 256) {
    int rr = t >> 7, cc = t & 127;
    float v = sRed[rr][cc] + sRed[rr + 2][cc] + bhrs[cc];
    hrs[(r0 + rr) * 128 + cc] = v;
    sHrs[rr][cc] = v;
  }
  __syncthreads();
  if (t < 256) {
    int rr = t >> 7, cc = t & 127;
    float acc = bph[cc];
#pragma unroll 4
    for (int k = 0; k < 128; ++k) acc += sHrs[rr][k] * Wph[k * 128 + cc];
    sPh[rr][cc] = acc;
    ph[(r0 + rr) * 128 + cc] = acc;
  }
  __syncthreads();
  if (t < 6) {
    int rr = t / 3, h = t % 3;
    float s2 = 0.f;
#pragma unroll 4
    for (int k = 0; k < 128; ++k) s2 += sPh[rr][k] * wv[h * 128 + k];
    er[(r0 + rr) * 3 + h] = s2;
  }
}

// ===================== FUSED GCN via dense S' + MFMA =====================
__global__ void __launch_bounds__(512) k_gcn_fused(
    const float* __restrict__ x, const float* __restrict__ b1, const float* __restrict__ b2,
    const uint8_t* __restrict__ Sg8, const float* __restrict__ q, const float* __restrict__ ch,
    const float* __restrict__ er, const float* __restrict__ hrs,
    const u16* __restrict__ w1t, const u16* __restrict__ w2t, float* __restrict__ poi_pool,
    float* __restrict__ pooled, u16* __restrict__ mfnb) {
  extern __shared__ char sm[];
  u16* sS = (u16*)sm;
  u16* sB2 = (u16*)(sm + 32768);
  u16* sPt = (u16*)(sm + 32768);
  u16* sXt = (u16*)(sm + 65536);
  u16* sAgg1 = (u16*)(sm + 81920);
  u16* sW1t = (u16*)(sm + 98304);
  float* sXrm = (float*)(sm + 114688);
  u16* sW2t = (u16*)(sm + 114688);
  u16* sAgg2 = (u16*)(sm + 65536);
  u16* sP = (u16*)sm;
  float* sNorm = (float*)(sm + 147968);
  float* sQ = (float*)(sm + 148480);
  float* sAl = (float*)(sm + 150016);
  float* sPool = (float*)(sm + 151552);
  float* sEr = (float*)(sm + 152064);
  float* sCh = (float*)(sm + 152080);

  int b = blockIdx.x, t = threadIdx.x;
  int base = b << 7;
  int l = t & 63, w = t >> 6;
  const uint8_t* Sgb = Sg8 + (size_t)base * 128;

  // ---- phase 0: norms from u8 row-sums; stage Xrm, W1t, q/er/ch ----
  if (t < 128) {
    const uint4* rp = (const uint4*)(Sgb + (size_t)t * 128);
    uint32_t s = 0;
#pragma unroll
    for (int k = 0; k < 8; ++k) {
      uint4 v = rp[k];
      uint32_t ws[4] = {v.x, v.y, v.z, v.w};
#pragma unroll
      for (int p = 0; p < 4; ++p)
        s += (ws[p] & 0xff) + ((ws[p] >> 8) & 0xff) + ((ws[p] >> 16) & 0xff) + (ws[p] >> 24);
    }
    sNorm[t] = rsqrtf((float)s + 1.0f);
  }
  for (int i = t; i < 8192; i += 512) {
    int s = i >> 6, f = i & 63;
    sXrm[s * 65 + f] = x[(size_t)(base + s) * 64 + f];
  }
  for (int g = t; g < 1024; g += 512) {
    int n = g >> 3, blk = g & 7;
    *(uint4*)(sW1t + n * 64 + ((blk ^ (n & 7)) << 3)) = ((const uint4*)w1t)[g];
  }
  for (int i = t; i < 384; i += 512) sQ[i] = q[i];
  if (t < 3) {
    sEr[t] = er[b * 3 + t];
    sCh[t] = ch[t];
  }
  __syncthreads();

  // ---- phase 1: S' from u8 counts (uint4 loads, 32 counts/thread) + X transpose->bf16 ----
  {
    int r = t >> 2, sb = (t & 3) * 32;
    const uint4* cp = (const uint4*)(Sgb + r * 128 + sb);
    uint4 c0 = cp[0], c1 = cp[1];
    float nr = sNorm[r];
    int sw = (r & 7) << 3;
    uint32_t words[8] = {c0.x, c0.y, c0.z, c0.w, c1.x, c1.y, c1.z, c1.w};
#pragma unroll
    for (int qd = 0; qd < 8; ++qd) {
      uint32_t wd = words[qd];
#pragma unroll
      for (int p = 0; p < 4; p += 2) {
        int s0 = sb + qd * 4 + p;
        float v0 = ((float)((wd >> (p * 8)) & 0xff) + (r == s0 ? 1.f : 0.f)) * nr * sNorm[s0];
        float v1 =
            ((float)((wd >> (p * 8 + 8)) & 0xff) + (r == s0 + 1 ? 1.f : 0.f)) * nr * sNorm[s0 + 1];
        uint32_t pk = (uint32_t)f2b(v0) | ((uint32_t)f2b(v1) << 16);
        *(uint32_t*)(sS + r * 128 + (s0 ^ sw)) = pk;
      }
    }
  }
  for (int i = t; i < 4096; i += 512) {
    int f = i >> 6, s = (i & 63) * 2;
    float v0 = sXrm[s * 65 + f] * sNorm[s];
    float v1 = sXrm[(s + 1) * 65 + f] * sNorm[s + 1];
    uint32_t pk = (uint32_t)f2b(v0) | ((uint32_t)f2b(v1) << 16);
    *(uint32_t*)(sXt + (f * 128 + (s ^ ((f & 7) << 3)))) = pk;
  }
  __syncthreads();

  int mrow = w * 16 + (l & 15);
  int kblk = (l >> 4) * 8;
  int rbase = w * 16 + (l >> 4) * 4;

  // ---- phase 3: agg1 = S' @ X ; stage W2t (over dead sXrm) ----
  for (int nt = 0; nt < 4; ++nt) {
    f32x4 acc = {0.f, 0.f, 0.f, 0.f};
    int cg = nt * 16 + (l & 15);
#pragma unroll
    for (int ks = 0; ks < 4; ++ks) {
      int kc = ks * 32 + kblk;
      s8v a = *(const s8v*)(sS + swz128(mrow, kc));
      s8v bf = *(const s8v*)(sXt + swz128(cg, kc));
      acc = __builtin_amdgcn_mfma_f32_16x16x32_bf16(a, bf, acc, 0, 0, 0);
    }
#pragma unroll
    for (int rg = 0; rg < 4; ++rg) sAgg1[swz64(rbase + rg, cg)] = f2b(acc[rg]);
  }
  for (int g = t; g < 2048; g += 512) {
    int n = g >> 4, blk = g & 15;
    *(uint4*)(sW2t + n * 128 + ((blk ^ (n & 7)) << 3)) = ((const uint4*)w2t)[g];
  }
  __syncthreads();

  // ---- phase 4: h1 = relu(agg1 @ W1 + b1) -> h1^T ----
  for (int nt = 0; nt < 8; ++nt) {
    int cg = nt * 16 + (l & 15);
    float bv = b1[cg];
    f32x4 acc = {bv, bv, bv, bv};
#pragma unroll
    for (int ks = 0; ks < 2; ++ks) {
      int kc = ks * 32 + kblk;
      s8v a = *(const s8v*)(sAgg1 + swz64(mrow, kc));
      s8v bf = *(const s8v*)(sW1t + swz64(cg, kc));
      acc = __builtin_amdgcn_mfma_f32_16x16x32_bf16(a, bf, acc, 0, 0, 0);
    }
    u16 h0 = f2b(fmaxf(acc[0], 0.f)), h1v = f2b(fmaxf(acc[1], 0.f));
    u16 h2 = f2b(fmaxf(acc[2], 0.f)), h3 = f2b(fmaxf(acc[3], 0.f));
    uint2 pk;
    pk.x = (uint32_t)h0 | ((uint32_t)h1v << 16);
    pk.y = (uint32_t)h2 | ((uint32_t)h3 << 16);
    *(uint2*)(sB2 + swz128(cg, rbase)) = pk;
  }
  __syncthreads();

  // ---- phase 5: agg2 = S' @ h1 ----
  for (int nt = 0; nt < 8; ++nt) {
    f32x4 acc = {0.f, 0.f, 0.f, 0.f};
    int cg = nt * 16 + (l & 15);
#pragma unroll
    for (int ks = 0; ks < 4; ++ks) {
      int kc = ks * 32 + kblk;
      s8v a = *(const s8v*)(sS + swz128(mrow, kc));
      s8v bf = *(const s8v*)(sB2 + swz128(cg, kc));
      acc = __builtin_amdgcn_mfma_f32_16x16x32_bf16(a, bf, acc, 0, 0, 0);
    }
#pragma unroll
    for (int rg = 0; rg < 4; ++rg) sAgg2[swz128(rbase + rg, cg)] = f2b(acc[rg]);
  }
  __syncthreads();

  // ---- phase 6: poi = agg2 @ W2 + b2 -> sP + sPt ----
  for (int nt = 0; nt < 8; ++nt) {
    int cg = nt * 16 + (l & 15);
    float bv = b2[cg];
    f32x4 acc = {bv, bv, bv, bv};
#pragma unroll
    for (int ks = 0; ks < 4; ++ks) {
      int kc = ks * 32 + kblk;
      s8v a = *(const s8v*)(sAgg2 + swz128(mrow, kc));
      s8v bf = *(const s8v*)(sW2t + swz128(cg, kc));
      acc = __builtin_amdgcn_mfma_f32_16x16x32_bf16(a, bf, acc, 0, 0, 0);
    }
    u16 p0 = f2b(acc[0]), p1 = f2b(acc[1]), p2 = f2b(acc[2]), p3 = f2b(acc[3]);
#pragma unroll
    for (int rg = 0; rg < 4; ++rg)
      sP[swz128(rbase + rg, cg)] = (rg == 0) ? p0 : (rg == 1) ? p1 : (rg == 2) ? p2 : p3;
    uint2 pk;
    pk.x = (uint32_t)p0 | ((uint32_t)p1 << 16);
    pk.y = (uint32_t)p2 | ((uint32_t)p3 << 16);
    *(uint2*)(sPt + swz128(cg, rbase)) = pk;
  }
  __syncthreads();

  // ---- tail: pool from Pt rows ----
  if (t < 128) {
    int c = t;
    float s = 0.f;
    const u16* rowp = sPt + c * 128;
    int sw = (c & 7) << 3;
#pragma unroll
    for (int k8 = 0; k8 < 16; ++k8) {
      s8v v = *(const s8v*)(rowp + ((k8 * 8) ^ sw));
#pragma unroll
      for (int j = 0; j < 8; ++j) s += b2f((u16)v[j]);
    }
    sPool[c] = s;
    poi_pool[b * 128 + c] = s * (1.0f / 128.0f);
  }
  if (t < 384) {
    int r = t & 127, h = t >> 7;
    int sw = (r & 7) << 3;
    const u16* rowp = sP + r * 128;
    const float* qh = &sQ[h * 128];
    float d = 0.f;
#pragma unroll
    for (int k8 = 0; k8 < 16; ++k8) {
      int c8 = (k8 * 8) ^ sw;
      s8v v = *(const s8v*)(rowp + c8);
#pragma unroll
      for (int j = 0; j < 8; ++j) d += b2f((u16)v[j]) * qh[c8 + j];
    }
    float e = d + sCh[h] + sEr[h];
    sAl[h * 128 + r] = (e > 0.f) ? e : 0.2f * e;
  }
  __syncthreads();

  if (t < 192) {
    int h = t >> 6, ll = t & 63;
    float v0 = sAl[h * 128 + ll], v1 = sAl[h * 128 + 64 + ll];
    float m = fmaxf(v0, v1);
    for (int off = 32; off > 0; off >>= 1) m = fmaxf(m, __shfl_xor(m, off));
    float x0 = __expf(v0 - m), x1 = __expf(v1 - m);
    float s = x0 + x1;
    for (int off = 32; off > 0; off >>= 1) s += __shfl_xor(s, off);
    float inv = 1.0f / s;
    sAl[h * 128 + ll] = x0 * inv;
    sAl[h * 128 + 64 + ll] = x1 * inv;
  }
  __syncthreads();

  if (t < 384) {
    int hh = t >> 7, c = t & 127;
    int sw = (c & 7) << 3;
    const u16* rowp = sPt + c * 128;
    const float* al = &sAl[hh * 128];
    float s = 0.f;
#pragma unroll
    for (int k8 = 0; k8 < 16; ++k8) {
      int r8 = (k8 * 8) ^ sw;
      s8v v = *(const s8v*)(rowp + r8);
#pragma unroll
      for (int j = 0; j < 8; ++j) s += b2f((u16)v[j]) * al[r8 + j];
    }
    pooled[((size_t)b * 3 + hh) * 128 + c] = s;
  }
  __syncthreads();

  // ---- fused mfn (bf16 out) ----
  float hv = 0.f, pv = 0.f;
  if (t < 128) {
    hv = hrs[base + t];
    pv = sPool[t] * (1.0f / 128.0f);
    sQ[t] = hv * hv + pv * pv;
  }
  __syncthreads();
  if (t < 64) {
    float v = sQ[t] + sQ[t + 64];
    for (int off = 32; off > 0; off >>= 1) v += __shfl_xor(v, off);
    if (t == 0) sQ[0] = rsqrtf(v);
  }
  __syncthreads();
  if (t < 128) {
    float rn = sQ[0];
    mfnb[b * 256 + t] = f2b(hv * rn);
    mfnb[b * 256 + 128 + t] = f2b(pv * rn);
  }
}

// ===================== med via MFMA: med = (mfn @ mfn^T + 1)/2 =====================
__global__ void __launch_bounds__(256) k_med(const u16* __restrict__ mfnb,
                                             float* __restrict__ med) {
  __shared__ u16 sA[32 * 256];
  __shared__ u16 sB[32 * 256];
  int bi = blockIdx.x >> 4, bj = blockIdx.x & 15;
  int t = threadIdx.x;
  const uint4* srcA = (const uint4*)(mfnb + (size_t)bi * 32 * 256);
  const uint4* srcB = (const uint4*)(mfnb + (size_t)bj * 32 * 256);
  for (int g = t; g < 1024; g += 256) {
    int r = g >> 5, blk = g & 31;
    int db = (blk & 24) | ((blk ^ (r & 7)) & 7);
    uint4 va = srcA[g];
    uint4 vb = srcB[g];
    *(uint4*)(sA + r * 256 + db * 8) = va;
    *(uint4*)(sB + r * 256 + db * 8) = vb;
  }
  __syncthreads();
  int l = t & 63, w = t >> 6;
  int wr = w >> 1, wc = w & 1;
  int arow = wr * 16 + (l & 15);
  int brow = wc * 16 + (l & 15);
  int kblk = (l >> 4) * 8;
  f32x4 acc = {0.f, 0.f, 0.f, 0.f};
#pragma unroll
  for (int ks = 0; ks < 8; ++ks) {
    int kc = ks * 32 + kblk;
    s8v a = *(const s8v*)(sA + arow * 256 + (kc ^ ((arow & 7) << 3)));
    s8v bb = *(const s8v*)(sB + brow * 256 + (kc ^ ((brow & 7) << 3)));
    acc = __builtin_amdgcn_mfma_f32_16x16x32_bf16(a, bb, acc, 0, 0, 0);
  }
  int row0 = bi * 32 + wr * 16 + (l >> 4) * 4;
  int col = bj * 32 + wc * 16 + (l & 15);
#pragma unroll
  for (int rg = 0; rg < 4; ++rg)
    med[(size_t)(row0 + rg) * 512 + col] = (acc[rg] + 1.0f) * 0.5f;
}

__global__ void k_rowsum(const float* __restrict__ med, const float* __restrict__ T0p,
                         float* __restrict__ dinv) {
  int r = blockIdx.x, l = threadIdx.x;
  float T0 = *T0p;
  float cnt = 0.f;
  for (int j = l; j < 512; j += 64) cnt += ((med[(size_t)r * 512 + j] >= T0) || (j == r)) ? 1.0f : 0.0f;
  for (int off = 32; off > 0; off >>= 1) cnt += __shfl_xor(cnt, off);
  if (l == 0) dinv[r] = rsqrtf(cnt);
}

// ===================== epilogue: 512 threads, k-split mat-vecs =====================
__global__ void __launch_bounds__(512) k_epilogue(
    const float* __restrict__ med, const float* __restrict__ T0p,
    const float* __restrict__ dinv, const float* __restrict__ hrs,
    const float* __restrict__ pool, const float* __restrict__ pooled,
    const float* __restrict__ ph, const float* __restrict__ Wh1, const float* __restrict__ bh1,
    const float* __restrict__ Wp1, const float* __restrict__ bp1,
    const float* __restrict__ Wpp, const float* __restrict__ bpp,
    const float* __restrict__ Wg_in, const float* __restrict__ g0in,
    const float* __restrict__ G, const float* __restrict__ g0w,
    const float* __restrict__ Wfc, const float* __restrict__ bfc, float* __restrict__ out) {
  __shared__ float sMedRow[512];
  __shared__ float sT[2][128];
  __shared__ float sPld[3][128];
  __shared__ float sPh[128];
  __shared__ float sY[3][128];
  __shared__ float sYp[6][128];   // Y partials [h*2+kh][c]
  __shared__ float sC[4][128];
  __shared__ float sMv[4][128];   // matvec partials [half*2+kh][c]
  __shared__ float sP2[2][128];   // poi2img partials
  __shared__ float sG2[2][128];   // img2poi partials
  __shared__ float sRed[16][16];
  __shared__ int sNbr[64];
  __shared__ float sDw[64];
  __shared__ int sNnz;
  int i = blockIdx.x, t = threadIdx.x;
  int c = t & 127;
  float T0 = *T0p;

  // stage med row, pooled, ph (512 threads: one pass)
  if (t < 512) sMedRow[t] = med[(size_t)i * 512 + t];
  if (t < 384)
    sPld[t >> 7][t & 127] = pooled[(size_t)i * 384 + t];
  else
    sPh[t - 384] = ph[i * 128 + (t - 384)];
  __syncthreads();

  // deterministic neighbor-list build: wave 0
  if (t < 64) {
    int cnt = 0, flags = 0;
#pragma unroll
    for (int k = 0; k < 8; ++k) {
      int j = t * 8 + k;
      if (sMedRow[j] >= T0 || j == i) {
        flags |= 1 << k;
        ++cnt;
      }
    }
    int off = cnt;
    for (int d = 1; d < 64; d <<= 1) {
      int v = __shfl_up(off, d);
      if (t >= d) off += v;
    }
    off -= cnt;
    int pos = off;
#pragma unroll
    for (int k = 0; k < 8; ++k)
      if (flags & (1 << k)) {
        int j = t * 8 + k;
        if (pos < 64) {
          sNbr[pos] = j;
          sDw[pos] = dinv[j];
        }
        ++pos;
      }
    if (t == 63) sNnz = off + cnt;
  }
  __syncthreads();

  // Aagg (threads 0..255; sparse, nnz typically 1)
  if (t < 256) {
    int half = t >> 7;
    float di = dinv[i];
    const float* srcm = half ? pool : hrs;
    float acc = 0.f;
    int nnz = sNnz;
    if (nnz <= 64) {
      for (int n = 0; n < nnz; ++n) acc += sDw[n] * srcm[sNbr[n] * 128 + c];
    } else {
      for (int j = 0; j < 512; ++j)
        if (sMedRow[j] >= T0 || j == i) acc += dinv[j] * srcm[j * 128 + c];
    }
    sT[half][c] = acc * di;
  }
  __syncthreads();

  // matvec partials: (half, kh, c) = 512 threads, 64 k each
  {
    int half = (t >> 7) & 1, kh = t >> 8;
    const float* Wm = half ? Wp1 : Wh1;
    const float* xr = sT[half];
    float acc = 0.f;
    int k0 = kh * 64;
#pragma unroll 4
    for (int k = k0; k < k0 + 64; ++k) acc += xr[k] * Wm[k * 128 + c];
    sMv[half * 2 + kh][c] = acc;
  }
  // Y partials: 768 tasks (h, kh, c)
  for (int task = t; task < 768; task += 512) {
    int h = task >> 8, khh = (task >> 7) & 1, cc = task & 127;
    float acc = 0.f;
    int k0 = khh * 64;
#pragma unroll 4
    for (int k = k0; k < k0 + 64; ++k) acc += sPld[h][k] * Wpp[k * 128 + cc];
    sYp[h * 2 + khh][cc] = acc;
  }
  __syncthreads();

  // combine
  if (t < 256) {
    int half = t >> 7;
    sC[half ? 1 : 3][c] = sMv[half * 2][c] + sMv[half * 2 + 1][c] + (half ? bp1[c] : bh1[c]);
  }
  if (t < 384) {
    int h = t >> 7, cc = t & 127;
    sY[h][cc] = sYp[h * 2][cc] + sYp[h * 2 + 1][cc] + bpp[cc];
  }
  __syncthreads();

  // poi2img partials (t<256) / img2poi partials (t>=256)
  if (t < 256) {
    int kh = t >> 7;
    int k0 = kh * 64;
    float acc = 0.f;
    for (int h = 0; h < 3; ++h) {
      const float* y = sY[h];
      const float* Wc = Wg_in + h * 128 + c;
#pragma unroll 4
      for (int k = k0; k < k0 + 64; ++k) acc += y[k] * Wc[k * 384];
    }
    sP2[kh][c] = acc;
  } else {
    int kh = (t >> 7) & 1;
    int k0 = kh * 64;
    float acc = 0.f;
#pragma unroll 4
    for (int k = k0; k < k0 + 64; ++k) acc += sPh[k] * G[k * 128 + c];
    sG2[kh][c] = acc;
  }
  __syncthreads();

  if (t < 128) {
    sC[2][t] = (sP2[0][t] + sP2[1][t]) * (1.0f / 3.0f) + g0in[t];
  } else if (t < 256) {
    sC[0][c] = sG2[0][c] + sG2[1][c] + g0w[c];
  }
  __syncthreads();

  // final: 256 threads, o = t>>4, chunk = t&15, 32 k each
  if (t < 256) {
    int o = t >> 4, chunk = t & 15;
    float acc = 0.f;
    const float* cv = &sC[0][0] + chunk * 32;
    const float* Wv = Wfc + (size_t)(chunk * 32) * 16 + o;
#pragma unroll 4
    for (int k = 0; k < 32; ++k) acc += cv[k] * Wv[k * 16];
    sRed[o][chunk] = acc;
  }
  __syncthreads();
  if (t < 16) {
    float acc = bfc[t];
#pragma unroll
    for (int j = 0; j < 16; ++j) acc += sRed[t][j];
    out[i * 16 + t] = acc;
  }
}

// ===================== host =====================
extern "C" void kernel_launch(void* const* d_in, const int* in_sizes, int n_in,
                              void* d_out, int out_size, void* d_ws, size_t ws_size,
                              hipStream_t stream) {
  const float* poi_x = (const float*)d_in[0];
  const float* img = (const float*)d_in[1];
  const int* edges = (const int*)d_in[2];
  const float* T0p = (const float*)d_in[4];
  const float* W1 = (const float*)d_in[5];
  const float* b1 = (const float*)d_in[6];
  const float* W2 = (const float*)d_in[7];
  const float* b2 = (const float*)d_in[8];
  const float* Whrs = (const float*)d_in[9];
  const float* bhrs = (const float*)d_in[10];
  const float* Wph = (const float*)d_in[11];
  const float* bph = (const float*)d_in[12];
  const float* Wpp = (const float*)d_in[13];
  const float* bpp = (const float*)d_in[14];
  const float* Wg_in = (const float*)d_in[15];
  const float* al_in = (const float*)d_in[16];
  const float* ar_in = (const float*)d_in[17];
  const float* bg_in = (const float*)d_in[18];
  const float* Wg_w = (const float*)d_in[19];
  const float* bg_w = (const float*)d_in[22];
  const float* Wh1 = (const float*)d_in[23];
  const float* bh1 = (const float*)d_in[24];
  const float* Wp1 = (const float*)d_in[25];
  const float* bp1 = (const float*)d_in[26];
  const float* Wfc = (const float*)d_in[27];
  const float* bfc = (const float*)d_in[28];

  const int* esrc = edges;
  const int* edst = edges + EE;

  char* ws = (char*)d_ws;
  size_t off = 0;
  auto alloc = [&](size_t nbytes) -> char* {
    char* p = ws + off;
    off += (nbytes + 255) & ~(size_t)255;
    return p;
  };
  uint8_t* Sg8 = (uint8_t*)alloc((size_t)NN * 128);  // 8.4 MB u8 count matrix
  u16* w1t = (u16*)alloc(8192 * 2);
  u16* w2t = (u16*)alloc(16384 * 2);
  float* hrs = (float*)alloc(512 * 128 * 4);
  float* phb = (float*)alloc(512 * 128 * 4);
  float* er = (float*)alloc(512 * 3 * 4);
  float* u = (float*)alloc(384 * 4);
  float* wv = (float*)alloc(384 * 4);
  float* q = (float*)alloc(384 * 4);
  float* chv = (float*)alloc(16);
  float* G = (float*)alloc(16384 * 4);
  float* g0w = (float*)alloc(128 * 4);
  float* g0in = (float*)alloc(128 * 4);
  float* pool = (float*)alloc(512 * 128 * 4);
  float* pooled = (float*)alloc((size_t)1536 * 128 * 4);
  u16* mfnb = (u16*)alloc(512 * 256 * 2);
  float* dinv = (float*)alloc(512 * 4);

  float* out = (float*)d_out;
  float* med = out + 512 * 16;

  hipMemsetAsync(Sg8, 0, (size_t)NN * 128, stream);

  size_t dynf = 152096;
  hipFuncSetAttribute((const void*)k_gcn_fused, hipFuncAttributeMaxDynamicSharedMemorySize,
                      (int)dynf);

  k_prepAll<<<161, 256, 0, stream>>>(Wg_w, bg_w, bg_in, W1, W2, Wg_in, al_in, ar_in, Wpp, bpp,
                                     G, g0w, g0in, w1t, w2t, u, wv, q, chv);
  k_scatterS<<<EE / 256, 256, 0, stream>>>(esrc, edst, (uint32_t*)Sg8);
  k_hrs<<<256, 512, 0, stream>>>(img, Whrs, bhrs, Wph, bph, wv, hrs, phb, er);
  k_gcn_fused<<<512, 512, dynf, stream>>>(poi_x, b1, b2, Sg8, q, chv, er, hrs, w1t, w2t, pool,
                                          pooled, mfnb);
  k_med<<<256, 256, 0, stream>>>(mfnb, med);
  k_rowsum<<<512, 64, 0, stream>>>(med, T0p, dinv);
  k_epilogue<<<512, 512, 0, stream>>>(med, T0p, dinv, hrs, pool, pooled, phb, Wh1, bh1, Wp1,
                                      bp1, Wpp, bpp, Wg_in, g0in, G, g0w, Wfc, bfc, out);

  (void)in_sizes; (void)n_in; (void)out_size; (void)ws_size;
}